// Round 1
// baseline (2696.246 us; speedup 1.0000x reference)
//
#include <hip/hip_runtime.h>
#include <hip/hip_bf16.h>
#include <math.h>

#define Vv   32
#define Dd   128
#define Hh   8
#define HDd  16
#define Bb   8
#define Mm   2048
#define BM   (Bb*Mm)        // 16384
#define NEL  (BM*Dd)        // 2097152 floats = 8 MB

// ---------------- RoPE tables: cos/sin[m][i], i in [0,64) ----------------
__global__ __launch_bounds__(256) void rope_table_kernel(float* __restrict__ cosT,
                                                         float* __restrict__ sinT) {
    int gid = blockIdx.x * 256 + threadIdx.x;       // Mm*64 total
    int i = gid & 63;
    int m = gid >> 6;
    // base = 10000^(-2*(i-1)/D)   (note the (i-1): mirrors the reference exactly)
    float ex = -2.0f * ((float)i - 1.0f) / 128.0f;
    float base = expf(ex * 9.210340371976184f);     // ln(10000)
    float ang = (float)m * base;
    cosT[gid] = cosf(ang);
    sinT[gid] = sinf(ang);
}

// ---------------- embedding gather + per-batch sum of squares ----------------
__global__ __launch_bounds__(256) void gather_sumsq_kernel(const int* __restrict__ idx,
                                                           const float* __restrict__ emb,
                                                           float* __restrict__ X,
                                                           float* __restrict__ ssq) {
    int gid = blockIdx.x * 256 + threadIdx.x;       // NEL total
    int d = gid & 127;
    int token = gid >> 7;                           // b*M + m
    float x = emb[idx[token] * Dd + d];
    X[gid] = x;
    float v = x * x;
    #pragma unroll
    for (int off = 32; off; off >>= 1) v += __shfl_xor(v, off);
    __shared__ float wsum[4];
    int lane = threadIdx.x & 63, wave = threadIdx.x >> 6;
    if (lane == 0) wsum[wave] = v;
    __syncthreads();
    if (threadIdx.x == 0) atomicAdd(&ssq[gid >> 18], wsum[0] + wsum[1] + wsum[2] + wsum[3]);
}

// ---------------- per-batch sum of squares (no gather) ----------------
__global__ __launch_bounds__(256) void sumsq_kernel(const float* __restrict__ X,
                                                    float* __restrict__ ssq) {
    int gid = blockIdx.x * 256 + threadIdx.x;
    float x = X[gid];
    float v = x * x;
    #pragma unroll
    for (int off = 32; off; off >>= 1) v += __shfl_xor(v, off);
    __shared__ float wsum[4];
    int lane = threadIdx.x & 63, wave = threadIdx.x >> 6;
    if (lane == 0) wsum[wave] = v;
    __syncthreads();
    if (threadIdx.x == 0) atomicAdd(&ssq[gid >> 18], wsum[0] + wsum[1] + wsum[2] + wsum[3]);
}

// ---------------- x * (sqrt(M*D)/sqrt(ssq[b])) * scale[m,d] ----------------
__global__ __launch_bounds__(256) void normscale_kernel(const float* __restrict__ X,
                                                        const float* __restrict__ scale,
                                                        const float* __restrict__ ssq,
                                                        float* __restrict__ out) {
    int gid = blockIdx.x * 256 + threadIdx.x;
    int b = gid >> 18;                              // M*D = 2^18 per batch
    int md = gid & ((Mm * Dd) - 1);                 // m*D + d
    float inv = 512.0f / sqrtf(ssq[b]);             // sqrt(M*D)=512
    out[gid] = X[gid] * inv * scale[md];
}

// ---------------- generic row GEMM: out = A(16384x128) @ W(128x128)^T (+bias)(relu?)(+resid) ----------------
__global__ __launch_bounds__(128) void gemm128_kernel(const float* __restrict__ A,
                                                      const float* __restrict__ W,
                                                      const float* __restrict__ bias,
                                                      const float* __restrict__ resid,
                                                      float* __restrict__ out,
                                                      int relu) {
    __shared__ float As[8][128];
    int r0 = blockIdx.x * 8;
    int c = threadIdx.x;
    #pragma unroll
    for (int r = 0; r < 8; r++) As[r][c] = A[(size_t)(r0 + r) * 128 + c];
    __syncthreads();
    float acc[8];
    #pragma unroll
    for (int r = 0; r < 8; r++) acc[r] = 0.f;
    const float* wr = W + (size_t)c * 128;
    for (int k = 0; k < 128; k += 4) {
        float4 w4 = *(const float4*)(wr + k);
        #pragma unroll
        for (int r = 0; r < 8; r++) {
            acc[r] += As[r][k] * w4.x + As[r][k + 1] * w4.y + As[r][k + 2] * w4.z + As[r][k + 3] * w4.w;
        }
    }
    float bv = bias ? bias[c] : 0.f;
    #pragma unroll
    for (int r = 0; r < 8; r++) {
        float v = acc[r] + bv;
        if (relu) v = fmaxf(v, 0.f);
        if (resid) v += resid[(size_t)(r0 + r) * 128 + c];
        out[(size_t)(r0 + r) * 128 + c] = v;
    }
}

// ---------------- in-place RoPE over (b,m,i) pairs ----------------
__global__ __launch_bounds__(256) void rope_kernel(float* __restrict__ T,
                                                   const float* __restrict__ cosT,
                                                   const float* __restrict__ sinT) {
    int gid = blockIdx.x * 256 + threadIdx.x;       // B*M*64 total
    int i = gid & 63;
    int token = gid >> 6;                           // b*M + m
    int m = token & (Mm - 1);
    float c = cosT[m * 64 + i], s = sinT[m * 64 + i];
    float2* p = (float2*)(T + (size_t)token * Dd) + i;
    float2 eo = *p;
    float2 r;
    r.x = eo.x * c + eo.y * s;
    r.y = -eo.x * s + eo.y * c;
    *p = r;
}

// ---------------- flash attention: one wave per (b,h,q-row) ----------------
__global__ __launch_bounds__(256) void attn_kernel(const float* __restrict__ Q,
                                                   const float* __restrict__ K,
                                                   const float* __restrict__ Vp,
                                                   float* __restrict__ O) {
    int wave = threadIdx.x >> 6, lane = threadIdx.x & 63;
    int row = blockIdx.x * 4 + wave;                // (b*H + h)*M + m
    int m = row & (Mm - 1);
    int bh = row >> 11;
    int h = bh & (Hh - 1);
    int b = bh >> 3;
    const float* qptr = Q + (size_t)(b * Mm + m) * Dd + h * HDd;
    float4 q0 = *(const float4*)(qptr);
    float4 q1 = *(const float4*)(qptr + 4);
    float4 q2 = *(const float4*)(qptr + 8);
    float4 q3 = *(const float4*)(qptr + 12);
    float mx = -INFINITY, sum = 0.f;
    float acc[16];
    #pragma unroll
    for (int i = 0; i < 16; i++) acc[i] = 0.f;
    const float* Kb = K + (size_t)b * Mm * Dd + h * HDd;
    const float* Vb = Vp + (size_t)b * Mm * Dd + h * HDd;
    for (int j = lane; j <= m; j += 64) {
        const float* kp = Kb + (size_t)j * Dd;
        float4 k0 = *(const float4*)(kp);
        float4 k1 = *(const float4*)(kp + 4);
        float4 k2 = *(const float4*)(kp + 8);
        float4 k3 = *(const float4*)(kp + 12);
        float s = q0.x * k0.x + q0.y * k0.y + q0.z * k0.z + q0.w * k0.w
                + q1.x * k1.x + q1.y * k1.y + q1.z * k1.z + q1.w * k1.w
                + q2.x * k2.x + q2.y * k2.y + q2.z * k2.z + q2.w * k2.w
                + q3.x * k3.x + q3.y * k3.y + q3.z * k3.z + q3.w * k3.w;
        s *= 0.25f;                                  // 1/sqrt(HD)
        float mn = fmaxf(mx, s);
        float corr = __expf(mx - mn);                // first iter: exp(-inf)=0, safe
        float p = __expf(s - mn);
        sum = sum * corr + p;
        const float* vp = Vb + (size_t)j * Dd;
        float4 v0 = *(const float4*)(vp);
        float4 v1 = *(const float4*)(vp + 4);
        float4 v2 = *(const float4*)(vp + 8);
        float4 v3 = *(const float4*)(vp + 12);
        acc[0]  = acc[0]  * corr + p * v0.x;  acc[1]  = acc[1]  * corr + p * v0.y;
        acc[2]  = acc[2]  * corr + p * v0.z;  acc[3]  = acc[3]  * corr + p * v0.w;
        acc[4]  = acc[4]  * corr + p * v1.x;  acc[5]  = acc[5]  * corr + p * v1.y;
        acc[6]  = acc[6]  * corr + p * v1.z;  acc[7]  = acc[7]  * corr + p * v1.w;
        acc[8]  = acc[8]  * corr + p * v2.x;  acc[9]  = acc[9]  * corr + p * v2.y;
        acc[10] = acc[10] * corr + p * v2.z;  acc[11] = acc[11] * corr + p * v2.w;
        acc[12] = acc[12] * corr + p * v3.x;  acc[13] = acc[13] * corr + p * v3.y;
        acc[14] = acc[14] * corr + p * v3.z;  acc[15] = acc[15] * corr + p * v3.w;
        mx = mn;
    }
    // butterfly merge of online-softmax states across 64 lanes
    #pragma unroll
    for (int off = 32; off; off >>= 1) {
        float m_o = __shfl_xor(mx, off);
        float s_o = __shfl_xor(sum, off);
        float ao[16];
        #pragma unroll
        for (int i = 0; i < 16; i++) ao[i] = __shfl_xor(acc[i], off);
        float mn = fmaxf(mx, m_o);
        float ca = (sum > 0.f) ? __expf(mx - mn) : 0.f;
        float co = (s_o > 0.f) ? __expf(m_o - mn) : 0.f;
        sum = sum * ca + s_o * co;
        #pragma unroll
        for (int i = 0; i < 16; i++) acc[i] = acc[i] * ca + ao[i] * co;
        mx = mn;
    }
    if (lane == 0) {
        float inv = 1.f / sum;
        float* op = O + (size_t)(b * Mm + m) * Dd + h * HDd;
        #pragma unroll
        for (int i = 0; i < 16; i++) op[i] = acc[i] * inv;
    }
}

// ---------------- logits (V=32) + log_softmax + NLL accumulation ----------------
__global__ __launch_bounds__(256) void logits_loss_kernel(const float* __restrict__ X,
                                                          const float* __restrict__ Wo,
                                                          const float* __restrict__ bo,
                                                          const int* __restrict__ targets,
                                                          float* __restrict__ logits,
                                                          double* __restrict__ lossAcc) {
    int wave = threadIdx.x >> 6, lane = threadIdx.x & 63;
    int row = blockIdx.x * 4 + wave;
    int l = lane & 31;                              // lanes 32..63 duplicate group 0..31
    const float* xr = X + (size_t)row * 128;
    const float* wr = Wo + (size_t)l * 128;
    float acc = 0.f;
    for (int k = 0; k < 128; k += 4) {
        float4 x4 = *(const float4*)(xr + k);
        float4 w4 = *(const float4*)(wr + k);
        acc += x4.x * w4.x + x4.y * w4.y + x4.z * w4.z + x4.w * w4.w;
    }
    float logit = acc + bo[l];
    if (lane < 32) logits[(size_t)row * 32 + lane] = logit;
    float mx = logit;
    #pragma unroll
    for (int off = 16; off; off >>= 1) mx = fmaxf(mx, __shfl_xor(mx, off, 32));
    float e = __expf(logit - mx);
    float se = e;
    #pragma unroll
    for (int off = 16; off; off >>= 1) se += __shfl_xor(se, off, 32);
    int tgt = targets[row];
    float lt = __shfl(logit, tgt, 32);
    if (lane == 0) {
        float nll = logf(se) + mx - lt;
        atomicAdd(lossAcc, (double)nll);
    }
}

__global__ void loss_finalize_kernel(const double* __restrict__ lossAcc,
                                     float* __restrict__ out) {
    out[0] = (float)(lossAcc[0] * (1.0 / (double)BM));
}

extern "C" void kernel_launch(void* const* d_in, const int* in_sizes, int n_in,
                              void* d_out, int out_size, void* d_ws, size_t ws_size,
                              hipStream_t stream) {
    const int*   idx       = (const int*)d_in[0];
    const int*   targets   = (const int*)d_in[1];
    const float* emb       = (const float*)d_in[2];
    const float* rms_scale = (const float*)d_in[3];
    const float* Wq        = (const float*)d_in[4];
    const float* Wk        = (const float*)d_in[5];
    const float* Wv        = (const float*)d_in[6];
    const float* in_w      = (const float*)d_in[7];
    const float* in_b      = (const float*)d_in[8];
    const float* out_pw    = (const float*)d_in[9];
    const float* out_pb    = (const float*)d_in[10];
    const float* lin_w     = (const float*)d_in[11];
    const float* lin_b     = (const float*)d_in[12];
    const float* out_w     = (const float*)d_in[13];
    const float* out_b     = (const float*)d_in[14];
    float* out = (float*)d_out;

    float* ws   = (float*)d_ws;
    float* buf0 = ws;                // x gather / attn O
    float* buf1 = ws + (size_t)NEL;  // x_norm (residual 1)
    float* buf2 = ws + (size_t)2*NEL; // Q -> qp -> x_res
    float* buf3 = ws + (size_t)3*NEL; // K -> kp -> x2
    float* buf4 = ws + (size_t)4*NEL; // V -> vp -> ffn out
    float* cosT = ws + (size_t)5*NEL;
    float* sinT = cosT + Mm*64;
    float* accs = sinT + Mm*64;      // ssq[8], ssq2[8]
    double* lossAcc = (double*)(accs + 16);

    hipMemsetAsync(accs, 0, 16*sizeof(float) + sizeof(double), stream);

    rope_table_kernel<<<Mm*64/256, 256, 0, stream>>>(cosT, sinT);
    gather_sumsq_kernel<<<NEL/256, 256, 0, stream>>>(idx, emb, buf0, accs);
    normscale_kernel<<<NEL/256, 256, 0, stream>>>(buf0, rms_scale, accs, buf1);

    gemm128_kernel<<<BM/8, 128, 0, stream>>>(buf1, Wq, nullptr, nullptr, buf2, 0);
    gemm128_kernel<<<BM/8, 128, 0, stream>>>(buf1, Wk, nullptr, nullptr, buf3, 0);
    gemm128_kernel<<<BM/8, 128, 0, stream>>>(buf1, Wv, nullptr, nullptr, buf4, 0);

    rope_kernel<<<BM*64/256, 256, 0, stream>>>(buf2, cosT, sinT);
    rope_kernel<<<BM*64/256, 256, 0, stream>>>(buf3, cosT, sinT);
    rope_kernel<<<BM*64/256, 256, 0, stream>>>(buf4, cosT, sinT);

    gemm128_kernel<<<BM/8, 128, 0, stream>>>(buf2, in_w,            in_b,       nullptr, buf2, 0);
    gemm128_kernel<<<BM/8, 128, 0, stream>>>(buf3, in_w + Dd*Dd,    in_b + Dd,  nullptr, buf3, 0);
    gemm128_kernel<<<BM/8, 128, 0, stream>>>(buf4, in_w + 2*Dd*Dd,  in_b + 2*Dd, nullptr, buf4, 0);

    attn_kernel<<<Bb*Hh*Mm/4, 256, 0, stream>>>(buf2, buf3, buf4, buf0);

    gemm128_kernel<<<BM/8, 128, 0, stream>>>(buf0, out_pw, out_pb, buf1, buf2, 0);

    sumsq_kernel<<<NEL/256, 256, 0, stream>>>(buf2, accs + 8);
    normscale_kernel<<<NEL/256, 256, 0, stream>>>(buf2, rms_scale, accs + 8, buf3);

    gemm128_kernel<<<BM/8, 128, 0, stream>>>(buf3, lin_w, lin_b, buf3, buf4, 1);

    logits_loss_kernel<<<BM/4, 256, 0, stream>>>(buf4, out_w, out_b, targets, out, lossAcc);
    loss_finalize_kernel<<<1, 1, 0, stream>>>(lossAcc, out + (size_t)BM*Vv);
}

// Round 2
// 934.257 us; speedup vs baseline: 2.8860x; 2.8860x over previous
//
#include <hip/hip_runtime.h>
#include <hip/hip_bf16.h>
#include <math.h>

#define Vv   32
#define Dd   128
#define Hh   8
#define HDd  16
#define Bb   8
#define Mm   2048
#define BM   (Bb*Mm)        // 16384
#define NEL  (BM*Dd)        // 2097152 floats = 8 MB

typedef _Float16 half4_t __attribute__((ext_vector_type(4)));
typedef float    float4_t __attribute__((ext_vector_type(4)));

// ---------------- RoPE tables: cos/sin[m][i], i in [0,64) ----------------
__global__ __launch_bounds__(256) void rope_table_kernel(float* __restrict__ cosT,
                                                         float* __restrict__ sinT) {
    int gid = blockIdx.x * 256 + threadIdx.x;       // Mm*64 total
    int i = gid & 63;
    int m = gid >> 6;
    float ex = -2.0f * ((float)i - 1.0f) / 128.0f;
    float base = expf(ex * 9.210340371976184f);     // ln(10000)
    float ang = (float)m * base;
    cosT[gid] = cosf(ang);
    sinT[gid] = sinf(ang);
}

// ---------------- embedding gather + per-batch sum of squares ----------------
__global__ __launch_bounds__(256) void gather_sumsq_kernel(const int* __restrict__ idx,
                                                           const float* __restrict__ emb,
                                                           float* __restrict__ X,
                                                           float* __restrict__ ssq) {
    int gid = blockIdx.x * 256 + threadIdx.x;       // NEL total
    int d = gid & 127;
    int token = gid >> 7;
    float x = emb[idx[token] * Dd + d];
    X[gid] = x;
    float v = x * x;
    #pragma unroll
    for (int off = 32; off; off >>= 1) v += __shfl_xor(v, off);
    __shared__ float wsum[4];
    int lane = threadIdx.x & 63, wave = threadIdx.x >> 6;
    if (lane == 0) wsum[wave] = v;
    __syncthreads();
    if (threadIdx.x == 0) atomicAdd(&ssq[gid >> 18], wsum[0] + wsum[1] + wsum[2] + wsum[3]);
}

// ---------------- per-batch sum of squares ----------------
__global__ __launch_bounds__(256) void sumsq_kernel(const float* __restrict__ X,
                                                    float* __restrict__ ssq) {
    int gid = blockIdx.x * 256 + threadIdx.x;
    float x = X[gid];
    float v = x * x;
    #pragma unroll
    for (int off = 32; off; off >>= 1) v += __shfl_xor(v, off);
    __shared__ float wsum[4];
    int lane = threadIdx.x & 63, wave = threadIdx.x >> 6;
    if (lane == 0) wsum[wave] = v;
    __syncthreads();
    if (threadIdx.x == 0) atomicAdd(&ssq[gid >> 18], wsum[0] + wsum[1] + wsum[2] + wsum[3]);
}

// ---------------- x * (sqrt(M*D)/sqrt(ssq[b])) * scale[m,d] ----------------
__global__ __launch_bounds__(256) void normscale_kernel(const float* __restrict__ X,
                                                        const float* __restrict__ scale,
                                                        const float* __restrict__ ssq,
                                                        float* __restrict__ out) {
    int gid = blockIdx.x * 256 + threadIdx.x;
    int b = gid >> 18;
    int md = gid & ((Mm * Dd) - 1);
    float inv = 512.0f / sqrtf(ssq[b]);
    out[gid] = X[gid] * inv * scale[md];
}

// ---------------- row GEMM: out = A @ W^T (+bias)(relu?)(+resid); optional f16 output ----------------
__global__ __launch_bounds__(128) void gemm128_kernel(const float* __restrict__ A,
                                                      const float* __restrict__ W,
                                                      const float* __restrict__ bias,
                                                      const float* __restrict__ resid,
                                                      float* __restrict__ out,
                                                      _Float16* __restrict__ out_h,
                                                      int relu) {
    __shared__ float As[8][128];
    int r0 = blockIdx.x * 8;
    int c = threadIdx.x;
    #pragma unroll
    for (int r = 0; r < 8; r++) As[r][c] = A[(size_t)(r0 + r) * 128 + c];
    __syncthreads();
    float acc[8];
    #pragma unroll
    for (int r = 0; r < 8; r++) acc[r] = 0.f;
    const float* wr = W + (size_t)c * 128;
    for (int k = 0; k < 128; k += 4) {
        float4 w4 = *(const float4*)(wr + k);
        #pragma unroll
        for (int r = 0; r < 8; r++) {
            acc[r] += As[r][k] * w4.x + As[r][k + 1] * w4.y + As[r][k + 2] * w4.z + As[r][k + 3] * w4.w;
        }
    }
    float bv = bias ? bias[c] : 0.f;
    #pragma unroll
    for (int r = 0; r < 8; r++) {
        float v = acc[r] + bv;
        if (relu) v = fmaxf(v, 0.f);
        if (resid) v += resid[(size_t)(r0 + r) * 128 + c];
        if (out_h) out_h[(size_t)(r0 + r) * 128 + c] = (_Float16)v;
        else       out[(size_t)(r0 + r) * 128 + c] = v;
    }
}

// ---------------- in-place RoPE ----------------
__global__ __launch_bounds__(256) void rope_kernel(float* __restrict__ T,
                                                   const float* __restrict__ cosT,
                                                   const float* __restrict__ sinT) {
    int gid = blockIdx.x * 256 + threadIdx.x;       // B*M*64 total
    int i = gid & 63;
    int token = gid >> 6;
    int m = token & (Mm - 1);
    float c = cosT[m * 64 + i], s = sinT[m * 64 + i];
    float2* p = (float2*)(T + (size_t)token * Dd) + i;
    float2 eo = *p;
    float2 r;
    r.x = eo.x * c + eo.y * s;
    r.y = -eo.x * s + eo.y * c;
    *p = r;
}

// ---------------- vp (fp32 [b,m,h*16+d]) -> Vt (f16 [b,h,d,m]) via LDS transpose ----------------
// block: one (b,h), 64 m-rows x 16 d.  grid = B*H*(M/64) = 2048
__global__ __launch_bounds__(256) void vtrans_kernel(const float* __restrict__ vp,
                                                     _Float16* __restrict__ Vt) {
    __shared__ float tile[16][68];
    int blk = blockIdx.x;
    int mt = blk & (Mm / 64 - 1);       // 0..31
    int bh = blk >> 5;                  // 0..63
    int b = bh >> 3, h = bh & 7;
    int m0 = mt * 64;
    int t = threadIdx.x;
    {
        int ml = t >> 2;                // 0..63
        int dq = (t & 3) * 4;           // 0,4,8,12
        float4 v = *(const float4*)(vp + (size_t)(b * Mm + m0 + ml) * 128 + h * 16 + dq);
        tile[dq + 0][ml] = v.x;
        tile[dq + 1][ml] = v.y;
        tile[dq + 2][ml] = v.z;
        tile[dq + 3][ml] = v.w;
    }
    __syncthreads();
    {
        int d = t >> 4;                 // 0..15
        int mq = (t & 15) * 4;          // 0..60
        half4_t o;
        o[0] = (_Float16)tile[d][mq + 0];
        o[1] = (_Float16)tile[d][mq + 1];
        o[2] = (_Float16)tile[d][mq + 2];
        o[3] = (_Float16)tile[d][mq + 3];
        *(half4_t*)(Vt + (size_t)(bh * 16 + d) * Mm + m0 + mq) = o;
    }
}

// ---------------- MFMA flash attention ----------------
// one wave per 16-row q-tile; S^T = K@Q^T so P^T's C-layout IS P's A-layout for P@V.
__global__ __launch_bounds__(256) void attn_mfma_kernel(const _Float16* __restrict__ Qh,
                                                        const _Float16* __restrict__ Kh,
                                                        const _Float16* __restrict__ Vt,
                                                        float* __restrict__ O) {
    int wid = blockIdx.x * 4 + (threadIdx.x >> 6);  // 0..8191
    int lane = threadIdx.x & 63;
    int qt = wid & 127;
    int bh = wid >> 7;
    int b = bh >> 3, h = bh & 7;
    int q0 = qt * 16;
    int r = lane & 15;
    int c = lane >> 4;                               // 0..3

    // Q frag (B operand of S^T): Q[q0+r][4c+j]
    half4_t qf = *(const half4_t*)(Qh + (size_t)(b * Mm + q0 + r) * 128 + h * 16 + 4 * c);
    const _Float16* Kbase = Kh + (size_t)b * Mm * 128 + h * 16 + 4 * c;
    const _Float16* Vbase = Vt + (size_t)(bh * 16 + r) * Mm + 4 * c;

    float4_t o = {0.f, 0.f, 0.f, 0.f};
    float4_t zero = {0.f, 0.f, 0.f, 0.f};
    float lsum = 0.f;

    for (int kt = 0; kt < qt; kt++) {                // full tiles, no mask
        half4_t kf = *(const half4_t*)(Kbase + (size_t)(kt * 16 + r) * 128);
        half4_t vf = *(const half4_t*)(Vbase + kt * 16);
        float4_t st = __builtin_amdgcn_mfma_f32_16x16x16f16(kf, qf, zero, 0, 0, 0);
        float p0 = __expf(st[0] * 0.25f);
        float p1 = __expf(st[1] * 0.25f);
        float p2 = __expf(st[2] * 0.25f);
        float p3 = __expf(st[3] * 0.25f);
        lsum += (p0 + p1) + (p2 + p3);
        half4_t pf;
        pf[0] = (_Float16)p0; pf[1] = (_Float16)p1;
        pf[2] = (_Float16)p2; pf[3] = (_Float16)p3;
        o = __builtin_amdgcn_mfma_f32_16x16x16f16(pf, vf, o, 0, 0, 0);
    }
    {   // diagonal tile kt == qt: key_local = 4c+reg valid iff <= r
        half4_t kf = *(const half4_t*)(Kbase + (size_t)(qt * 16 + r) * 128);
        half4_t vf = *(const half4_t*)(Vbase + qt * 16);
        float4_t st = __builtin_amdgcn_mfma_f32_16x16x16f16(kf, qf, zero, 0, 0, 0);
        float p0 = (4 * c + 0 <= r) ? __expf(st[0] * 0.25f) : 0.f;
        float p1 = (4 * c + 1 <= r) ? __expf(st[1] * 0.25f) : 0.f;
        float p2 = (4 * c + 2 <= r) ? __expf(st[2] * 0.25f) : 0.f;
        float p3 = (4 * c + 3 <= r) ? __expf(st[3] * 0.25f) : 0.f;
        lsum += (p0 + p1) + (p2 + p3);
        half4_t pf;
        pf[0] = (_Float16)p0; pf[1] = (_Float16)p1;
        pf[2] = (_Float16)p2; pf[3] = (_Float16)p3;
        o = __builtin_amdgcn_mfma_f32_16x16x16f16(pf, vf, o, 0, 0, 0);
    }
    // denominator: lane holds partial for q=r over keys {4c..4c+3} mod 16 -> reduce over c
    lsum += __shfl_xor(lsum, 16);
    lsum += __shfl_xor(lsum, 32);
    // O C-layout: lane holds O[q = 4c+reg][d = r]
    #pragma unroll
    for (int reg = 0; reg < 4; reg++) {
        float lt = __shfl(lsum, 4 * c + reg);        // total for q-row 4c+reg
        O[(size_t)(b * Mm + q0 + 4 * c + reg) * 128 + h * 16 + r] = o[reg] / lt;
    }
}

// ---------------- logits (V=32) + log_softmax + NLL ----------------
__global__ __launch_bounds__(256) void logits_loss_kernel(const float* __restrict__ X,
                                                          const float* __restrict__ Wo,
                                                          const float* __restrict__ bo,
                                                          const int* __restrict__ targets,
                                                          float* __restrict__ logits,
                                                          double* __restrict__ lossAcc) {
    int wave = threadIdx.x >> 6, lane = threadIdx.x & 63;
    int row = blockIdx.x * 4 + wave;
    int l = lane & 31;
    const float* xr = X + (size_t)row * 128;
    const float* wr = Wo + (size_t)l * 128;
    float acc = 0.f;
    for (int k = 0; k < 128; k += 4) {
        float4 x4 = *(const float4*)(xr + k);
        float4 w4 = *(const float4*)(wr + k);
        acc += x4.x * w4.x + x4.y * w4.y + x4.z * w4.z + x4.w * w4.w;
    }
    float logit = acc + bo[l];
    if (lane < 32) logits[(size_t)row * 32 + lane] = logit;
    float mx = logit;
    #pragma unroll
    for (int off = 16; off; off >>= 1) mx = fmaxf(mx, __shfl_xor(mx, off, 32));
    float e = __expf(logit - mx);
    float se = e;
    #pragma unroll
    for (int off = 16; off; off >>= 1) se += __shfl_xor(se, off, 32);
    int tgt = targets[row];
    float lt = __shfl(logit, tgt, 32);
    if (lane == 0) {
        float nll = logf(se) + mx - lt;
        atomicAdd(lossAcc, (double)nll);
    }
}

__global__ void loss_finalize_kernel(const double* __restrict__ lossAcc,
                                     float* __restrict__ out) {
    out[0] = (float)(lossAcc[0] * (1.0 / (double)BM));
}

extern "C" void kernel_launch(void* const* d_in, const int* in_sizes, int n_in,
                              void* d_out, int out_size, void* d_ws, size_t ws_size,
                              hipStream_t stream) {
    const int*   idx       = (const int*)d_in[0];
    const int*   targets   = (const int*)d_in[1];
    const float* emb       = (const float*)d_in[2];
    const float* rms_scale = (const float*)d_in[3];
    const float* Wq        = (const float*)d_in[4];
    const float* Wk        = (const float*)d_in[5];
    const float* Wv        = (const float*)d_in[6];
    const float* in_w      = (const float*)d_in[7];
    const float* in_b      = (const float*)d_in[8];
    const float* out_pw    = (const float*)d_in[9];
    const float* out_pb    = (const float*)d_in[10];
    const float* lin_w     = (const float*)d_in[11];
    const float* lin_b     = (const float*)d_in[12];
    const float* out_w     = (const float*)d_in[13];
    const float* out_b     = (const float*)d_in[14];
    float* out = (float*)d_out;

    float* ws   = (float*)d_ws;
    float* buf0 = ws;                 // x gather -> free -> Qh/Kh (f16)
    float* buf1 = ws + (size_t)NEL;   // x_norm (residual 1) -> x2_norm
    float* buf2 = ws + (size_t)2*NEL; // Q rope -> attn O -> logits input
    float* buf3 = ws + (size_t)3*NEL; // K rope -> Vt (f16, first half)
    float* buf4 = ws + (size_t)4*NEL; // V rope -> vp -> x_res
    float* cosT = ws + (size_t)5*NEL;
    float* sinT = cosT + Mm*64;
    float* accs = sinT + Mm*64;       // ssq[8], ssq2[8]
    double* lossAcc = (double*)(accs + 16);

    _Float16* Qh = (_Float16*)buf0;
    _Float16* Kh = Qh + (size_t)NEL;  // second half of buf0
    _Float16* Vt = (_Float16*)buf3;

    hipMemsetAsync(accs, 0, 16*sizeof(float) + sizeof(double), stream);

    rope_table_kernel<<<Mm*64/256, 256, 0, stream>>>(cosT, sinT);
    gather_sumsq_kernel<<<NEL/256, 256, 0, stream>>>(idx, emb, buf2, accs);
    normscale_kernel<<<NEL/256, 256, 0, stream>>>(buf2, rms_scale, accs, buf1);

    // QKV projections (fp32)
    gemm128_kernel<<<BM/8, 128, 0, stream>>>(buf1, Wq, nullptr, nullptr, buf2, nullptr, 0);
    gemm128_kernel<<<BM/8, 128, 0, stream>>>(buf1, Wk, nullptr, nullptr, buf3, nullptr, 0);
    gemm128_kernel<<<BM/8, 128, 0, stream>>>(buf1, Wv, nullptr, nullptr, buf4, nullptr, 0);

    rope_kernel<<<BM*64/256, 256, 0, stream>>>(buf2, cosT, sinT);
    rope_kernel<<<BM*64/256, 256, 0, stream>>>(buf3, cosT, sinT);
    rope_kernel<<<BM*64/256, 256, 0, stream>>>(buf4, cosT, sinT);

    // in_proj: Q,K -> f16 directly; V -> fp32 (in-place) then transpose to f16
    gemm128_kernel<<<BM/8, 128, 0, stream>>>(buf2, in_w,           in_b,        nullptr, nullptr, Qh, 0);
    gemm128_kernel<<<BM/8, 128, 0, stream>>>(buf3, in_w + Dd*Dd,   in_b + Dd,   nullptr, nullptr, Kh, 0);
    gemm128_kernel<<<BM/8, 128, 0, stream>>>(buf4, in_w + 2*Dd*Dd, in_b + 2*Dd, nullptr, buf4, nullptr, 0);

    vtrans_kernel<<<Bb*Hh*(Mm/64), 256, 0, stream>>>(buf4, Vt);

    attn_mfma_kernel<<<Bb*Hh*(Mm/16)/4, 256, 0, stream>>>(Qh, Kh, Vt, buf2);

    // out_proj + residual(x_norm)
    gemm128_kernel<<<BM/8, 128, 0, stream>>>(buf2, out_pw, out_pb, buf1, buf4, nullptr, 0);

    sumsq_kernel<<<NEL/256, 256, 0, stream>>>(buf4, accs + 8);
    normscale_kernel<<<NEL/256, 256, 0, stream>>>(buf4, rms_scale, accs + 8, buf1);

    // FFN: x_res + relu(x2norm @ lin_w^T + b)
    gemm128_kernel<<<BM/8, 128, 0, stream>>>(buf1, lin_w, lin_b, buf4, buf2, nullptr, 1);

    logits_loss_kernel<<<BM/4, 256, 0, stream>>>(buf2, out_w, out_b, targets, out, lossAcc);
    loss_finalize_kernel<<<1, 1, 0, stream>>>(lossAcc, out + (size_t)BM*Vv);
}

// Round 3
// 821.986 us; speedup vs baseline: 3.2802x; 1.1366x over previous
//
#include <hip/hip_runtime.h>
#include <hip/hip_bf16.h>
#include <math.h>

#define Vv   32
#define Dd   128
#define Hh   8
#define HDd  16
#define Bb   8
#define Mm   2048
#define BM   (Bb*Mm)        // 16384
#define NEL  (BM*Dd)        // 2097152 floats = 8 MB

typedef _Float16 half4_t __attribute__((ext_vector_type(4)));
typedef float    float4_t __attribute__((ext_vector_type(4)));

// ---------------- RoPE tables: cos/sin[m][i], i in [0,64) ----------------
__global__ __launch_bounds__(256) void rope_table_kernel(float* __restrict__ cosT,
                                                         float* __restrict__ sinT) {
    int gid = blockIdx.x * 256 + threadIdx.x;       // Mm*64 total
    int i = gid & 63;
    int m = gid >> 6;
    float ex = -2.0f * ((float)i - 1.0f) / 128.0f;
    float base = expf(ex * 9.210340371976184f);     // ln(10000)
    float ang = (float)m * base;
    cosT[gid] = cosf(ang);
    sinT[gid] = sinf(ang);
}

// ---------------- convert 8 weight matrices (128x128 f32) to f16 ----------------
// layout: 0=Wq 1=Wk 2=Wv 3=in_w_q 4=in_w_k 5=in_w_v 6=out_pw 7=lin_w
__global__ __launch_bounds__(256) void wcvt_kernel(const float* __restrict__ Wq,
                                                   const float* __restrict__ Wk,
                                                   const float* __restrict__ Wv,
                                                   const float* __restrict__ in_w,
                                                   const float* __restrict__ out_pw,
                                                   const float* __restrict__ lin_w,
                                                   _Float16* __restrict__ Wh) {
    int gid = blockIdx.x * 256 + threadIdx.x;       // 131072 total
    int seg = gid >> 14, off = gid & 16383;
    const float* src =
        seg == 0 ? Wq : seg == 1 ? Wk : seg == 2 ? Wv :
        seg < 6 ? in_w + (size_t)(seg - 3) * 16384 :
        seg == 6 ? out_pw : lin_w;
    Wh[gid] = (_Float16)src[off];
}

// ---------------- embedding gather + per-batch sum of squares ----------------
__global__ __launch_bounds__(256) void gather_sumsq_kernel(const int* __restrict__ idx,
                                                           const float* __restrict__ emb,
                                                           float* __restrict__ X,
                                                           float* __restrict__ ssq) {
    int gid = blockIdx.x * 256 + threadIdx.x;       // NEL total
    int d = gid & 127;
    int token = gid >> 7;
    float x = emb[idx[token] * Dd + d];
    X[gid] = x;
    float v = x * x;
    #pragma unroll
    for (int off = 32; off; off >>= 1) v += __shfl_xor(v, off);
    __shared__ float wsum[4];
    int lane = threadIdx.x & 63, wave = threadIdx.x >> 6;
    if (lane == 0) wsum[wave] = v;
    __syncthreads();
    if (threadIdx.x == 0) atomicAdd(&ssq[gid >> 18], wsum[0] + wsum[1] + wsum[2] + wsum[3]);
}

// ---------------- x * (512/sqrt(ssq[b])) * scale[m,d] ----------------
__global__ __launch_bounds__(256) void normscale_kernel(const float* __restrict__ X,
                                                        const float* __restrict__ scale,
                                                        const float* __restrict__ ssq,
                                                        float* __restrict__ out) {
    int gid = blockIdx.x * 256 + threadIdx.x;
    int b = gid >> 18;
    int md = gid & ((Mm * Dd) - 1);
    float inv = 512.0f / sqrtf(ssq[b]);
    out[gid] = X[gid] * inv * scale[md];
}

// ---------------- MFMA GEMM: out[16384x128] = A f32 @ Wh^T f16, fused epilogue ----------------
// block 256 = 4 waves. wave w: rows row0 = blk*32 + (w&1)*16, cols n0 = (w>>1)*64.
// per wave: 8 k-steps x 4 col-tiles of 16x16x16 MFMA.
// epilogue options: +bias, relu, +resid, rope (needs cosT/sinT), f32 out, f16 out, ssq atomic.
__global__ __launch_bounds__(256) void gemm_mfma_kernel(const float* __restrict__ A,
                                                        const _Float16* __restrict__ Wh,
                                                        const float* __restrict__ bias,
                                                        const float* __restrict__ resid,
                                                        const float* __restrict__ cosT,
                                                        const float* __restrict__ sinT,
                                                        float* __restrict__ out,
                                                        _Float16* __restrict__ out_h,
                                                        float* __restrict__ ssq,
                                                        int relu) {
    int wave = threadIdx.x >> 6, lane = threadIdx.x & 63;
    int r = lane & 15, c = lane >> 4;
    int row0 = blockIdx.x * 32 + (wave & 1) * 16;
    int n0 = (wave >> 1) * 64;
    float4_t acc[4];
    #pragma unroll
    for (int t = 0; t < 4; t++) acc[t] = (float4_t){0.f, 0.f, 0.f, 0.f};
    #pragma unroll
    for (int kk = 0; kk < 8; kk++) {
        float4 a4 = *(const float4*)(A + (size_t)(row0 + r) * 128 + kk * 16 + 4 * c);
        half4_t af;
        af[0] = (_Float16)a4.x; af[1] = (_Float16)a4.y;
        af[2] = (_Float16)a4.z; af[3] = (_Float16)a4.w;
        #pragma unroll
        for (int t = 0; t < 4; t++) {
            half4_t wf = *(const half4_t*)(Wh + (size_t)(n0 + t * 16 + r) * 128 + kk * 16 + 4 * c);
            acc[t] = __builtin_amdgcn_mfma_f32_16x16x16f16(af, wf, acc[t], 0, 0, 0);
        }
    }
    float lssq = 0.f;
    #pragma unroll
    for (int t = 0; t < 4; t++) {
        int n = n0 + t * 16 + r;
        float bv = bias ? bias[n] : 0.f;
        #pragma unroll
        for (int reg = 0; reg < 4; reg++) {
            int row = row0 + 4 * c + reg;
            float v = acc[t][reg] + bv;
            if (relu) v = fmaxf(v, 0.f);
            if (resid) v += resid[(size_t)row * 128 + n];
            if (cosT) {  // fused RoPE: pair column n^1 lives in lane^1
                float vp = __shfl_xor(v, 1);
                int m = row & (Mm - 1);
                float cs = cosT[m * 64 + (n >> 1)];
                float sn = sinT[m * 64 + (n >> 1)];
                v = (n & 1) ? (-vp * sn + v * cs) : (v * cs + vp * sn);
            }
            if (ssq) lssq += v * v;
            if (out_h) out_h[(size_t)row * 128 + n] = (_Float16)v;
            if (out)   out[(size_t)row * 128 + n] = v;
        }
    }
    if (ssq) {
        #pragma unroll
        for (int off = 32; off; off >>= 1) lssq += __shfl_xor(lssq, off);
        if (lane == 0) atomicAdd(&ssq[row0 >> 11], lssq);
    }
}

// ---------------- vp (fp32 [b,m,h*16+d]) -> Vt (f16 [b,h,d,m]) via LDS transpose ----------------
__global__ __launch_bounds__(256) void vtrans_kernel(const float* __restrict__ vp,
                                                     _Float16* __restrict__ Vt) {
    __shared__ float tile[16][68];
    int blk = blockIdx.x;
    int mt = blk & (Mm / 64 - 1);
    int bh = blk >> 5;
    int b = bh >> 3, h = bh & 7;
    int m0 = mt * 64;
    int t = threadIdx.x;
    {
        int ml = t >> 2;
        int dq = (t & 3) * 4;
        float4 v = *(const float4*)(vp + (size_t)(b * Mm + m0 + ml) * 128 + h * 16 + dq);
        tile[dq + 0][ml] = v.x;
        tile[dq + 1][ml] = v.y;
        tile[dq + 2][ml] = v.z;
        tile[dq + 3][ml] = v.w;
    }
    __syncthreads();
    {
        int d = t >> 4;
        int mq = (t & 15) * 4;
        half4_t o;
        o[0] = (_Float16)tile[d][mq + 0];
        o[1] = (_Float16)tile[d][mq + 1];
        o[2] = (_Float16)tile[d][mq + 2];
        o[3] = (_Float16)tile[d][mq + 3];
        *(half4_t*)(Vt + (size_t)(bh * 16 + d) * Mm + m0 + mq) = o;
    }
}

// ---------------- MFMA flash attention, 4-tile unrolled ----------------
__global__ __launch_bounds__(256) void attn_mfma_kernel(const _Float16* __restrict__ Qh,
                                                        const _Float16* __restrict__ Kh,
                                                        const _Float16* __restrict__ Vt,
                                                        float* __restrict__ O) {
    int wid = blockIdx.x * 4 + (threadIdx.x >> 6);
    int lane = threadIdx.x & 63;
    int qt = 127 - (wid & 127);                     // heavy tiles dispatch first
    int bh = wid >> 7;
    int b = bh >> 3, h = bh & 7;
    int q0 = qt * 16;
    int r = lane & 15;
    int c = lane >> 4;

    half4_t qf = *(const half4_t*)(Qh + (size_t)(b * Mm + q0 + r) * 128 + h * 16 + 4 * c);
    const _Float16* Kbase = Kh + (size_t)b * Mm * 128 + (size_t)r * 128 + h * 16 + 4 * c;
    const _Float16* Vbase = Vt + (size_t)(bh * 16 + r) * Mm + 4 * c;

    float4_t o0 = {0.f, 0.f, 0.f, 0.f}, o1 = {0.f, 0.f, 0.f, 0.f};
    float4_t zero = {0.f, 0.f, 0.f, 0.f};
    float lsum = 0.f;

    int kt = 0;
    for (; kt + 4 <= qt; kt += 4) {
        half4_t kf[4], vf[4];
        #pragma unroll
        for (int u = 0; u < 4; u++) {
            kf[u] = *(const half4_t*)(Kbase + (size_t)(kt + u) * 2048);
            vf[u] = *(const half4_t*)(Vbase + (kt + u) * 16);
        }
        float4_t st[4];
        #pragma unroll
        for (int u = 0; u < 4; u++)
            st[u] = __builtin_amdgcn_mfma_f32_16x16x16f16(kf[u], qf, zero, 0, 0, 0);
        half4_t pf[4];
        #pragma unroll
        for (int u = 0; u < 4; u++) {
            float p0 = __expf(st[u][0] * 0.25f);
            float p1 = __expf(st[u][1] * 0.25f);
            float p2 = __expf(st[u][2] * 0.25f);
            float p3 = __expf(st[u][3] * 0.25f);
            lsum += (p0 + p1) + (p2 + p3);
            pf[u][0] = (_Float16)p0; pf[u][1] = (_Float16)p1;
            pf[u][2] = (_Float16)p2; pf[u][3] = (_Float16)p3;
        }
        o0 = __builtin_amdgcn_mfma_f32_16x16x16f16(pf[0], vf[0], o0, 0, 0, 0);
        o1 = __builtin_amdgcn_mfma_f32_16x16x16f16(pf[1], vf[1], o1, 0, 0, 0);
        o0 = __builtin_amdgcn_mfma_f32_16x16x16f16(pf[2], vf[2], o0, 0, 0, 0);
        o1 = __builtin_amdgcn_mfma_f32_16x16x16f16(pf[3], vf[3], o1, 0, 0, 0);
    }
    for (; kt < qt; kt++) {
        half4_t kf = *(const half4_t*)(Kbase + (size_t)kt * 2048);
        half4_t vf = *(const half4_t*)(Vbase + kt * 16);
        float4_t st = __builtin_amdgcn_mfma_f32_16x16x16f16(kf, qf, zero, 0, 0, 0);
        float p0 = __expf(st[0] * 0.25f);
        float p1 = __expf(st[1] * 0.25f);
        float p2 = __expf(st[2] * 0.25f);
        float p3 = __expf(st[3] * 0.25f);
        lsum += (p0 + p1) + (p2 + p3);
        half4_t pf;
        pf[0] = (_Float16)p0; pf[1] = (_Float16)p1;
        pf[2] = (_Float16)p2; pf[3] = (_Float16)p3;
        o0 = __builtin_amdgcn_mfma_f32_16x16x16f16(pf, vf, o0, 0, 0, 0);
    }
    {   // diagonal tile: key_local = 4c+reg valid iff <= r
        half4_t kf = *(const half4_t*)(Kbase + (size_t)qt * 2048);
        half4_t vf = *(const half4_t*)(Vbase + qt * 16);
        float4_t st = __builtin_amdgcn_mfma_f32_16x16x16f16(kf, qf, zero, 0, 0, 0);
        float p0 = (4 * c + 0 <= r) ? __expf(st[0] * 0.25f) : 0.f;
        float p1 = (4 * c + 1 <= r) ? __expf(st[1] * 0.25f) : 0.f;
        float p2 = (4 * c + 2 <= r) ? __expf(st[2] * 0.25f) : 0.f;
        float p3 = (4 * c + 3 <= r) ? __expf(st[3] * 0.25f) : 0.f;
        lsum += (p0 + p1) + (p2 + p3);
        half4_t pf;
        pf[0] = (_Float16)p0; pf[1] = (_Float16)p1;
        pf[2] = (_Float16)p2; pf[3] = (_Float16)p3;
        o1 = __builtin_amdgcn_mfma_f32_16x16x16f16(pf, vf, o1, 0, 0, 0);
    }
    float4_t o = o0 + o1;
    lsum += __shfl_xor(lsum, 16);
    lsum += __shfl_xor(lsum, 32);
    #pragma unroll
    for (int reg = 0; reg < 4; reg++) {
        float lt = __shfl(lsum, 4 * c + reg);
        O[(size_t)(b * Mm + q0 + 4 * c + reg) * 128 + h * 16 + r] = o[reg] / lt;
    }
}

// ---------------- logits (V=32) + log_softmax + NLL ----------------
__global__ __launch_bounds__(256) void logits_loss_kernel(const float* __restrict__ X,
                                                          const float* __restrict__ Wo,
                                                          const float* __restrict__ bo,
                                                          const int* __restrict__ targets,
                                                          float* __restrict__ logits,
                                                          double* __restrict__ lossAcc) {
    int wave = threadIdx.x >> 6, lane = threadIdx.x & 63;
    int row = blockIdx.x * 4 + wave;
    int l = lane & 31;
    const float* xr = X + (size_t)row * 128;
    const float* wr = Wo + (size_t)l * 128;
    float acc = 0.f;
    for (int k = 0; k < 128; k += 4) {
        float4 x4 = *(const float4*)(xr + k);
        float4 w4 = *(const float4*)(wr + k);
        acc += x4.x * w4.x + x4.y * w4.y + x4.z * w4.z + x4.w * w4.w;
    }
    float logit = acc + bo[l];
    if (lane < 32) logits[(size_t)row * 32 + lane] = logit;
    float mx = logit;
    #pragma unroll
    for (int off = 16; off; off >>= 1) mx = fmaxf(mx, __shfl_xor(mx, off, 32));
    float e = __expf(logit - mx);
    float se = e;
    #pragma unroll
    for (int off = 16; off; off >>= 1) se += __shfl_xor(se, off, 32);
    int tgt = targets[row];
    float lt = __shfl(logit, tgt, 32);
    if (lane == 0) {
        float nll = logf(se) + mx - lt;
        atomicAdd(lossAcc, (double)nll);
    }
}

__global__ void loss_finalize_kernel(const double* __restrict__ lossAcc,
                                     float* __restrict__ out) {
    out[0] = (float)(lossAcc[0] * (1.0 / (double)BM));
}

extern "C" void kernel_launch(void* const* d_in, const int* in_sizes, int n_in,
                              void* d_out, int out_size, void* d_ws, size_t ws_size,
                              hipStream_t stream) {
    const int*   idx       = (const int*)d_in[0];
    const int*   targets   = (const int*)d_in[1];
    const float* emb       = (const float*)d_in[2];
    const float* rms_scale = (const float*)d_in[3];
    const float* Wq        = (const float*)d_in[4];
    const float* Wk        = (const float*)d_in[5];
    const float* Wv        = (const float*)d_in[6];
    const float* in_w      = (const float*)d_in[7];
    const float* in_b      = (const float*)d_in[8];
    const float* out_pw    = (const float*)d_in[9];
    const float* out_pb    = (const float*)d_in[10];
    const float* lin_w     = (const float*)d_in[11];
    const float* lin_b     = (const float*)d_in[12];
    const float* out_w     = (const float*)d_in[13];
    const float* out_b     = (const float*)d_in[14];
    float* out = (float*)d_out;

    float* ws   = (float*)d_ws;
    float* buf0 = ws;                 // x gather -> Qh/Kh (f16)
    float* buf1 = ws + (size_t)NEL;   // x_norm (residual 1) -> x2_norm
    float* buf2 = ws + (size_t)2*NEL; // Q (roped) -> attn O -> ffn out
    float* buf3 = ws + (size_t)3*NEL; // K (roped) -> Vt (f16)
    float* buf4 = ws + (size_t)4*NEL; // V (roped) -> vp -> x_res
    float* cosT = ws + (size_t)5*NEL;
    float* sinT = cosT + Mm*64;
    float* accs = sinT + Mm*64;       // ssq[8], ssq2[8]
    double* lossAcc = (double*)(accs + 16);
    _Float16* Wh = (_Float16*)(accs + 32);  // 8 x 128x128 f16 = 256 KB

    _Float16* Qh = (_Float16*)buf0;
    _Float16* Kh = Qh + (size_t)NEL;
    _Float16* Vt = (_Float16*)buf3;

    hipMemsetAsync(accs, 0, 16*sizeof(float) + sizeof(double), stream);

    rope_table_kernel<<<Mm*64/256, 256, 0, stream>>>(cosT, sinT);
    wcvt_kernel<<<131072/256, 256, 0, stream>>>(Wq, Wk, Wv, in_w, out_pw, lin_w, Wh);
    gather_sumsq_kernel<<<NEL/256, 256, 0, stream>>>(idx, emb, buf2, accs);
    normscale_kernel<<<NEL/256, 256, 0, stream>>>(buf2, rms_scale, accs, buf1);

    // QKV projections with fused RoPE (fp32 out)
    gemm_mfma_kernel<<<BM/32, 256, 0, stream>>>(buf1, Wh,            nullptr, nullptr, cosT, sinT, buf2, nullptr, nullptr, 0);
    gemm_mfma_kernel<<<BM/32, 256, 0, stream>>>(buf1, Wh + 16384,    nullptr, nullptr, cosT, sinT, buf3, nullptr, nullptr, 0);
    gemm_mfma_kernel<<<BM/32, 256, 0, stream>>>(buf1, Wh + 2*16384,  nullptr, nullptr, cosT, sinT, buf4, nullptr, nullptr, 0);

    // in_proj: Q,K -> f16; V -> fp32 then transpose to f16
    gemm_mfma_kernel<<<BM/32, 256, 0, stream>>>(buf2, Wh + 3*16384, in_b,        nullptr, nullptr, nullptr, nullptr, Qh, nullptr, 0);
    gemm_mfma_kernel<<<BM/32, 256, 0, stream>>>(buf3, Wh + 4*16384, in_b + Dd,   nullptr, nullptr, nullptr, nullptr, Kh, nullptr, 0);
    gemm_mfma_kernel<<<BM/32, 256, 0, stream>>>(buf4, Wh + 5*16384, in_b + 2*Dd, nullptr, nullptr, nullptr, buf4, nullptr, nullptr, 0);

    vtrans_kernel<<<Bb*Hh*(Mm/64), 256, 0, stream>>>(buf4, Vt);

    attn_mfma_kernel<<<Bb*Hh*(Mm/16)/4, 256, 0, stream>>>(Qh, Kh, Vt, buf2);

    // out_proj + residual(x_norm) + fused ssq of result
    gemm_mfma_kernel<<<BM/32, 256, 0, stream>>>(buf2, Wh + 6*16384, out_pb, buf1, nullptr, nullptr, buf4, nullptr, accs + 8, 0);

    normscale_kernel<<<NEL/256, 256, 0, stream>>>(buf4, rms_scale, accs + 8, buf1);

    // FFN: x_res + relu(x2norm @ lin_w^T + b)
    gemm_mfma_kernel<<<BM/32, 256, 0, stream>>>(buf1, Wh + 7*16384, lin_b, buf4, nullptr, nullptr, buf2, nullptr, nullptr, 1);

    logits_loss_kernel<<<BM/4, 256, 0, stream>>>(buf2, out_w, out_b, targets, out, lossAcc);
    loss_finalize_kernel<<<1, 1, 0, stream>>>(lossAcc, out + (size_t)BM*Vv);
}

// Round 5
// 588.545 us; speedup vs baseline: 4.5812x; 1.3966x over previous
//
#include <hip/hip_runtime.h>
#include <hip/hip_bf16.h>
#include <math.h>

#define Vv   32
#define Dd   128
#define Hh   8
#define Bb   8
#define Mm   2048
#define BM   (Bb*Mm)        // 16384
#define NEL  (BM*Dd)        // 2097152

typedef _Float16 half4_t __attribute__((ext_vector_type(4)));
typedef float    float4_t __attribute__((ext_vector_type(4)));
#define MFMA16 __builtin_amdgcn_mfma_f32_16x16x16f16

// ---------------- RoPE tables ----------------
__global__ __launch_bounds__(256) void rope_table_kernel(float* __restrict__ cosT,
                                                         float* __restrict__ sinT) {
    int gid = blockIdx.x * 256 + threadIdx.x;
    int i = gid & 63;
    int m = gid >> 6;
    float ex = -2.0f * ((float)i - 1.0f) / 128.0f;
    float base = expf(ex * 9.210340371976184f);
    float ang = (float)m * base;
    cosT[gid] = cosf(ang);
    sinT[gid] = sinf(ang);
}

// ---------------- weights -> f16 (0=Wq 1=Wk 2=Wv 3..5=in_w 6=out_pw 7=lin_w) ----------------
__global__ __launch_bounds__(256) void wcvt_kernel(const float* __restrict__ Wq,
                                                   const float* __restrict__ Wk,
                                                   const float* __restrict__ Wv,
                                                   const float* __restrict__ in_w,
                                                   const float* __restrict__ out_pw,
                                                   const float* __restrict__ lin_w,
                                                   _Float16* __restrict__ Wh) {
    int gid = blockIdx.x * 256 + threadIdx.x;
    int seg = gid >> 14, off = gid & 16383;
    const float* src =
        seg == 0 ? Wq : seg == 1 ? Wk : seg == 2 ? Wv :
        seg < 6 ? in_w + (size_t)(seg - 3) * 16384 :
        seg == 6 ? out_pw : lin_w;
    Wh[gid] = (_Float16)src[off];
}

// ---------------- embedding gather + per-batch ssq ----------------
__global__ __launch_bounds__(256) void gather_sumsq_kernel(const int* __restrict__ idx,
                                                           const float* __restrict__ emb,
                                                           float* __restrict__ X,
                                                           float* __restrict__ ssq) {
    int gid = blockIdx.x * 256 + threadIdx.x;
    int d = gid & 127;
    int token = gid >> 7;
    float x = emb[idx[token] * Dd + d];
    X[gid] = x;
    float v = x * x;
    #pragma unroll
    for (int off = 32; off; off >>= 1) v += __shfl_xor(v, off);
    __shared__ float wsum[4];
    int lane = threadIdx.x & 63, wave = threadIdx.x >> 6;
    if (lane == 0) wsum[wave] = v;
    __syncthreads();
    if (threadIdx.x == 0) atomicAdd(&ssq[gid >> 18], wsum[0] + wsum[1] + wsum[2] + wsum[3]);
}

// ---------------- x * (512/sqrt(ssq[b])) * scale[m,d] ----------------
__global__ __launch_bounds__(256) void normscale_kernel(const float* __restrict__ X,
                                                        const float* __restrict__ scale,
                                                        const float* __restrict__ ssq,
                                                        float* __restrict__ out) {
    int gid = blockIdx.x * 256 + threadIdx.x;
    int b = gid >> 18;
    int md = gid & ((Mm * Dd) - 1);
    float inv = 512.0f / sqrtf(ssq[b]);
    out[gid] = X[gid] * inv * scale[md];
}

// ---------------- QKV projection GEMM + fused RoPE -> f16 row-major [16384][384] ----------------
__global__ __launch_bounds__(256) void gemm_qkv_kernel(const float* __restrict__ A,
                                                       const _Float16* __restrict__ Wh,
                                                       const float* __restrict__ cosT,
                                                       const float* __restrict__ sinT,
                                                       _Float16* __restrict__ outh) {
    int wave = threadIdx.x >> 6, lane = threadIdx.x & 63;
    int r = lane & 15, c = lane >> 4;
    int row0 = blockIdx.x * 32 + (wave & 1) * 16;
    int n0 = blockIdx.y * 128 + (wave >> 1) * 64;
    const float* Ar = A + (size_t)(row0 + r) * 128 + 4 * c;
    float4 a4[8];
    #pragma unroll
    for (int kk = 0; kk < 8; kk++) a4[kk] = *(const float4*)(Ar + kk * 16);
    half4_t af[8];
    #pragma unroll
    for (int kk = 0; kk < 8; kk++) {
        af[kk][0] = (_Float16)a4[kk].x; af[kk][1] = (_Float16)a4[kk].y;
        af[kk][2] = (_Float16)a4[kk].z; af[kk][3] = (_Float16)a4[kk].w;
    }
    float4_t acc[4];
    #pragma unroll
    for (int t = 0; t < 4; t++) acc[t] = (float4_t){0.f, 0.f, 0.f, 0.f};
    #pragma unroll
    for (int kk = 0; kk < 8; kk++) {
        #pragma unroll
        for (int t = 0; t < 4; t++) {
            half4_t wf = *(const half4_t*)(Wh + (size_t)(n0 + t * 16 + r) * 128 + kk * 16 + 4 * c);
            acc[t] = MFMA16(af[kk], wf, acc[t], 0, 0, 0);
        }
    }
    #pragma unroll
    for (int t = 0; t < 4; t++) {
        int n = n0 + t * 16 + r;
        int ci = (n >> 1) & 63;
        #pragma unroll
        for (int reg = 0; reg < 4; reg++) {
            int row = row0 + 4 * c + reg;
            int m = row & (Mm - 1);
            float v = acc[t][reg];
            float vp = __shfl_xor(v, 1);                 // pair column n^1 lives in lane^1
            float cs = cosT[m * 64 + ci], sn = sinT[m * 64 + ci];
            v = (n & 1) ? (-vp * sn + v * cs) : (v * cs + vp * sn);
            outh[(size_t)row * 384 + n] = (_Float16)v;
        }
    }
}

// ---------------- in_proj GEMM (A f16 [16384][384]) -> tile-blocked Qp/Kp/Vp f16 ----------------
// Qp/Kp: [bh][tile][token&15][d]  (512B tiles);  Vp: [bh][tile][d][token&15]
__global__ __launch_bounds__(256) void gemm_inproj_kernel(const _Float16* __restrict__ Ah,
                                                          const _Float16* __restrict__ Wh3,
                                                          const float* __restrict__ bias,
                                                          _Float16* __restrict__ Qp,
                                                          _Float16* __restrict__ Kp,
                                                          _Float16* __restrict__ Vp) {
    int wave = threadIdx.x >> 6, lane = threadIdx.x & 63;
    int r = lane & 15, c = lane >> 4;
    int row0 = blockIdx.x * 32 + (wave & 1) * 16;
    int seg = blockIdx.y;
    int n0 = seg * 128 + (wave >> 1) * 64;
    const _Float16* Ar = Ah + (size_t)(row0 + r) * 384 + seg * 128 + 4 * c;
    half4_t af[8];
    #pragma unroll
    for (int kk = 0; kk < 8; kk++) af[kk] = *(const half4_t*)(Ar + kk * 16);
    float4_t acc[4];
    #pragma unroll
    for (int t = 0; t < 4; t++) acc[t] = (float4_t){0.f, 0.f, 0.f, 0.f};
    #pragma unroll
    for (int kk = 0; kk < 8; kk++) {
        #pragma unroll
        for (int t = 0; t < 4; t++) {
            half4_t wf = *(const half4_t*)(Wh3 + (size_t)(n0 + t * 16 + r) * 128 + kk * 16 + 4 * c);
            acc[t] = MFMA16(af[kk], wf, acc[t], 0, 0, 0);
        }
    }
    int b = row0 >> 11;
    int t16 = (row0 & 2047) >> 4;
    int hh = (n0 & 127) >> 4;                            // 0 or 4
    _Float16* dst = seg == 0 ? Qp : seg == 1 ? Kp : Vp;
    #pragma unroll
    for (int t = 0; t < 4; t++) {
        int h = hh + t;
        size_t tb = ((size_t)(b * 8 + h) * 128 + t16) * 256;
        float bv = bias[n0 + t * 16 + r];
        #pragma unroll
        for (int reg = 0; reg < 4; reg++) {
            float v = acc[t][reg] + bv;
            int key = 4 * c + reg;                       // token index within tile
            if (seg < 2) dst[tb + key * 16 + r] = (_Float16)v;   // [token][d=r]
            else         dst[tb + r * 16 + key] = (_Float16)v;   // [d=r][token]
        }
    }
}

// ---------------- generic epilogue GEMM: out f32 = A f32 @ W128^T + bias (relu?)(+resid)(ssq?) ----------------
__global__ __launch_bounds__(256) void gemm_ep_kernel(const float* __restrict__ A,
                                                      const _Float16* __restrict__ W128,
                                                      const float* __restrict__ bias,
                                                      const float* __restrict__ resid,
                                                      float* __restrict__ out,
                                                      float* __restrict__ ssq,
                                                      int relu) {
    int wave = threadIdx.x >> 6, lane = threadIdx.x & 63;
    int r = lane & 15, c = lane >> 4;
    int row0 = blockIdx.x * 32 + (wave & 1) * 16;
    int n0 = (wave >> 1) * 64;
    const float* Ar = A + (size_t)(row0 + r) * 128 + 4 * c;
    float4 a4[8];
    #pragma unroll
    for (int kk = 0; kk < 8; kk++) a4[kk] = *(const float4*)(Ar + kk * 16);
    half4_t af[8];
    #pragma unroll
    for (int kk = 0; kk < 8; kk++) {
        af[kk][0] = (_Float16)a4[kk].x; af[kk][1] = (_Float16)a4[kk].y;
        af[kk][2] = (_Float16)a4[kk].z; af[kk][3] = (_Float16)a4[kk].w;
    }
    float4_t acc[4];
    #pragma unroll
    for (int t = 0; t < 4; t++) acc[t] = (float4_t){0.f, 0.f, 0.f, 0.f};
    #pragma unroll
    for (int kk = 0; kk < 8; kk++) {
        #pragma unroll
        for (int t = 0; t < 4; t++) {
            half4_t wf = *(const half4_t*)(W128 + (size_t)(n0 + t * 16 + r) * 128 + kk * 16 + 4 * c);
            acc[t] = MFMA16(af[kk], wf, acc[t], 0, 0, 0);
        }
    }
    float lssq = 0.f;
    #pragma unroll
    for (int t = 0; t < 4; t++) {
        int n = n0 + t * 16 + r;
        float bv = bias[n];
        #pragma unroll
        for (int reg = 0; reg < 4; reg++) {
            int row = row0 + 4 * c + reg;
            float v = acc[t][reg] + bv;
            if (relu) v = fmaxf(v, 0.f);
            if (resid) v += resid[(size_t)row * 128 + n];
            if (ssq) lssq += v * v;
            out[(size_t)row * 128 + n] = v;
        }
    }
    if (ssq) {
        #pragma unroll
        for (int off = 32; off; off >>= 1) lssq += __shfl_xor(lssq, off);
        if (lane == 0) atomicAdd(&ssq[row0 >> 11], lssq);
    }
}

// ---------------- attention helpers (inline fns: no macro name-capture) ----------------
__device__ __forceinline__ half4_t attn_exps(float4_t st, float& ls) {
    float p0 = __expf(st[0] * 0.25f), p1 = __expf(st[1] * 0.25f);
    float p2 = __expf(st[2] * 0.25f), p3 = __expf(st[3] * 0.25f);
    ls += (p0 + p1) + (p2 + p3);
    half4_t pf;
    pf[0] = (_Float16)p0; pf[1] = (_Float16)p1;
    pf[2] = (_Float16)p2; pf[3] = (_Float16)p3;
    return pf;
}
__device__ __forceinline__ half4_t attn_exps_masked(float4_t st, float& ls, int r, int c) {
    float p0 = (4 * c + 0 <= r) ? __expf(st[0] * 0.25f) : 0.f;
    float p1 = (4 * c + 1 <= r) ? __expf(st[1] * 0.25f) : 0.f;
    float p2 = (4 * c + 2 <= r) ? __expf(st[2] * 0.25f) : 0.f;
    float p3 = (4 * c + 3 <= r) ? __expf(st[3] * 0.25f) : 0.f;
    ls += (p0 + p1) + (p2 + p3);
    half4_t pf;
    pf[0] = (_Float16)p0; pf[1] = (_Float16)p1;
    pf[2] = (_Float16)p2; pf[3] = (_Float16)p3;
    return pf;
}

// ---------------- MFMA flash attention, paired q-tiles (qa, 127-qa), shared K/V loads ----------------
__global__ __launch_bounds__(256) void attn_kernel(const _Float16* __restrict__ Qp,
                                                   const _Float16* __restrict__ Kp,
                                                   const _Float16* __restrict__ Vp,
                                                   float* __restrict__ O) {
    int wave = threadIdx.x >> 6, lane = threadIdx.x & 63;
    int wid = blockIdx.x * 4 + wave;
    int qa = wid & 63, bh = wid >> 6, qb = 127 - qa;
    int r = lane & 15, c = lane >> 4;
    int lofs = r * 16 + 4 * c;                      // every frag load: contiguous 512B/wave
    const _Float16* Kb = Kp + (size_t)bh * 32768 + lofs;
    const _Float16* Vb = Vp + (size_t)bh * 32768 + lofs;
    const _Float16* Qb = Qp + (size_t)bh * 32768 + lofs;
    half4_t qfa = *(const half4_t*)(Qb + qa * 256);
    half4_t qfb = *(const half4_t*)(Qb + qb * 256);
    float4_t zero = {0.f, 0.f, 0.f, 0.f};
    float4_t oa = zero, ob = zero;
    float lsa = 0.f, lsb = 0.f;

    int kt = 0;
    for (; kt + 2 <= qa; kt += 2) {                 // shared range: both q-tiles
        half4_t k0 = *(const half4_t*)(Kb + kt * 256);
        half4_t v0 = *(const half4_t*)(Vb + kt * 256);
        half4_t k1 = *(const half4_t*)(Kb + kt * 256 + 256);
        half4_t v1 = *(const half4_t*)(Vb + kt * 256 + 256);
        float4_t s0a = MFMA16(k0, qfa, zero, 0, 0, 0);
        float4_t s0b = MFMA16(k0, qfb, zero, 0, 0, 0);
        float4_t s1a = MFMA16(k1, qfa, zero, 0, 0, 0);
        float4_t s1b = MFMA16(k1, qfb, zero, 0, 0, 0);
        half4_t p0a = attn_exps(s0a, lsa);
        half4_t p0b = attn_exps(s0b, lsb);
        half4_t p1a = attn_exps(s1a, lsa);
        half4_t p1b = attn_exps(s1b, lsb);
        oa = MFMA16(p0a, v0, oa, 0, 0, 0);
        ob = MFMA16(p0b, v0, ob, 0, 0, 0);
        oa = MFMA16(p1a, v1, oa, 0, 0, 0);
        ob = MFMA16(p1b, v1, ob, 0, 0, 0);
    }
    if (kt < qa) {                                  // odd remainder of shared range
        half4_t k0 = *(const half4_t*)(Kb + kt * 256);
        half4_t v0 = *(const half4_t*)(Vb + kt * 256);
        float4_t sa = MFMA16(k0, qfa, zero, 0, 0, 0);
        float4_t sb = MFMA16(k0, qfb, zero, 0, 0, 0);
        half4_t pa = attn_exps(sa, lsa);
        half4_t pb = attn_exps(sb, lsb);
        oa = MFMA16(pa, v0, oa, 0, 0, 0);
        ob = MFMA16(pb, v0, ob, 0, 0, 0);
    }
    {                                               // kt == qa: diagonal for a, full for b
        half4_t k0 = *(const half4_t*)(Kb + qa * 256);
        half4_t v0 = *(const half4_t*)(Vb + qa * 256);
        float4_t sa = MFMA16(k0, qfa, zero, 0, 0, 0);
        float4_t sb = MFMA16(k0, qfb, zero, 0, 0, 0);
        half4_t pa = attn_exps_masked(sa, lsa, r, c);
        half4_t pb = attn_exps(sb, lsb);
        oa = MFMA16(pa, v0, oa, 0, 0, 0);
        ob = MFMA16(pb, v0, ob, 0, 0, 0);
    }
    for (kt = qa + 1; kt + 2 <= qb; kt += 2) {      // b-only range (even length, no tail)
        half4_t k0 = *(const half4_t*)(Kb + kt * 256);
        half4_t v0 = *(const half4_t*)(Vb + kt * 256);
        half4_t k1 = *(const half4_t*)(Kb + kt * 256 + 256);
        half4_t v1 = *(const half4_t*)(Vb + kt * 256 + 256);
        float4_t s0 = MFMA16(k0, qfb, zero, 0, 0, 0);
        float4_t s1 = MFMA16(k1, qfb, zero, 0, 0, 0);
        half4_t p0 = attn_exps(s0, lsb);
        half4_t p1 = attn_exps(s1, lsb);
        ob = MFMA16(p0, v0, ob, 0, 0, 0);
        ob = MFMA16(p1, v1, ob, 0, 0, 0);
    }
    {                                               // kt == qb: diagonal for b
        half4_t k0 = *(const half4_t*)(Kb + qb * 256);
        half4_t v0 = *(const half4_t*)(Vb + qb * 256);
        float4_t sb = MFMA16(k0, qfb, zero, 0, 0, 0);
        half4_t pb = attn_exps_masked(sb, lsb, r, c);
        ob = MFMA16(pb, v0, ob, 0, 0, 0);
    }
    lsa += __shfl_xor(lsa, 16); lsa += __shfl_xor(lsa, 32);
    lsb += __shfl_xor(lsb, 16); lsb += __shfl_xor(lsb, 32);
    int b = bh >> 3, h = bh & 7;
    #pragma unroll
    for (int reg = 0; reg < 4; reg++) {
        float la = __shfl(lsa, 4 * c + reg);
        float lb = __shfl(lsb, 4 * c + reg);
        O[(size_t)(b * Mm + qa * 16 + 4 * c + reg) * 128 + h * 16 + r] = oa[reg] / la;
        O[(size_t)(b * Mm + qb * 16 + 4 * c + reg) * 128 + h * 16 + r] = ob[reg] / lb;
    }
}

// ---------------- logits (V=32) + log_softmax + NLL ----------------
__global__ __launch_bounds__(256) void logits_loss_kernel(const float* __restrict__ X,
                                                          const float* __restrict__ Wo,
                                                          const float* __restrict__ bo,
                                                          const int* __restrict__ targets,
                                                          float* __restrict__ logits,
                                                          double* __restrict__ lossAcc) {
    int wave = threadIdx.x >> 6, lane = threadIdx.x & 63;
    int row = blockIdx.x * 4 + wave;
    int l = lane & 31;
    const float* xr = X + (size_t)row * 128;
    const float* wr = Wo + (size_t)l * 128;
    float acc = 0.f;
    for (int k = 0; k < 128; k += 4) {
        float4 x4 = *(const float4*)(xr + k);
        float4 w4 = *(const float4*)(wr + k);
        acc += x4.x * w4.x + x4.y * w4.y + x4.z * w4.z + x4.w * w4.w;
    }
    float logit = acc + bo[l];
    if (lane < 32) logits[(size_t)row * 32 + lane] = logit;
    float mx = logit;
    #pragma unroll
    for (int off = 16; off; off >>= 1) mx = fmaxf(mx, __shfl_xor(mx, off, 32));
    float e = __expf(logit - mx);
    float se = e;
    #pragma unroll
    for (int off = 16; off; off >>= 1) se += __shfl_xor(se, off, 32);
    int tgt = targets[row];
    float lt = __shfl(logit, tgt, 32);
    if (lane == 0) {
        float nll = logf(se) + mx - lt;
        atomicAdd(lossAcc, (double)nll);
    }
}

__global__ void loss_finalize_kernel(const double* __restrict__ lossAcc,
                                     float* __restrict__ out) {
    out[0] = (float)(lossAcc[0] * (1.0 / (double)BM));
}

extern "C" void kernel_launch(void* const* d_in, const int* in_sizes, int n_in,
                              void* d_out, int out_size, void* d_ws, size_t ws_size,
                              hipStream_t stream) {
    const int*   idx       = (const int*)d_in[0];
    const int*   targets   = (const int*)d_in[1];
    const float* emb       = (const float*)d_in[2];
    const float* rms_scale = (const float*)d_in[3];
    const float* Wq        = (const float*)d_in[4];
    const float* Wk        = (const float*)d_in[5];
    const float* Wv        = (const float*)d_in[6];
    const float* in_w      = (const float*)d_in[7];
    const float* in_b      = (const float*)d_in[8];
    const float* out_pw    = (const float*)d_in[9];
    const float* out_pb    = (const float*)d_in[10];
    const float* lin_w     = (const float*)d_in[11];
    const float* lin_b     = (const float*)d_in[12];
    const float* out_w     = (const float*)d_in[13];
    const float* out_b     = (const float*)d_in[14];
    float* out = (float*)d_out;

    char* base = (char*)d_ws;
    const size_t MB = 1024 * 1024;
    float*     xbuf   = (float*)base;                        // 0..8MB   (then Qp/Kp, then x2n)
    float*     xnorm  = (float*)(base + 8 * MB);             // 8..16MB  (alive thru out_proj resid)
    _Float16*  XQKVh  = (_Float16*)(base + 16 * MB);         // 16..28MB (f16 roped QKV)
    _Float16*  Qp     = (_Float16*)base;                     // 0..4MB
    _Float16*  Kp     = (_Float16*)(base + 4 * MB);          // 4..8MB
    _Float16*  Vp     = (_Float16*)(base + 28 * MB);         // 28..32MB
    float*     Obuf   = (float*)(base + 16 * MB);            // 16..24MB (attn out)
    float*     xres   = (float*)(base + 24 * MB);            // 24..32MB
    float*     x2n    = (float*)base;                        // 0..8MB
    float*     ffo    = (float*)(base + 32 * MB);            // 32..40MB
    float*     cosT   = (float*)(base + 40 * MB);
    float*     sinT   = cosT + Mm * 64;
    float*     accs   = sinT + Mm * 64;                      // ssq[8], ssq2[8]
    double*    lossAcc = (double*)(accs + 16);
    _Float16*  Wh     = (_Float16*)(accs + 24);              // 8 x 128x128 f16

    (void)hipMemsetAsync(accs, 0, 96, stream);

    rope_table_kernel<<<Mm * 64 / 256, 256, 0, stream>>>(cosT, sinT);
    wcvt_kernel<<<131072 / 256, 256, 0, stream>>>(Wq, Wk, Wv, in_w, out_pw, lin_w, Wh);
    gather_sumsq_kernel<<<NEL / 256, 256, 0, stream>>>(idx, emb, xbuf, accs);
    normscale_kernel<<<NEL / 256, 256, 0, stream>>>(xbuf, rms_scale, accs, xnorm);

    gemm_qkv_kernel<<<dim3(BM / 32, 3), 256, 0, stream>>>(xnorm, Wh, cosT, sinT, XQKVh);
    gemm_inproj_kernel<<<dim3(BM / 32, 3), 256, 0, stream>>>(XQKVh, Wh + 3 * 16384, in_b, Qp, Kp, Vp);

    attn_kernel<<<64 * 64 / 4, 256, 0, stream>>>(Qp, Kp, Vp, Obuf);

    gemm_ep_kernel<<<BM / 32, 256, 0, stream>>>(Obuf, Wh + 6 * 16384, out_pb, xnorm, xres, accs + 8, 0);
    normscale_kernel<<<NEL / 256, 256, 0, stream>>>(xres, rms_scale, accs + 8, x2n);
    gemm_ep_kernel<<<BM / 32, 256, 0, stream>>>(x2n, Wh + 7 * 16384, lin_b, xres, ffo, nullptr, 1);

    logits_loss_kernel<<<BM / 4, 256, 0, stream>>>(ffo, out_w, out_b, targets, out, lossAcc);
    loss_finalize_kernel<<<1, 1, 0, stream>>>(lossAcc, out + (size_t)BM * Vv);
}

// Round 6
// 409.402 us; speedup vs baseline: 6.5858x; 1.4376x over previous
//
#include <hip/hip_runtime.h>
#include <hip/hip_bf16.h>
#include <math.h>

#define Vv   32
#define Dd   128
#define Hh   8
#define Bb   8
#define Mm   2048
#define BM   (Bb*Mm)        // 16384
#define NEL  (BM*Dd)        // 2097152

typedef _Float16 half4_t __attribute__((ext_vector_type(4)));
typedef float    float4_t __attribute__((ext_vector_type(4)));
#define MFMA16 __builtin_amdgcn_mfma_f32_16x16x16f16

// ---------------- RoPE tables ----------------
__global__ __launch_bounds__(256) void rope_table_kernel(float* __restrict__ cosT,
                                                         float* __restrict__ sinT) {
    int gid = blockIdx.x * 256 + threadIdx.x;
    int i = gid & 63;
    int m = gid >> 6;
    float ex = -2.0f * ((float)i - 1.0f) / 128.0f;
    float base = expf(ex * 9.210340371976184f);
    float ang = (float)m * base;
    cosT[gid] = cosf(ang);
    sinT[gid] = sinf(ang);
}

// ---------------- weights -> f16 (0=Wq 1=Wk 2=Wv 3..5=in_w 6=out_pw 7=lin_w) ----------------
__global__ __launch_bounds__(256) void wcvt_kernel(const float* __restrict__ Wq,
                                                   const float* __restrict__ Wk,
                                                   const float* __restrict__ Wv,
                                                   const float* __restrict__ in_w,
                                                   const float* __restrict__ out_pw,
                                                   const float* __restrict__ lin_w,
                                                   _Float16* __restrict__ Wh) {
    int gid = blockIdx.x * 256 + threadIdx.x;
    int seg = gid >> 14, off = gid & 16383;
    const float* src =
        seg == 0 ? Wq : seg == 1 ? Wk : seg == 2 ? Wv :
        seg < 6 ? in_w + (size_t)(seg - 3) * 16384 :
        seg == 6 ? out_pw : lin_w;
    Wh[gid] = (_Float16)src[off];
}

// ---------------- embedding gather + per-batch ssq ----------------
__global__ __launch_bounds__(256) void gather_sumsq_kernel(const int* __restrict__ idx,
                                                           const float* __restrict__ emb,
                                                           float* __restrict__ X,
                                                           float* __restrict__ ssq) {
    int gid = blockIdx.x * 256 + threadIdx.x;
    int d = gid & 127;
    int token = gid >> 7;
    float x = emb[idx[token] * Dd + d];
    X[gid] = x;
    float v = x * x;
    #pragma unroll
    for (int off = 32; off; off >>= 1) v += __shfl_xor(v, off);
    __shared__ float wsum[4];
    int lane = threadIdx.x & 63, wave = threadIdx.x >> 6;
    if (lane == 0) wsum[wave] = v;
    __syncthreads();
    if (threadIdx.x == 0) atomicAdd(&ssq[gid >> 18], wsum[0] + wsum[1] + wsum[2] + wsum[3]);
}

// ---------------- x * (512/sqrt(ssq[b])) * scale[m,d] ----------------
__global__ __launch_bounds__(256) void normscale_kernel(const float* __restrict__ X,
                                                        const float* __restrict__ scale,
                                                        const float* __restrict__ ssq,
                                                        float* __restrict__ out) {
    int gid = blockIdx.x * 256 + threadIdx.x;
    int b = gid >> 18;
    int md = gid & ((Mm * Dd) - 1);
    float inv = 512.0f / sqrtf(ssq[b]);
    out[gid] = X[gid] * inv * scale[md];
}

// ---------------- QKV projection GEMM + fused RoPE -> f16 row-major [16384][384] ----------------
__global__ __launch_bounds__(256) void gemm_qkv_kernel(const float* __restrict__ A,
                                                       const _Float16* __restrict__ Wh,
                                                       const float* __restrict__ cosT,
                                                       const float* __restrict__ sinT,
                                                       _Float16* __restrict__ outh) {
    int wave = threadIdx.x >> 6, lane = threadIdx.x & 63;
    int r = lane & 15, c = lane >> 4;
    int row0 = blockIdx.x * 32 + (wave & 1) * 16;
    int n0 = blockIdx.y * 128 + (wave >> 1) * 64;
    const float* Ar = A + (size_t)(row0 + r) * 128 + 4 * c;
    float4 a4[8];
    #pragma unroll
    for (int kk = 0; kk < 8; kk++) a4[kk] = *(const float4*)(Ar + kk * 16);
    half4_t af[8];
    #pragma unroll
    for (int kk = 0; kk < 8; kk++) {
        af[kk][0] = (_Float16)a4[kk].x; af[kk][1] = (_Float16)a4[kk].y;
        af[kk][2] = (_Float16)a4[kk].z; af[kk][3] = (_Float16)a4[kk].w;
    }
    float4_t acc[4];
    #pragma unroll
    for (int t = 0; t < 4; t++) acc[t] = (float4_t){0.f, 0.f, 0.f, 0.f};
    #pragma unroll
    for (int kk = 0; kk < 8; kk++) {
        #pragma unroll
        for (int t = 0; t < 4; t++) {
            half4_t wf = *(const half4_t*)(Wh + (size_t)(n0 + t * 16 + r) * 128 + kk * 16 + 4 * c);
            acc[t] = MFMA16(af[kk], wf, acc[t], 0, 0, 0);
        }
    }
    #pragma unroll
    for (int t = 0; t < 4; t++) {
        int n = n0 + t * 16 + r;
        int ci = (n >> 1) & 63;
        #pragma unroll
        for (int reg = 0; reg < 4; reg++) {
            int row = row0 + 4 * c + reg;
            int m = row & (Mm - 1);
            float v = acc[t][reg];
            float vp = __shfl_xor(v, 1);                 // pair column n^1 lives in lane^1
            float cs = cosT[m * 64 + ci], sn = sinT[m * 64 + ci];
            v = (n & 1) ? (-vp * sn + v * cs) : (v * cs + vp * sn);
            outh[(size_t)row * 384 + n] = (_Float16)v;
        }
    }
}

// ---------------- in_proj GEMM (A f16 [16384][384]) -> tile-blocked Qp/Kp/Vp f16 ----------------
// Qp/Kp: [bh][tile][token&15][d]  (512B tiles);  Vp: [bh][tile][d][token&15]
__global__ __launch_bounds__(256) void gemm_inproj_kernel(const _Float16* __restrict__ Ah,
                                                          const _Float16* __restrict__ Wh3,
                                                          const float* __restrict__ bias,
                                                          _Float16* __restrict__ Qp,
                                                          _Float16* __restrict__ Kp,
                                                          _Float16* __restrict__ Vp) {
    int wave = threadIdx.x >> 6, lane = threadIdx.x & 63;
    int r = lane & 15, c = lane >> 4;
    int row0 = blockIdx.x * 32 + (wave & 1) * 16;
    int seg = blockIdx.y;
    int n0 = seg * 128 + (wave >> 1) * 64;
    const _Float16* Ar = Ah + (size_t)(row0 + r) * 384 + seg * 128 + 4 * c;
    half4_t af[8];
    #pragma unroll
    for (int kk = 0; kk < 8; kk++) af[kk] = *(const half4_t*)(Ar + kk * 16);
    float4_t acc[4];
    #pragma unroll
    for (int t = 0; t < 4; t++) acc[t] = (float4_t){0.f, 0.f, 0.f, 0.f};
    #pragma unroll
    for (int kk = 0; kk < 8; kk++) {
        #pragma unroll
        for (int t = 0; t < 4; t++) {
            half4_t wf = *(const half4_t*)(Wh3 + (size_t)(n0 + t * 16 + r) * 128 + kk * 16 + 4 * c);
            acc[t] = MFMA16(af[kk], wf, acc[t], 0, 0, 0);
        }
    }
    int b = row0 >> 11;
    int t16 = (row0 & 2047) >> 4;
    int hh = (n0 & 127) >> 4;                            // 0 or 4
    _Float16* dst = seg == 0 ? Qp : seg == 1 ? Kp : Vp;
    #pragma unroll
    for (int t = 0; t < 4; t++) {
        int h = hh + t;
        size_t tb = ((size_t)(b * 8 + h) * 128 + t16) * 256;
        float bv = bias[n0 + t * 16 + r];
        #pragma unroll
        for (int reg = 0; reg < 4; reg++) {
            float v = acc[t][reg] + bv;
            int key = 4 * c + reg;                       // token index within tile
            if (seg < 2) dst[tb + key * 16 + r] = (_Float16)v;   // [token][d=r]
            else         dst[tb + r * 16 + key] = (_Float16)v;   // [d=r][token]
        }
    }
}

// ---------------- generic epilogue GEMM: out f32 = A f32 @ W128^T + bias (relu?)(+resid)(ssq?) ----------------
__global__ __launch_bounds__(256) void gemm_ep_kernel(const float* __restrict__ A,
                                                      const _Float16* __restrict__ W128,
                                                      const float* __restrict__ bias,
                                                      const float* __restrict__ resid,
                                                      float* __restrict__ out,
                                                      float* __restrict__ ssq,
                                                      int relu) {
    int wave = threadIdx.x >> 6, lane = threadIdx.x & 63;
    int r = lane & 15, c = lane >> 4;
    int row0 = blockIdx.x * 32 + (wave & 1) * 16;
    int n0 = (wave >> 1) * 64;
    const float* Ar = A + (size_t)(row0 + r) * 128 + 4 * c;
    float4 a4[8];
    #pragma unroll
    for (int kk = 0; kk < 8; kk++) a4[kk] = *(const float4*)(Ar + kk * 16);
    half4_t af[8];
    #pragma unroll
    for (int kk = 0; kk < 8; kk++) {
        af[kk][0] = (_Float16)a4[kk].x; af[kk][1] = (_Float16)a4[kk].y;
        af[kk][2] = (_Float16)a4[kk].z; af[kk][3] = (_Float16)a4[kk].w;
    }
    float4_t acc[4];
    #pragma unroll
    for (int t = 0; t < 4; t++) acc[t] = (float4_t){0.f, 0.f, 0.f, 0.f};
    #pragma unroll
    for (int kk = 0; kk < 8; kk++) {
        #pragma unroll
        for (int t = 0; t < 4; t++) {
            half4_t wf = *(const half4_t*)(W128 + (size_t)(n0 + t * 16 + r) * 128 + kk * 16 + 4 * c);
            acc[t] = MFMA16(af[kk], wf, acc[t], 0, 0, 0);
        }
    }
    float lssq = 0.f;
    #pragma unroll
    for (int t = 0; t < 4; t++) {
        int n = n0 + t * 16 + r;
        float bv = bias[n];
        #pragma unroll
        for (int reg = 0; reg < 4; reg++) {
            int row = row0 + 4 * c + reg;
            float v = acc[t][reg] + bv;
            if (relu) v = fmaxf(v, 0.f);
            if (resid) v += resid[(size_t)row * 128 + n];
            if (ssq) lssq += v * v;
            out[(size_t)row * 128 + n] = v;
        }
    }
    if (ssq) {
        #pragma unroll
        for (int off = 32; off; off >>= 1) lssq += __shfl_xor(lssq, off);
        if (lane == 0) atomicAdd(&ssq[row0 >> 11], lssq);
    }
}

// ---------------- attention helpers ----------------
__device__ __forceinline__ half4_t attn_exps(float4_t st, float& ls) {
    float p0 = __expf(st[0] * 0.25f), p1 = __expf(st[1] * 0.25f);
    float p2 = __expf(st[2] * 0.25f), p3 = __expf(st[3] * 0.25f);
    ls += (p0 + p1) + (p2 + p3);
    half4_t pf;
    pf[0] = (_Float16)p0; pf[1] = (_Float16)p1;
    pf[2] = (_Float16)p2; pf[3] = (_Float16)p3;
    return pf;
}
__device__ __forceinline__ half4_t attn_exps_masked(float4_t st, float& ls, int r, int c) {
    float p0 = (4 * c + 0 <= r) ? __expf(st[0] * 0.25f) : 0.f;
    float p1 = (4 * c + 1 <= r) ? __expf(st[1] * 0.25f) : 0.f;
    float p2 = (4 * c + 2 <= r) ? __expf(st[2] * 0.25f) : 0.f;
    float p3 = (4 * c + 3 <= r) ? __expf(st[3] * 0.25f) : 0.f;
    ls += (p0 + p1) + (p2 + p3);
    half4_t pf;
    pf[0] = (_Float16)p0; pf[1] = (_Float16)p1;
    pf[2] = (_Float16)p2; pf[3] = (_Float16)p3;
    return pf;
}

// ---------------- MFMA flash attention, paired q-tiles (qa, 127-qa), shared K/V loads ----------------
__global__ __launch_bounds__(256) void attn_kernel(const _Float16* __restrict__ Qp,
                                                   const _Float16* __restrict__ Kp,
                                                   const _Float16* __restrict__ Vp,
                                                   float* __restrict__ O) {
    int wave = threadIdx.x >> 6, lane = threadIdx.x & 63;
    int wid = blockIdx.x * 4 + wave;
    int qa = wid & 63, bh = wid >> 6, qb = 127 - qa;
    int r = lane & 15, c = lane >> 4;
    int lofs = r * 16 + 4 * c;                      // every frag load: contiguous 512B/wave
    const _Float16* Kb = Kp + (size_t)bh * 32768 + lofs;
    const _Float16* Vb = Vp + (size_t)bh * 32768 + lofs;
    const _Float16* Qb = Qp + (size_t)bh * 32768 + lofs;
    half4_t qfa = *(const half4_t*)(Qb + qa * 256);
    half4_t qfb = *(const half4_t*)(Qb + qb * 256);
    float4_t zero = {0.f, 0.f, 0.f, 0.f};
    float4_t oa = zero, ob = zero;
    float lsa = 0.f, lsb = 0.f;

    int kt = 0;
    for (; kt + 2 <= qa; kt += 2) {                 // shared range: both q-tiles
        half4_t k0 = *(const half4_t*)(Kb + kt * 256);
        half4_t v0 = *(const half4_t*)(Vb + kt * 256);
        half4_t k1 = *(const half4_t*)(Kb + kt * 256 + 256);
        half4_t v1 = *(const half4_t*)(Vb + kt * 256 + 256);
        float4_t s0a = MFMA16(k0, qfa, zero, 0, 0, 0);
        float4_t s0b = MFMA16(k0, qfb, zero, 0, 0, 0);
        float4_t s1a = MFMA16(k1, qfa, zero, 0, 0, 0);
        float4_t s1b = MFMA16(k1, qfb, zero, 0, 0, 0);
        half4_t p0a = attn_exps(s0a, lsa);
        half4_t p0b = attn_exps(s0b, lsb);
        half4_t p1a = attn_exps(s1a, lsa);
        half4_t p1b = attn_exps(s1b, lsb);
        oa = MFMA16(p0a, v0, oa, 0, 0, 0);
        ob = MFMA16(p0b, v0, ob, 0, 0, 0);
        oa = MFMA16(p1a, v1, oa, 0, 0, 0);
        ob = MFMA16(p1b, v1, ob, 0, 0, 0);
    }
    if (kt < qa) {                                  // odd remainder of shared range
        half4_t k0 = *(const half4_t*)(Kb + kt * 256);
        half4_t v0 = *(const half4_t*)(Vb + kt * 256);
        float4_t sa = MFMA16(k0, qfa, zero, 0, 0, 0);
        float4_t sb = MFMA16(k0, qfb, zero, 0, 0, 0);
        half4_t pa = attn_exps(sa, lsa);
        half4_t pb = attn_exps(sb, lsb);
        oa = MFMA16(pa, v0, oa, 0, 0, 0);
        ob = MFMA16(pb, v0, ob, 0, 0, 0);
    }
    {                                               // kt == qa: diagonal for a, full for b
        half4_t k0 = *(const half4_t*)(Kb + qa * 256);
        half4_t v0 = *(const half4_t*)(Vb + qa * 256);
        float4_t sa = MFMA16(k0, qfa, zero, 0, 0, 0);
        float4_t sb = MFMA16(k0, qfb, zero, 0, 0, 0);
        half4_t pa = attn_exps_masked(sa, lsa, r, c);
        half4_t pb = attn_exps(sb, lsb);
        oa = MFMA16(pa, v0, oa, 0, 0, 0);
        ob = MFMA16(pb, v0, ob, 0, 0, 0);
    }
    for (kt = qa + 1; kt + 2 <= qb; kt += 2) {      // b-only range (even length, no tail)
        half4_t k0 = *(const half4_t*)(Kb + kt * 256);
        half4_t v0 = *(const half4_t*)(Vb + kt * 256);
        half4_t k1 = *(const half4_t*)(Kb + kt * 256 + 256);
        half4_t v1 = *(const half4_t*)(Vb + kt * 256 + 256);
        float4_t s0 = MFMA16(k0, qfb, zero, 0, 0, 0);
        float4_t s1 = MFMA16(k1, qfb, zero, 0, 0, 0);
        half4_t p0 = attn_exps(s0, lsb);
        half4_t p1 = attn_exps(s1, lsb);
        ob = MFMA16(p0, v0, ob, 0, 0, 0);
        ob = MFMA16(p1, v1, ob, 0, 0, 0);
    }
    {                                               // kt == qb: diagonal for b
        half4_t k0 = *(const half4_t*)(Kb + qb * 256);
        half4_t v0 = *(const half4_t*)(Vb + qb * 256);
        float4_t sb = MFMA16(k0, qfb, zero, 0, 0, 0);
        half4_t pb = attn_exps_masked(sb, lsb, r, c);
        ob = MFMA16(pb, v0, ob, 0, 0, 0);
    }
    lsa += __shfl_xor(lsa, 16); lsa += __shfl_xor(lsa, 32);
    lsb += __shfl_xor(lsb, 16); lsb += __shfl_xor(lsb, 32);
    int b = bh >> 3, h = bh & 7;
    #pragma unroll
    for (int reg = 0; reg < 4; reg++) {
        float la = __shfl(lsa, 4 * c + reg);
        float lb = __shfl(lsb, 4 * c + reg);
        O[(size_t)(b * Mm + qa * 16 + 4 * c + reg) * 128 + h * 16 + r] = oa[reg] / la;
        O[(size_t)(b * Mm + qb * 16 + 4 * c + reg) * 128 + h * 16 + r] = ob[reg] / lb;
    }
}

// ---------------- logits (V=32) + log_softmax + per-row NLL (no global atomic) ----------------
// wave handles 2 rows: 32 lanes per row. grid = BM/8 blocks of 256.
__global__ __launch_bounds__(256) void logits_loss_kernel(const float* __restrict__ X,
                                                          const float* __restrict__ Wo,
                                                          const float* __restrict__ bo,
                                                          const int* __restrict__ targets,
                                                          float* __restrict__ logits,
                                                          float* __restrict__ nllBuf) {
    int wave = threadIdx.x >> 6, lane = threadIdx.x & 63;
    int sub = lane >> 5, l = lane & 31;
    int row = blockIdx.x * 8 + wave * 2 + sub;
    const float* xr = X + (size_t)row * 128;
    const float* wr = Wo + (size_t)l * 128;
    float acc = 0.f;
    #pragma unroll
    for (int k = 0; k < 128; k += 4) {
        float4 x4 = *(const float4*)(xr + k);
        float4 w4 = *(const float4*)(wr + k);
        acc += x4.x * w4.x + x4.y * w4.y + x4.z * w4.z + x4.w * w4.w;
    }
    float logit = acc + bo[l];
    logits[(size_t)row * 32 + l] = logit;
    float mx = logit;
    #pragma unroll
    for (int off = 16; off; off >>= 1) mx = fmaxf(mx, __shfl_xor(mx, off, 32));
    float e = __expf(logit - mx);
    float se = e;
    #pragma unroll
    for (int off = 16; off; off >>= 1) se += __shfl_xor(se, off, 32);
    int tgt = targets[row];
    float lt = __shfl(logit, tgt, 32);
    if (l == 0) nllBuf[row] = logf(se) + mx - lt;
}

// ---------------- reduce 16384 NLLs -> mean (double accumulation) ----------------
__global__ __launch_bounds__(256) void loss_reduce_kernel(const float* __restrict__ nllBuf,
                                                          float* __restrict__ out) {
    int t = threadIdx.x;
    double s = 0.0;
    #pragma unroll
    for (int i = 0; i < 64; i++) s += (double)nllBuf[t * 64 + i];
    __shared__ double sh[256];
    sh[t] = s;
    __syncthreads();
    for (int off = 128; off; off >>= 1) {
        if (t < off) sh[t] += sh[t + off];
        __syncthreads();
    }
    if (t == 0) out[0] = (float)(sh[0] * (1.0 / (double)BM));
}

extern "C" void kernel_launch(void* const* d_in, const int* in_sizes, int n_in,
                              void* d_out, int out_size, void* d_ws, size_t ws_size,
                              hipStream_t stream) {
    const int*   idx       = (const int*)d_in[0];
    const int*   targets   = (const int*)d_in[1];
    const float* emb       = (const float*)d_in[2];
    const float* rms_scale = (const float*)d_in[3];
    const float* Wq        = (const float*)d_in[4];
    const float* Wk        = (const float*)d_in[5];
    const float* Wv        = (const float*)d_in[6];
    const float* in_w      = (const float*)d_in[7];
    const float* in_b      = (const float*)d_in[8];
    const float* out_pw    = (const float*)d_in[9];
    const float* out_pb    = (const float*)d_in[10];
    const float* lin_w     = (const float*)d_in[11];
    const float* lin_b     = (const float*)d_in[12];
    const float* out_w     = (const float*)d_in[13];
    const float* out_b     = (const float*)d_in[14];
    float* out = (float*)d_out;

    char* base = (char*)d_ws;
    const size_t MB = 1024 * 1024;
    float*     xbuf   = (float*)base;                        // 0..8MB   (then Qp/Kp, then x2n)
    float*     xnorm  = (float*)(base + 8 * MB);             // 8..16MB  (alive thru out_proj resid)
    _Float16*  XQKVh  = (_Float16*)(base + 16 * MB);         // 16..28MB (f16 roped QKV)
    _Float16*  Qp     = (_Float16*)base;                     // 0..4MB
    _Float16*  Kp     = (_Float16*)(base + 4 * MB);          // 4..8MB
    _Float16*  Vp     = (_Float16*)(base + 28 * MB);         // 28..32MB
    float*     Obuf   = (float*)(base + 16 * MB);            // 16..24MB (attn out; dead at logits)
    float*     xres   = (float*)(base + 24 * MB);            // 24..32MB
    float*     x2n    = (float*)base;                        // 0..8MB
    float*     ffo    = (float*)(base + 32 * MB);            // 32..40MB
    float*     nllBuf = (float*)(base + 16 * MB);            // reuse dead Obuf (64 KB)
    float*     cosT   = (float*)(base + 40 * MB);
    float*     sinT   = cosT + Mm * 64;
    float*     accs   = sinT + Mm * 64;                      // ssq[8], ssq2[8]
    _Float16*  Wh     = (_Float16*)(accs + 24);              // 8 x 128x128 f16

    (void)hipMemsetAsync(accs, 0, 96, stream);

    rope_table_kernel<<<Mm * 64 / 256, 256, 0, stream>>>(cosT, sinT);
    wcvt_kernel<<<131072 / 256, 256, 0, stream>>>(Wq, Wk, Wv, in_w, out_pw, lin_w, Wh);
    gather_sumsq_kernel<<<NEL / 256, 256, 0, stream>>>(idx, emb, xbuf, accs);
    normscale_kernel<<<NEL / 256, 256, 0, stream>>>(xbuf, rms_scale, accs, xnorm);

    gemm_qkv_kernel<<<dim3(BM / 32, 3), 256, 0, stream>>>(xnorm, Wh, cosT, sinT, XQKVh);
    gemm_inproj_kernel<<<dim3(BM / 32, 3), 256, 0, stream>>>(XQKVh, Wh + 3 * 16384, in_b, Qp, Kp, Vp);

    attn_kernel<<<64 * 64 / 4, 256, 0, stream>>>(Qp, Kp, Vp, Obuf);

    gemm_ep_kernel<<<BM / 32, 256, 0, stream>>>(Obuf, Wh + 6 * 16384, out_pb, xnorm, xres, accs + 8, 0);
    normscale_kernel<<<NEL / 256, 256, 0, stream>>>(xres, rms_scale, accs + 8, x2n);
    gemm_ep_kernel<<<BM / 32, 256, 0, stream>>>(x2n, Wh + 7 * 16384, lin_b, xres, ffo, nullptr, 1);

    logits_loss_kernel<<<BM / 8, 256, 0, stream>>>(ffo, out_w, out_b, targets, out, nllBuf);
    loss_reduce_kernel<<<1, 256, 0, stream>>>(nllBuf, out + (size_t)BM * Vv);
}

// Round 7
// 282.815 us; speedup vs baseline: 9.5336x; 1.4476x over previous
//
#include <hip/hip_runtime.h>
#include <hip/hip_bf16.h>
#include <math.h>

#define Vv   32
#define Dd   128
#define Hh   8
#define Bb   8
#define Mm   2048
#define BM   (Bb*Mm)        // 16384
#define NEL  (BM*Dd)        // 2097152

typedef _Float16 half4_t __attribute__((ext_vector_type(4)));
typedef float    float4_t __attribute__((ext_vector_type(4)));
#define MFMA16 __builtin_amdgcn_mfma_f32_16x16x16f16

// ---------------- RoPE tables ----------------
__global__ __launch_bounds__(256) void rope_table_kernel(float* __restrict__ cosT,
                                                         float* __restrict__ sinT) {
    int gid = blockIdx.x * 256 + threadIdx.x;
    int i = gid & 63;
    int m = gid >> 6;
    float ex = -2.0f * ((float)i - 1.0f) / 128.0f;
    float base = expf(ex * 9.210340371976184f);
    float ang = (float)m * base;
    cosT[gid] = cosf(ang);
    sinT[gid] = sinf(ang);
}

// ---------------- weights -> f16 (0=Wq 1=Wk 2=Wv 3..5=in_w 6=out_pw 7=lin_w) ----------------
__global__ __launch_bounds__(256) void wcvt_kernel(const float* __restrict__ Wq,
                                                   const float* __restrict__ Wk,
                                                   const float* __restrict__ Wv,
                                                   const float* __restrict__ in_w,
                                                   const float* __restrict__ out_pw,
                                                   const float* __restrict__ lin_w,
                                                   _Float16* __restrict__ Wh) {
    int gid = blockIdx.x * 256 + threadIdx.x;
    int seg = gid >> 14, off = gid & 16383;
    const float* src =
        seg == 0 ? Wq : seg == 1 ? Wk : seg == 2 ? Wv :
        seg < 6 ? in_w + (size_t)(seg - 3) * 16384 :
        seg == 6 ? out_pw : lin_w;
    Wh[gid] = (_Float16)src[off];
}

// ---------------- embedding gather (float4/thread) + per-BLOCK ssq partial ----------------
// grid = NEL/1024 = 2048 blocks; block covers 1024 elements (one batch spans 256 blocks)
__global__ __launch_bounds__(256) void gather_sumsq_kernel(const int* __restrict__ idx,
                                                           const float* __restrict__ emb,
                                                           float* __restrict__ X,
                                                           float* __restrict__ partials) {
    int gid = blockIdx.x * 256 + threadIdx.x;       // NEL/4 total
    int t4 = gid & 31;                              // float4 slot within 128-col row
    int token = gid >> 5;
    float4 x = *(const float4*)(emb + (size_t)idx[token] * 128 + t4 * 4);
    *(float4*)(X + (size_t)gid * 4) = x;
    float v = x.x * x.x + x.y * x.y + x.z * x.z + x.w * x.w;
    #pragma unroll
    for (int off = 32; off; off >>= 1) v += __shfl_xor(v, off);
    __shared__ float wsum[4];
    int lane = threadIdx.x & 63, wave = threadIdx.x >> 6;
    if (lane == 0) wsum[wave] = v;
    __syncthreads();
    if (threadIdx.x == 0) partials[blockIdx.x] = wsum[0] + wsum[1] + wsum[2] + wsum[3];
}

// ---------------- partials[b*count..] -> inv[b] = 512/sqrt(sum) ----------------
__global__ __launch_bounds__(256) void ssq_reduce_kernel(const float* __restrict__ partials,
                                                         int count,
                                                         float* __restrict__ inv) {
    int b = blockIdx.x, t = threadIdx.x;
    float v = (t < count) ? partials[b * count + t] : 0.f;
    #pragma unroll
    for (int off = 32; off; off >>= 1) v += __shfl_xor(v, off);
    __shared__ float wsum[4];
    int lane = t & 63, wave = t >> 6;
    if (lane == 0) wsum[wave] = v;
    __syncthreads();
    if (t == 0) inv[b] = 512.0f / sqrtf(wsum[0] + wsum[1] + wsum[2] + wsum[3]);
}

// ---------------- x * inv[b] * scale[m,d] ----------------
__global__ __launch_bounds__(256) void normscale_kernel(const float* __restrict__ X,
                                                        const float* __restrict__ scale,
                                                        const float* __restrict__ inv,
                                                        float* __restrict__ out) {
    int gid = blockIdx.x * 256 + threadIdx.x;
    int b = gid >> 18;
    int md = gid & ((Mm * Dd) - 1);
    out[gid] = X[gid] * inv[b] * scale[md];
}

// ---------------- QKV projection GEMM + fused RoPE -> f16 row-major [16384][384] ----------------
__global__ __launch_bounds__(256) void gemm_qkv_kernel(const float* __restrict__ A,
                                                       const _Float16* __restrict__ Wh,
                                                       const float* __restrict__ cosT,
                                                       const float* __restrict__ sinT,
                                                       _Float16* __restrict__ outh) {
    int wave = threadIdx.x >> 6, lane = threadIdx.x & 63;
    int r = lane & 15, c = lane >> 4;
    int row0 = blockIdx.x * 32 + (wave & 1) * 16;
    int n0 = blockIdx.y * 128 + (wave >> 1) * 64;
    const float* Ar = A + (size_t)(row0 + r) * 128 + 4 * c;
    float4 a4[8];
    #pragma unroll
    for (int kk = 0; kk < 8; kk++) a4[kk] = *(const float4*)(Ar + kk * 16);
    half4_t af[8];
    #pragma unroll
    for (int kk = 0; kk < 8; kk++) {
        af[kk][0] = (_Float16)a4[kk].x; af[kk][1] = (_Float16)a4[kk].y;
        af[kk][2] = (_Float16)a4[kk].z; af[kk][3] = (_Float16)a4[kk].w;
    }
    float4_t acc[4];
    #pragma unroll
    for (int t = 0; t < 4; t++) acc[t] = (float4_t){0.f, 0.f, 0.f, 0.f};
    #pragma unroll
    for (int kk = 0; kk < 8; kk++) {
        #pragma unroll
        for (int t = 0; t < 4; t++) {
            half4_t wf = *(const half4_t*)(Wh + (size_t)(n0 + t * 16 + r) * 128 + kk * 16 + 4 * c);
            acc[t] = MFMA16(af[kk], wf, acc[t], 0, 0, 0);
        }
    }
    #pragma unroll
    for (int t = 0; t < 4; t++) {
        int n = n0 + t * 16 + r;
        int ci = (n >> 1) & 63;
        #pragma unroll
        for (int reg = 0; reg < 4; reg++) {
            int row = row0 + 4 * c + reg;
            int m = row & (Mm - 1);
            float v = acc[t][reg];
            float vp = __shfl_xor(v, 1);                 // pair column n^1 lives in lane^1
            float cs = cosT[m * 64 + ci], sn = sinT[m * 64 + ci];
            v = (n & 1) ? (-vp * sn + v * cs) : (v * cs + vp * sn);
            outh[(size_t)row * 384 + n] = (_Float16)v;
        }
    }
}

// ---------------- in_proj GEMM (A f16 [16384][384]) -> tile-blocked Qp/Kp/Vp f16 ----------------
// Qp/Kp: [bh][tile][token&15][d]  (512B tiles);  Vp: [bh][tile][d][token&15]
__global__ __launch_bounds__(256) void gemm_inproj_kernel(const _Float16* __restrict__ Ah,
                                                          const _Float16* __restrict__ Wh3,
                                                          const float* __restrict__ bias,
                                                          _Float16* __restrict__ Qp,
                                                          _Float16* __restrict__ Kp,
                                                          _Float16* __restrict__ Vp) {
    int wave = threadIdx.x >> 6, lane = threadIdx.x & 63;
    int r = lane & 15, c = lane >> 4;
    int row0 = blockIdx.x * 32 + (wave & 1) * 16;
    int seg = blockIdx.y;
    int n0 = seg * 128 + (wave >> 1) * 64;
    const _Float16* Ar = Ah + (size_t)(row0 + r) * 384 + seg * 128 + 4 * c;
    half4_t af[8];
    #pragma unroll
    for (int kk = 0; kk < 8; kk++) af[kk] = *(const half4_t*)(Ar + kk * 16);
    float4_t acc[4];
    #pragma unroll
    for (int t = 0; t < 4; t++) acc[t] = (float4_t){0.f, 0.f, 0.f, 0.f};
    #pragma unroll
    for (int kk = 0; kk < 8; kk++) {
        #pragma unroll
        for (int t = 0; t < 4; t++) {
            half4_t wf = *(const half4_t*)(Wh3 + (size_t)(n0 + t * 16 + r) * 128 + kk * 16 + 4 * c);
            acc[t] = MFMA16(af[kk], wf, acc[t], 0, 0, 0);
        }
    }
    int b = row0 >> 11;
    int t16 = (row0 & 2047) >> 4;
    int hh = (n0 & 127) >> 4;                            // 0 or 4
    _Float16* dst = seg == 0 ? Qp : seg == 1 ? Kp : Vp;
    #pragma unroll
    for (int t = 0; t < 4; t++) {
        int h = hh + t;
        size_t tb = ((size_t)(b * 8 + h) * 128 + t16) * 256;
        float bv = bias[n0 + t * 16 + r];
        #pragma unroll
        for (int reg = 0; reg < 4; reg++) {
            float v = acc[t][reg] + bv;
            int key = 4 * c + reg;                       // token index within tile
            if (seg < 2) dst[tb + key * 16 + r] = (_Float16)v;   // [token][d=r]
            else         dst[tb + r * 16 + key] = (_Float16)v;   // [d=r][token]
        }
    }
}

// ---------------- epilogue GEMM: out f32 = A f32 @ W128^T + bias (relu?)(+resid)(per-block ssq partial) ----------------
__global__ __launch_bounds__(256) void gemm_ep_kernel(const float* __restrict__ A,
                                                      const _Float16* __restrict__ W128,
                                                      const float* __restrict__ bias,
                                                      const float* __restrict__ resid,
                                                      float* __restrict__ out,
                                                      float* __restrict__ partials,
                                                      int relu) {
    int wave = threadIdx.x >> 6, lane = threadIdx.x & 63;
    int r = lane & 15, c = lane >> 4;
    int row0 = blockIdx.x * 32 + (wave & 1) * 16;
    int n0 = (wave >> 1) * 64;
    const float* Ar = A + (size_t)(row0 + r) * 128 + 4 * c;
    float4 a4[8];
    #pragma unroll
    for (int kk = 0; kk < 8; kk++) a4[kk] = *(const float4*)(Ar + kk * 16);
    half4_t af[8];
    #pragma unroll
    for (int kk = 0; kk < 8; kk++) {
        af[kk][0] = (_Float16)a4[kk].x; af[kk][1] = (_Float16)a4[kk].y;
        af[kk][2] = (_Float16)a4[kk].z; af[kk][3] = (_Float16)a4[kk].w;
    }
    float4_t acc[4];
    #pragma unroll
    for (int t = 0; t < 4; t++) acc[t] = (float4_t){0.f, 0.f, 0.f, 0.f};
    #pragma unroll
    for (int kk = 0; kk < 8; kk++) {
        #pragma unroll
        for (int t = 0; t < 4; t++) {
            half4_t wf = *(const half4_t*)(W128 + (size_t)(n0 + t * 16 + r) * 128 + kk * 16 + 4 * c);
            acc[t] = MFMA16(af[kk], wf, acc[t], 0, 0, 0);
        }
    }
    float lssq = 0.f;
    #pragma unroll
    for (int t = 0; t < 4; t++) {
        int n = n0 + t * 16 + r;
        float bv = bias[n];
        #pragma unroll
        for (int reg = 0; reg < 4; reg++) {
            int row = row0 + 4 * c + reg;
            float v = acc[t][reg] + bv;
            if (relu) v = fmaxf(v, 0.f);
            if (resid) v += resid[(size_t)row * 128 + n];
            if (partials) lssq += v * v;
            out[(size_t)row * 128 + n] = v;
        }
    }
    if (partials) {
        #pragma unroll
        for (int off = 32; off; off >>= 1) lssq += __shfl_xor(lssq, off);
        __shared__ float wsum[4];
        if (lane == 0) wsum[wave] = lssq;
        __syncthreads();
        if (threadIdx.x == 0) partials[blockIdx.x] = wsum[0] + wsum[1] + wsum[2] + wsum[3];
    }
}

// ---------------- attention helpers ----------------
__device__ __forceinline__ half4_t attn_exps(float4_t st, float& ls) {
    float p0 = __expf(st[0] * 0.25f), p1 = __expf(st[1] * 0.25f);
    float p2 = __expf(st[2] * 0.25f), p3 = __expf(st[3] * 0.25f);
    ls += (p0 + p1) + (p2 + p3);
    half4_t pf;
    pf[0] = (_Float16)p0; pf[1] = (_Float16)p1;
    pf[2] = (_Float16)p2; pf[3] = (_Float16)p3;
    return pf;
}
__device__ __forceinline__ half4_t attn_exps_masked(float4_t st, float& ls, int r, int c) {
    float p0 = (4 * c + 0 <= r) ? __expf(st[0] * 0.25f) : 0.f;
    float p1 = (4 * c + 1 <= r) ? __expf(st[1] * 0.25f) : 0.f;
    float p2 = (4 * c + 2 <= r) ? __expf(st[2] * 0.25f) : 0.f;
    float p3 = (4 * c + 3 <= r) ? __expf(st[3] * 0.25f) : 0.f;
    ls += (p0 + p1) + (p2 + p3);
    half4_t pf;
    pf[0] = (_Float16)p0; pf[1] = (_Float16)p1;
    pf[2] = (_Float16)p2; pf[3] = (_Float16)p3;
    return pf;
}

// ---------------- MFMA flash attention, paired q-tiles (qa, 127-qa), shared K/V loads ----------------
__global__ __launch_bounds__(256) void attn_kernel(const _Float16* __restrict__ Qp,
                                                   const _Float16* __restrict__ Kp,
                                                   const _Float16* __restrict__ Vp,
                                                   float* __restrict__ O) {
    int wave = threadIdx.x >> 6, lane = threadIdx.x & 63;
    int wid = blockIdx.x * 4 + wave;
    int qa = wid & 63, bh = wid >> 6, qb = 127 - qa;
    int r = lane & 15, c = lane >> 4;
    int lofs = r * 16 + 4 * c;                      // every frag load: contiguous 512B/wave
    const _Float16* Kb = Kp + (size_t)bh * 32768 + lofs;
    const _Float16* Vb = Vp + (size_t)bh * 32768 + lofs;
    const _Float16* Qb = Qp + (size_t)bh * 32768 + lofs;
    half4_t qfa = *(const half4_t*)(Qb + qa * 256);
    half4_t qfb = *(const half4_t*)(Qb + qb * 256);
    float4_t zero = {0.f, 0.f, 0.f, 0.f};
    float4_t oa = zero, ob = zero;
    float lsa = 0.f, lsb = 0.f;

    int kt = 0;
    for (; kt + 2 <= qa; kt += 2) {                 // shared range: both q-tiles
        half4_t k0 = *(const half4_t*)(Kb + kt * 256);
        half4_t v0 = *(const half4_t*)(Vb + kt * 256);
        half4_t k1 = *(const half4_t*)(Kb + kt * 256 + 256);
        half4_t v1 = *(const half4_t*)(Vb + kt * 256 + 256);
        float4_t s0a = MFMA16(k0, qfa, zero, 0, 0, 0);
        float4_t s0b = MFMA16(k0, qfb, zero, 0, 0, 0);
        float4_t s1a = MFMA16(k1, qfa, zero, 0, 0, 0);
        float4_t s1b = MFMA16(k1, qfb, zero, 0, 0, 0);
        half4_t p0a = attn_exps(s0a, lsa);
        half4_t p0b = attn_exps(s0b, lsb);
        half4_t p1a = attn_exps(s1a, lsa);
        half4_t p1b = attn_exps(s1b, lsb);
        oa = MFMA16(p0a, v0, oa, 0, 0, 0);
        ob = MFMA16(p0b, v0, ob, 0, 0, 0);
        oa = MFMA16(p1a, v1, oa, 0, 0, 0);
        ob = MFMA16(p1b, v1, ob, 0, 0, 0);
    }
    if (kt < qa) {                                  // odd remainder of shared range
        half4_t k0 = *(const half4_t*)(Kb + kt * 256);
        half4_t v0 = *(const half4_t*)(Vb + kt * 256);
        float4_t sa = MFMA16(k0, qfa, zero, 0, 0, 0);
        float4_t sb = MFMA16(k0, qfb, zero, 0, 0, 0);
        half4_t pa = attn_exps(sa, lsa);
        half4_t pb = attn_exps(sb, lsb);
        oa = MFMA16(pa, v0, oa, 0, 0, 0);
        ob = MFMA16(pb, v0, ob, 0, 0, 0);
    }
    {                                               // kt == qa: diagonal for a, full for b
        half4_t k0 = *(const half4_t*)(Kb + qa * 256);
        half4_t v0 = *(const half4_t*)(Vb + qa * 256);
        float4_t sa = MFMA16(k0, qfa, zero, 0, 0, 0);
        float4_t sb = MFMA16(k0, qfb, zero, 0, 0, 0);
        half4_t pa = attn_exps_masked(sa, lsa, r, c);
        half4_t pb = attn_exps(sb, lsb);
        oa = MFMA16(pa, v0, oa, 0, 0, 0);
        ob = MFMA16(pb, v0, ob, 0, 0, 0);
    }
    for (kt = qa + 1; kt + 2 <= qb; kt += 2) {      // b-only range (even length, no tail)
        half4_t k0 = *(const half4_t*)(Kb + kt * 256);
        half4_t v0 = *(const half4_t*)(Vb + kt * 256);
        half4_t k1 = *(const half4_t*)(Kb + kt * 256 + 256);
        half4_t v1 = *(const half4_t*)(Vb + kt * 256 + 256);
        float4_t s0 = MFMA16(k0, qfb, zero, 0, 0, 0);
        float4_t s1 = MFMA16(k1, qfb, zero, 0, 0, 0);
        half4_t p0 = attn_exps(s0, lsb);
        half4_t p1 = attn_exps(s1, lsb);
        ob = MFMA16(p0, v0, ob, 0, 0, 0);
        ob = MFMA16(p1, v1, ob, 0, 0, 0);
    }
    {                                               // kt == qb: diagonal for b
        half4_t k0 = *(const half4_t*)(Kb + qb * 256);
        half4_t v0 = *(const half4_t*)(Vb + qb * 256);
        float4_t sb = MFMA16(k0, qfb, zero, 0, 0, 0);
        half4_t pb = attn_exps_masked(sb, lsb, r, c);
        ob = MFMA16(pb, v0, ob, 0, 0, 0);
    }
    lsa += __shfl_xor(lsa, 16); lsa += __shfl_xor(lsa, 32);
    lsb += __shfl_xor(lsb, 16); lsb += __shfl_xor(lsb, 32);
    int b = bh >> 3, h = bh & 7;
    #pragma unroll
    for (int reg = 0; reg < 4; reg++) {
        float la = __shfl(lsa, 4 * c + reg);
        float lb = __shfl(lsb, 4 * c + reg);
        O[(size_t)(b * Mm + qa * 16 + 4 * c + reg) * 128 + h * 16 + r] = oa[reg] / la;
        O[(size_t)(b * Mm + qb * 16 + 4 * c + reg) * 128 + h * 16 + r] = ob[reg] / lb;
    }
}

// ---------------- logits (V=32) + log_softmax + per-row NLL ----------------
__global__ __launch_bounds__(256) void logits_loss_kernel(const float* __restrict__ X,
                                                          const float* __restrict__ Wo,
                                                          const float* __restrict__ bo,
                                                          const int* __restrict__ targets,
                                                          float* __restrict__ logits,
                                                          float* __restrict__ nllBuf) {
    int wave = threadIdx.x >> 6, lane = threadIdx.x & 63;
    int sub = lane >> 5, l = lane & 31;
    int row = blockIdx.x * 8 + wave * 2 + sub;
    const float* xr = X + (size_t)row * 128;
    const float* wr = Wo + (size_t)l * 128;
    float acc = 0.f;
    #pragma unroll
    for (int k = 0; k < 128; k += 4) {
        float4 x4 = *(const float4*)(xr + k);
        float4 w4 = *(const float4*)(wr + k);
        acc += x4.x * w4.x + x4.y * w4.y + x4.z * w4.z + x4.w * w4.w;
    }
    float logit = acc + bo[l];
    logits[(size_t)row * 32 + l] = logit;
    float mx = logit;
    #pragma unroll
    for (int off = 16; off; off >>= 1) mx = fmaxf(mx, __shfl_xor(mx, off, 32));
    float e = __expf(logit - mx);
    float se = e;
    #pragma unroll
    for (int off = 16; off; off >>= 1) se += __shfl_xor(se, off, 32);
    int tgt = targets[row];
    float lt = __shfl(logit, tgt, 32);
    if (l == 0) nllBuf[row] = logf(se) + mx - lt;
}

// ---------------- reduce 16384 NLLs -> mean (double accumulation) ----------------
__global__ __launch_bounds__(256) void loss_reduce_kernel(const float* __restrict__ nllBuf,
                                                          float* __restrict__ out) {
    int t = threadIdx.x;
    double s = 0.0;
    #pragma unroll
    for (int i = 0; i < 64; i++) s += (double)nllBuf[t * 64 + i];
    __shared__ double sh[256];
    sh[t] = s;
    __syncthreads();
    for (int off = 128; off; off >>= 1) {
        if (t < off) sh[t] += sh[t + off];
        __syncthreads();
    }
    if (t == 0) out[0] = (float)(sh[0] * (1.0 / (double)BM));
}

extern "C" void kernel_launch(void* const* d_in, const int* in_sizes, int n_in,
                              void* d_out, int out_size, void* d_ws, size_t ws_size,
                              hipStream_t stream) {
    const int*   idx       = (const int*)d_in[0];
    const int*   targets   = (const int*)d_in[1];
    const float* emb       = (const float*)d_in[2];
    const float* rms_scale = (const float*)d_in[3];
    const float* Wq        = (const float*)d_in[4];
    const float* Wk        = (const float*)d_in[5];
    const float* Wv        = (const float*)d_in[6];
    const float* in_w      = (const float*)d_in[7];
    const float* in_b      = (const float*)d_in[8];
    const float* out_pw    = (const float*)d_in[9];
    const float* out_pb    = (const float*)d_in[10];
    const float* lin_w     = (const float*)d_in[11];
    const float* lin_b     = (const float*)d_in[12];
    const float* out_w     = (const float*)d_in[13];
    const float* out_b     = (const float*)d_in[14];
    float* out = (float*)d_out;

    char* base = (char*)d_ws;
    const size_t MB = 1024 * 1024;
    float*     xbuf   = (float*)base;                        // 0..8MB   (then Qp/Kp, then x2n)
    float*     xnorm  = (float*)(base + 8 * MB);             // 8..16MB  (alive thru out_proj resid)
    _Float16*  XQKVh  = (_Float16*)(base + 16 * MB);         // 16..28MB (f16 roped QKV)
    _Float16*  Qp     = (_Float16*)base;                     // 0..4MB
    _Float16*  Kp     = (_Float16*)(base + 4 * MB);          // 4..8MB
    _Float16*  Vp     = (_Float16*)(base + 28 * MB);         // 28..32MB
    float*     Obuf   = (float*)(base + 16 * MB);            // 16..24MB (attn out; dead at logits)
    float*     xres   = (float*)(base + 24 * MB);            // 24..32MB
    float*     x2n    = (float*)base;                        // 0..8MB
    float*     ffo    = (float*)(base + 32 * MB);            // 32..40MB
    float*     nllBuf = (float*)(base + 16 * MB);            // reuse dead Obuf (64 KB)
    float*     cosT   = (float*)(base + 40 * MB);
    float*     sinT   = cosT + Mm * 64;
    float*     part1  = sinT + Mm * 64;                      // 2048 floats (gather ssq partials)
    float*     part2  = part1 + 2048;                        // 512 floats (out_proj ssq partials)
    float*     inv1   = part2 + 512;                         // 8
    float*     inv2   = inv1 + 8;                            // 8
    _Float16*  Wh     = (_Float16*)(inv2 + 8);               // 8 x 128x128 f16

    rope_table_kernel<<<Mm * 64 / 256, 256, 0, stream>>>(cosT, sinT);
    wcvt_kernel<<<131072 / 256, 256, 0, stream>>>(Wq, Wk, Wv, in_w, out_pw, lin_w, Wh);
    gather_sumsq_kernel<<<NEL / 1024, 256, 0, stream>>>(idx, emb, xbuf, part1);
    ssq_reduce_kernel<<<8, 256, 0, stream>>>(part1, 256, inv1);
    normscale_kernel<<<NEL / 256, 256, 0, stream>>>(xbuf, rms_scale, inv1, xnorm);

    gemm_qkv_kernel<<<dim3(BM / 32, 3), 256, 0, stream>>>(xnorm, Wh, cosT, sinT, XQKVh);
    gemm_inproj_kernel<<<dim3(BM / 32, 3), 256, 0, stream>>>(XQKVh, Wh + 3 * 16384, in_b, Qp, Kp, Vp);

    attn_kernel<<<64 * 64 / 4, 256, 0, stream>>>(Qp, Kp, Vp, Obuf);

    gemm_ep_kernel<<<BM / 32, 256, 0, stream>>>(Obuf, Wh + 6 * 16384, out_pb, xnorm, xres, part2, 0);
    ssq_reduce_kernel<<<8, 256, 0, stream>>>(part2, 64, inv2);
    normscale_kernel<<<NEL / 256, 256, 0, stream>>>(xres, rms_scale, inv2, x2n);
    gemm_ep_kernel<<<BM / 32, 256, 0, stream>>>(x2n, Wh + 7 * 16384, lin_b, xres, ffo, nullptr, 1);

    logits_loss_kernel<<<BM / 8, 256, 0, stream>>>(ffo, out_w, out_b, targets, out, nllBuf);
    loss_reduce_kernel<<<1, 256, 0, stream>>>(nllBuf, out + (size_t)BM * Vv);
}

// Round 9
// 243.489 us; speedup vs baseline: 11.0734x; 1.1615x over previous
//
#include <hip/hip_runtime.h>
#include <hip/hip_bf16.h>
#include <math.h>

#define Vv   32
#define Dd   128
#define Hh   8
#define Bb   8
#define Mm   2048
#define BM   (Bb*Mm)        // 16384
#define NEL  (BM*Dd)        // 2097152

typedef _Float16 half4_t __attribute__((ext_vector_type(4)));
typedef __fp16   fp16x2  __attribute__((ext_vector_type(2)));
typedef float    float4_t __attribute__((ext_vector_type(4)));
#define MFMA16 __builtin_amdgcn_mfma_f32_16x16x16f16

#if __has_builtin(__builtin_amdgcn_exp2f)
__device__ __forceinline__ float fexp2(float x) { return __builtin_amdgcn_exp2f(x); }
#else
__device__ __forceinline__ float fexp2(float x) { return __expf(x * 0.6931471805599453f); }
#endif

// ---------------- prep: 8 weight mats + out_w -> f16, RoPE tables ----------------
__global__ __launch_bounds__(256) void prep_kernel(const float* __restrict__ Wq,
                                                   const float* __restrict__ Wk,
                                                   const float* __restrict__ Wv,
                                                   const float* __restrict__ in_w,
                                                   const float* __restrict__ out_pw,
                                                   const float* __restrict__ lin_w,
                                                   const float* __restrict__ out_w,
                                                   _Float16* __restrict__ Wh,
                                                   float* __restrict__ cosT,
                                                   float* __restrict__ sinT) {
    int gid = blockIdx.x * 256 + threadIdx.x;       // 1040*256 = 266240
    if (gid < 135168) {
        const float* src; int off;
        if (gid < 131072) {
            int seg = gid >> 14; off = gid & 16383;
            src = seg == 0 ? Wq : seg == 1 ? Wk : seg == 2 ? Wv :
                  seg < 6 ? in_w + (size_t)(seg - 3) * 16384 :
                  seg == 6 ? out_pw : lin_w;
        } else { src = out_w; off = gid - 131072; }
        Wh[gid] = (_Float16)src[off];
    } else {
        int rid = gid - 135168;                     // 131072 = Mm*64
        int i = rid & 63, m = rid >> 6;
        float ex = -2.0f * ((float)i - 1.0f) / 128.0f;
        float basef = expf(ex * 9.210340371976184f);
        float ang = (float)m * basef;
        cosT[rid] = cosf(ang);
        sinT[rid] = sinf(ang);
    }
}

// ---------------- embedding gather -> f16 + per-block ssq partial ----------------
__global__ __launch_bounds__(256) void gather_sumsq_kernel(const int* __restrict__ idx,
                                                           const float* __restrict__ emb,
                                                           _Float16* __restrict__ Xh,
                                                           float* __restrict__ partials) {
    int gid = blockIdx.x * 256 + threadIdx.x;       // NEL/4; grid 2048
    int token = gid >> 5, t4 = gid & 31;
    float4 x = *(const float4*)(emb + (size_t)idx[token] * 128 + t4 * 4);
    half4_t o;
    o[0] = (_Float16)x.x; o[1] = (_Float16)x.y; o[2] = (_Float16)x.z; o[3] = (_Float16)x.w;
    *(half4_t*)(Xh + (size_t)gid * 4) = o;
    float v = x.x * x.x + x.y * x.y + x.z * x.z + x.w * x.w;
    #pragma unroll
    for (int off = 32; off; off >>= 1) v += __shfl_xor(v, off);
    __shared__ float wsum[4];
    int lane = threadIdx.x & 63, wave = threadIdx.x >> 6;
    if (lane == 0) wsum[wave] = v;
    __syncthreads();
    if (threadIdx.x == 0) partials[blockIdx.x] = wsum[0] + wsum[1] + wsum[2] + wsum[3];
}

// ---------------- partials -> inv[b] = 512/sqrt(sum) ----------------
__global__ __launch_bounds__(256) void ssq_reduce_kernel(const float* __restrict__ partials,
                                                         int count,
                                                         float* __restrict__ inv) {
    int b = blockIdx.x, t = threadIdx.x;
    float v = (t < count) ? partials[b * count + t] : 0.f;
    #pragma unroll
    for (int off = 32; off; off >>= 1) v += __shfl_xor(v, off);
    __shared__ float wsum[4];
    int lane = t & 63, wave = t >> 6;
    if (lane == 0) wsum[wave] = v;
    __syncthreads();
    if (t == 0) inv[b] = 512.0f / sqrtf(wsum[0] + wsum[1] + wsum[2] + wsum[3]);
}

// ---------------- normscale: f16 in -> f16 out ----------------
__global__ __launch_bounds__(256) void normscale_h_kernel(const _Float16* __restrict__ Xh,
                                                          const float* __restrict__ scale,
                                                          const float* __restrict__ inv,
                                                          _Float16* __restrict__ outh) {
    int gid = blockIdx.x * 256 + threadIdx.x;       // NEL/4
    float iv = inv[gid >> 16];
    const float* sp = scale + (size_t)((gid >> 5) & 2047) * 128 + (gid & 31) * 4;
    float4 s4 = *(const float4*)sp;
    half4_t x = *(const half4_t*)(Xh + (size_t)gid * 4);
    half4_t o;
    o[0] = (_Float16)((float)x[0] * iv * s4.x);
    o[1] = (_Float16)((float)x[1] * iv * s4.y);
    o[2] = (_Float16)((float)x[2] * iv * s4.z);
    o[3] = (_Float16)((float)x[3] * iv * s4.w);
    *(half4_t*)(outh + (size_t)gid * 4) = o;
}

// ---------------- normscale: f32 in -> f16 out ----------------
__global__ __launch_bounds__(256) void normscale_f_kernel(const float* __restrict__ X,
                                                          const float* __restrict__ scale,
                                                          const float* __restrict__ inv,
                                                          _Float16* __restrict__ outh) {
    int gid = blockIdx.x * 256 + threadIdx.x;       // NEL/4
    float iv = inv[gid >> 16];
    const float* sp = scale + (size_t)((gid >> 5) & 2047) * 128 + (gid & 31) * 4;
    float4 s4 = *(const float4*)sp;
    float4 x = *(const float4*)(X + (size_t)gid * 4);
    half4_t o;
    o[0] = (_Float16)(x.x * iv * s4.x);
    o[1] = (_Float16)(x.y * iv * s4.y);
    o[2] = (_Float16)(x.z * iv * s4.z);
    o[3] = (_Float16)(x.w * iv * s4.w);
    *(half4_t*)(outh + (size_t)gid * 4) = o;
}

// ---------------- QKV projection + fused RoPE: xnh f16 @ (Wq;Wk;Wv)^T -> f16 [16384][384] ----------------
// grid 1024; block = 16 rows; wave w: cols w*96..w*96+95 (6 tiles)
__global__ __launch_bounds__(256) void gemm_qkv_kernel(const _Float16* __restrict__ Ah,
                                                       const _Float16* __restrict__ Wh,
                                                       const float* __restrict__ cosT,
                                                       const float* __restrict__ sinT,
                                                       _Float16* __restrict__ outh) {
    int wave = threadIdx.x >> 6, lane = threadIdx.x & 63;
    int r = lane & 15, c = lane >> 4;
    int row0 = blockIdx.x * 16;
    int nb = wave * 96;
    const _Float16* Ar = Ah + (size_t)(row0 + r) * 128 + 4 * c;
    half4_t af[8];
    #pragma unroll
    for (int kk = 0; kk < 8; kk++) af[kk] = *(const half4_t*)(Ar + kk * 16);
    float4_t acc[6];
    #pragma unroll
    for (int t = 0; t < 6; t++) acc[t] = (float4_t){0.f, 0.f, 0.f, 0.f};
    #pragma unroll
    for (int kk = 0; kk < 8; kk++) {
        #pragma unroll
        for (int t = 0; t < 6; t++) {
            half4_t wf = *(const half4_t*)(Wh + (size_t)(nb + t * 16 + r) * 128 + kk * 16 + 4 * c);
            acc[t] = MFMA16(af[kk], wf, acc[t], 0, 0, 0);
        }
    }
    #pragma unroll
    for (int t = 0; t < 6; t++) {
        int n = nb + t * 16 + r;
        int ci = (n & 127) >> 1;
        #pragma unroll
        for (int reg = 0; reg < 4; reg++) {
            int row = row0 + 4 * c + reg;
            int m = row & (Mm - 1);
            float v = acc[t][reg];
            float vp = __shfl_xor(v, 1);
            float cs = cosT[m * 64 + ci], sn = sinT[m * 64 + ci];
            v = (n & 1) ? (-vp * sn + v * cs) : (v * cs + vp * sn);
            outh[(size_t)row * 384 + n] = (_Float16)v;
        }
    }
}

// ---------------- in_proj GEMM -> tile-blocked Qp/Kp/Vp f16 ----------------
// grid (1024, 3); block 16 rows; wave w: 2 col-tiles (32 cols)
__global__ __launch_bounds__(256) void gemm_inproj_kernel(const _Float16* __restrict__ Ah,
                                                          const _Float16* __restrict__ Wh3,
                                                          const float* __restrict__ bias,
                                                          _Float16* __restrict__ Qp,
                                                          _Float16* __restrict__ Kp,
                                                          _Float16* __restrict__ Vp) {
    int wave = threadIdx.x >> 6, lane = threadIdx.x & 63;
    int r = lane & 15, c = lane >> 4;
    int row0 = blockIdx.x * 16;
    int seg = blockIdx.y;
    int n0 = seg * 128 + wave * 32;
    const _Float16* Ar = Ah + (size_t)(row0 + r) * 384 + seg * 128 + 4 * c;
    half4_t af[8];
    #pragma unroll
    for (int kk = 0; kk < 8; kk++) af[kk] = *(const half4_t*)(Ar + kk * 16);
    float4_t acc[2];
    acc[0] = (float4_t){0.f, 0.f, 0.f, 0.f};
    acc[1] = (float4_t){0.f, 0.f, 0.f, 0.f};
    #pragma unroll
    for (int kk = 0; kk < 8; kk++) {
        #pragma unroll
        for (int t = 0; t < 2; t++) {
            half4_t wf = *(const half4_t*)(Wh3 + (size_t)(n0 + t * 16 + r) * 128 + kk * 16 + 4 * c);
            acc[t] = MFMA16(af[kk], wf, acc[t], 0, 0, 0);
        }
    }
    int b = row0 >> 11;
    int t16 = (row0 & 2047) >> 4;
    _Float16* dst = seg == 0 ? Qp : seg == 1 ? Kp : Vp;
    #pragma unroll
    for (int t = 0; t < 2; t++) {
        int h = wave * 2 + t;
        size_t tb = ((size_t)(b * 8 + h) * 128 + t16) * 256;
        float bv = bias[n0 + t * 16 + r];
        #pragma unroll
        for (int reg = 0; reg < 4; reg++) {
            float v = acc[t][reg] + bv;
            int key = 4 * c + reg;
            if (seg < 2) dst[tb + key * 16 + r] = (_Float16)v;   // [token][d=r]
            else         dst[tb + r * 16 + key] = (_Float16)v;   // [d=r][token]
        }
    }
}

// ---------------- out_proj: Obuf f32 @ W^T + bias + resid(xnh) -> xres f32, ssq partials ----------------
__global__ __launch_bounds__(256) void gemm_ep1_kernel(const float* __restrict__ A,
                                                       const _Float16* __restrict__ W6,
                                                       const float* __restrict__ bias,
                                                       const _Float16* __restrict__ xnh,
                                                       float* __restrict__ xres,
                                                       float* __restrict__ partials) {
    int wave = threadIdx.x >> 6, lane = threadIdx.x & 63;
    int r = lane & 15, c = lane >> 4;
    int row0 = blockIdx.x * 16;
    int n0 = wave * 32;
    const float* Ar = A + (size_t)(row0 + r) * 128 + 4 * c;
    half4_t af[8];
    #pragma unroll
    for (int kk = 0; kk < 8; kk++) {
        float4 a4 = *(const float4*)(Ar + kk * 16);
        af[kk][0] = (_Float16)a4.x; af[kk][1] = (_Float16)a4.y;
        af[kk][2] = (_Float16)a4.z; af[kk][3] = (_Float16)a4.w;
    }
    float4_t acc[2];
    acc[0] = (float4_t){0.f, 0.f, 0.f, 0.f};
    acc[1] = (float4_t){0.f, 0.f, 0.f, 0.f};
    #pragma unroll
    for (int kk = 0; kk < 8; kk++) {
        #pragma unroll
        for (int t = 0; t < 2; t++) {
            half4_t wf = *(const half4_t*)(W6 + (size_t)(n0 + t * 16 + r) * 128 + kk * 16 + 4 * c);
            acc[t] = MFMA16(af[kk], wf, acc[t], 0, 0, 0);
        }
    }
    float lssq = 0.f;
    #pragma unroll
    for (int t = 0; t < 2; t++) {
        int n = n0 + t * 16 + r;
        float bv = bias[n];
        #pragma unroll
        for (int reg = 0; reg < 4; reg++) {
            int row = row0 + 4 * c + reg;
            float v = acc[t][reg] + bv + (float)xnh[(size_t)row * 128 + n];
            lssq += v * v;
            xres[(size_t)row * 128 + n] = v;
        }
    }
    #pragma unroll
    for (int off = 32; off; off >>= 1) lssq += __shfl_xor(lssq, off);
    __shared__ float wsum[4];
    if (lane == 0) wsum[wave] = lssq;
    __syncthreads();
    if (threadIdx.x == 0) partials[blockIdx.x] = wsum[0] + wsum[1] + wsum[2] + wsum[3];
}

// ---------------- FFN: x2nh f16 @ W^T + bias, relu, + resid(xres f32) -> ffoh f16 ----------------
__global__ __launch_bounds__(256) void gemm_ep2_kernel(const _Float16* __restrict__ Ah,
                                                       const _Float16* __restrict__ W7,
                                                       const float* __restrict__ bias,
                                                       const float* __restrict__ xres,
                                                       _Float16* __restrict__ ffoh) {
    int wave = threadIdx.x >> 6, lane = threadIdx.x & 63;
    int r = lane & 15, c = lane >> 4;
    int row0 = blockIdx.x * 16;
    int n0 = wave * 32;
    const _Float16* Ar = Ah + (size_t)(row0 + r) * 128 + 4 * c;
    half4_t af[8];
    #pragma unroll
    for (int kk = 0; kk < 8; kk++) af[kk] = *(const half4_t*)(Ar + kk * 16);
    float4_t acc[2];
    acc[0] = (float4_t){0.f, 0.f, 0.f, 0.f};
    acc[1] = (float4_t){0.f, 0.f, 0.f, 0.f};
    #pragma unroll
    for (int kk = 0; kk < 8; kk++) {
        #pragma unroll
        for (int t = 0; t < 2; t++) {
            half4_t wf = *(const half4_t*)(W7 + (size_t)(n0 + t * 16 + r) * 128 + kk * 16 + 4 * c);
            acc[t] = MFMA16(af[kk], wf, acc[t], 0, 0, 0);
        }
    }
    #pragma unroll
    for (int t = 0; t < 2; t++) {
        int n = n0 + t * 16 + r;
        float bv = bias[n];
        #pragma unroll
        for (int reg = 0; reg < 4; reg++) {
            int row = row0 + 4 * c + reg;
            float v = fmaxf(acc[t][reg] + bv, 0.f) + xres[(size_t)row * 128 + n];
            ffoh[(size_t)row * 128 + n] = (_Float16)v;
        }
    }
}

// ---------------- attention helpers ----------------
__device__ __forceinline__ half4_t attn_exps(float4_t st, float& ls) {
    float p0 = fexp2(st[0]), p1 = fexp2(st[1]);
    float p2 = fexp2(st[2]), p3 = fexp2(st[3]);
    ls += (p0 + p1) + (p2 + p3);
    fp16x2 lo = __builtin_amdgcn_cvt_pkrtz(p0, p1);
    fp16x2 hi = __builtin_amdgcn_cvt_pkrtz(p2, p3);
    half4_t pf;
    pf[0] = (_Float16)lo[0]; pf[1] = (_Float16)lo[1];
    pf[2] = (_Float16)hi[0]; pf[3] = (_Float16)hi[1];
    return pf;
}
__device__ __forceinline__ half4_t attn_exps_masked(float4_t st, float& ls, int r, int c) {
    float p0 = (4 * c + 0 <= r) ? fexp2(st[0]) : 0.f;
    float p1 = (4 * c + 1 <= r) ? fexp2(st[1]) : 0.f;
    float p2 = (4 * c + 2 <= r) ? fexp2(st[2]) : 0.f;
    float p3 = (4 * c + 3 <= r) ? fexp2(st[3]) : 0.f;
    ls += (p0 + p1) + (p2 + p3);
    fp16x2 lo = __builtin_amdgcn_cvt_pkrtz(p0, p1);
    fp16x2 hi = __builtin_amdgcn_cvt_pkrtz(p2, p3);
    half4_t pf;
    pf[0] = (_Float16)lo[0]; pf[1] = (_Float16)lo[1];
    pf[2] = (_Float16)hi[0]; pf[3] = (_Float16)hi[1];
    return pf;
}

// ---------------- MFMA flash attention, paired q-tiles, Q pre-scaled by 0.25*log2e ----------------
__global__ __launch_bounds__(256) void attn_kernel(const _Float16* __restrict__ Qp,
                                                   const _Float16* __restrict__ Kp,
                                                   const _Float16* __restrict__ Vp,
                                                   float* __restrict__ O) {
    int wave = threadIdx.x >> 6, lane = threadIdx.x & 63;
    int wid = blockIdx.x * 4 + wave;
    int qa = wid & 63, bh = wid >> 6, qb = 127 - qa;
    int r = lane & 15, c = lane >> 4;
    int lofs = r * 16 + 4 * c;
    const _Float16* Kb = Kp + (size_t)bh * 32768 + lofs;
    const _Float16* Vb = Vp + (size_t)bh * 32768 + lofs;
    const _Float16* Qb = Qp + (size_t)bh * 32768 + lofs;
    half4_t qfa = *(const half4_t*)(Qb + qa * 256);
    half4_t qfb = *(const half4_t*)(Qb + qb * 256);
    const _Float16 qscale = (_Float16)0.36067376f;   // 0.25 * log2(e)
    qfa *= qscale;
    qfb *= qscale;
    float4_t zero = {0.f, 0.f, 0.f, 0.f};
    float4_t oa = zero, ob = zero;
    float lsa = 0.f, lsb = 0.f;

    int kt = 0;
    for (; kt + 2 <= qa; kt += 2) {
        half4_t k0 = *(const half4_t*)(Kb + kt * 256);
        half4_t v0 = *(const half4_t*)(Vb + kt * 256);
        half4_t k1 = *(const half4_t*)(Kb + kt * 256 + 256);
        half4_t v1 = *(const half4_t*)(Vb + kt * 256 + 256);
        float4_t s0a = MFMA16(k0, qfa, zero, 0, 0, 0);
        float4_t s0b = MFMA16(k0, qfb, zero, 0, 0, 0);
        float4_t s1a = MFMA16(k1, qfa, zero, 0, 0, 0);
        float4_t s1b = MFMA16(k1, qfb, zero, 0, 0, 0);
        half4_t p0a = attn_exps(s0a, lsa);
        half4_t p0b = attn_exps(s0b, lsb);
        half4_t p1a = attn_exps(s1a, lsa);
        half4_t p1b = attn_exps(s1b, lsb);
        oa = MFMA16(p0a, v0, oa, 0, 0, 0);
        ob = MFMA16(p0b, v0, ob, 0, 0, 0);
        oa = MFMA16(p1a, v1, oa, 0, 0, 0);
        ob = MFMA16(p1b, v1, ob, 0, 0, 0);
    }
    if (kt < qa) {
        half4_t k0 = *(const half4_t*)(Kb + kt * 256);
        half4_t v0 = *(const half4_t*)(Vb + kt * 256);
        float4_t sa = MFMA16(k0, qfa, zero, 0, 0, 0);
        float4_t sb = MFMA16(k0, qfb, zero, 0, 0, 0);
        half4_t pa = attn_exps(sa, lsa);
        half4_t pb = attn_exps(sb, lsb);
        oa = MFMA16(pa, v0, oa, 0, 0, 0);
        ob = MFMA16(pb, v0, ob, 0, 0, 0);
    }
    {
        half4_t k0 = *(const half4_t*)(Kb + qa * 256);
        half4_t v0 = *(const half4_t*)(Vb + qa * 256);
        float4_t sa = MFMA16(k0, qfa, zero, 0, 0, 0);
        float4_t sb = MFMA16(k0, qfb, zero, 0, 0, 0);
        half4_t pa = attn_exps_masked(sa, lsa, r, c);
        half4_t pb = attn_exps(sb, lsb);
        oa = MFMA16(pa, v0, oa, 0, 0, 0);
        ob = MFMA16(pb, v0, ob, 0, 0, 0);
    }
    for (kt = qa + 1; kt + 2 <= qb; kt += 2) {
        half4_t k0 = *(const half4_t*)(Kb + kt * 256);
        half4_t v0 = *(const half4_t*)(Vb + kt * 256);
        half4_t k1 = *(const half4_t*)(Kb + kt * 256 + 256);
        half4_t v1 = *(const half4_t*)(Vb + kt * 256 + 256);
        float4_t s0 = MFMA16(k0, qfb, zero, 0, 0, 0);
        float4_t s1 = MFMA16(k1, qfb, zero, 0, 0, 0);
        half4_t p0 = attn_exps(s0, lsb);
        half4_t p1 = attn_exps(s1, lsb);
        ob = MFMA16(p0, v0, ob, 0, 0, 0);
        ob = MFMA16(p1, v1, ob, 0, 0, 0);
    }
    {
        half4_t k0 = *(const half4_t*)(Kb + qb * 256);
        half4_t v0 = *(const half4_t*)(Vb + qb * 256);
        float4_t sb = MFMA16(k0, qfb, zero, 0, 0, 0);
        half4_t pb = attn_exps_masked(sb, lsb, r, c);
        ob = MFMA16(pb, v0, ob, 0, 0, 0);
    }
    lsa += __shfl_xor(lsa, 16); lsa += __shfl_xor(lsa, 32);
    lsb += __shfl_xor(lsb, 16); lsb += __shfl_xor(lsb, 32);
    int b = bh >> 3, h = bh & 7;
    #pragma unroll
    for (int reg = 0; reg < 4; reg++) {
        float la = __shfl(lsa, 4 * c + reg);
        float lb = __shfl(lsb, 4 * c + reg);
        O[(size_t)(b * Mm + qa * 16 + 4 * c + reg) * 128 + h * 16 + r] = oa[reg] / la;
        O[(size_t)(b * Mm + qb * 16 + 4 * c + reg) * 128 + h * 16 + r] = ob[reg] / lb;
    }
}

// ---------------- MFMA logits (V=32) + log_softmax + per-row NLL ----------------
// grid 256 blocks; wave = 16 rows x 32 vocab cols (2 tiles)
__global__ __launch_bounds__(256) void logits_loss_kernel(const _Float16* __restrict__ Xh,
                                                          const _Float16* __restrict__ Wo16,
                                                          const float* __restrict__ bo,
                                                          const int* __restrict__ targets,
                                                          float* __restrict__ logits,
                                                          float* __restrict__ nllBuf) {
    int wave = threadIdx.x >> 6, lane = threadIdx.x & 63;
    int r = lane & 15, c = lane >> 4;
    int row0 = (blockIdx.x * 4 + wave) * 16;
    const _Float16* Ar = Xh + (size_t)(row0 + r) * 128 + 4 * c;
    half4_t af[8];
    #pragma unroll
    for (int kk = 0; kk < 8; kk++) af[kk] = *(const half4_t*)(Ar + kk * 16);
    float4_t acc[2];
    acc[0] = (float4_t){0.f, 0.f, 0.f, 0.f};
    acc[1] = (float4_t){0.f, 0.f, 0.f, 0.f};
    #pragma unroll
    for (int kk = 0; kk < 8; kk++) {
        #pragma unroll
        for (int t = 0; t < 2; t++) {
            half4_t wf = *(const half4_t*)(Wo16 + (size_t)(t * 16 + r) * 128 + kk * 16 + 4 * c);
            acc[t] = MFMA16(af[kk], wf, acc[t], 0, 0, 0);
        }
    }
    float b0 = bo[r], b1 = bo[r + 16];
    #pragma unroll
    for (int reg = 0; reg < 4; reg++) {
        int row = row0 + 4 * c + reg;
        float l0 = acc[0][reg] + b0;
        float l1 = acc[1][reg] + b1;
        logits[(size_t)row * 32 + r] = l0;
        logits[(size_t)row * 32 + 16 + r] = l1;
        float mx = fmaxf(l0, l1);
        #pragma unroll
        for (int off = 8; off; off >>= 1) mx = fmaxf(mx, __shfl_xor(mx, off));
        float se = __expf(l0 - mx) + __expf(l1 - mx);
        #pragma unroll
        for (int off = 8; off; off >>= 1) se += __shfl_xor(se, off);
        int tgt = targets[row];
        float sel = (tgt & 16) ? l1 : l0;
        float tval = __shfl(sel, (lane & 48) | (tgt & 15));
        if (r == 0) nllBuf[row] = logf(se) + mx - tval;
    }
}

// ---------------- reduce 16384 NLLs -> mean (double accumulation) ----------------
__global__ __launch_bounds__(256) void loss_reduce_kernel(const float* __restrict__ nllBuf,
                                                          float* __restrict__ out) {
    int t = threadIdx.x;
    double s = 0.0;
    #pragma unroll
    for (int i = 0; i < 64; i++) s += (double)nllBuf[t * 64 + i];
    __shared__ double sh[256];
    sh[t] = s;
    __syncthreads();
    for (int off = 128; off; off >>= 1) {
        if (t < off) sh[t] += sh[t + off];
        __syncthreads();
    }
    if (t == 0) out[0] = (float)(sh[0] * (1.0 / (double)BM));
}

extern "C" void kernel_launch(void* const* d_in, const int* in_sizes, int n_in,
                              void* d_out, int out_size, void* d_ws, size_t ws_size,
                              hipStream_t stream) {
    const int*   idx       = (const int*)d_in[0];
    const int*   targets   = (const int*)d_in[1];
    const float* emb       = (const float*)d_in[2];
    const float* rms_scale = (const float*)d_in[3];
    const float* Wq        = (const float*)d_in[4];
    const float* Wk        = (const float*)d_in[5];
    const float* Wv        = (const float*)d_in[6];
    const float* in_w      = (const float*)d_in[7];
    const float* in_b      = (const float*)d_in[8];
    const float* out_pw    = (const float*)d_in[9];
    const float* out_pb    = (const float*)d_in[10];
    const float* lin_w     = (const float*)d_in[11];
    const float* lin_b     = (const float*)d_in[12];
    const float* out_w     = (const float*)d_in[13];
    const float* out_b     = (const float*)d_in[14];
    float* out = (float*)d_out;

    char* base = (char*)d_ws;
    const size_t MB = 1024 * 1024;
    _Float16* xh16  = (_Float16*)base;                 // 0..4MB   gathered x (f16)
    _Float16* xnh   = (_Float16*)(base + 4 * MB);      // 4..8MB   normed x (f16; resid for out_proj)
    _Float16* XQKVh = (_Float16*)(base + 8 * MB);      // 8..20MB  roped QKV (f16)
    _Float16* Qp    = (_Float16*)(base + 20 * MB);     // 20..24MB
    _Float16* Kp    = (_Float16*)(base + 24 * MB);     // 24..28MB
    _Float16* Vp    = (_Float16*)(base + 28 * MB);     // 28..32MB
    float*    Obuf  = (float*)(base + 8 * MB);         // 8..16MB  attn out (XQKVh dead)
    float*    xres  = (float*)(base + 32 * MB);        // 32..40MB
    _Float16* x2nh  = (_Float16*)(base + 16 * MB);     // 16..20MB (Obuf tail region free after ep1)
    _Float16* ffoh  = (_Float16*)(base + 20 * MB);     // 20..24MB (Qp dead after attn)
    float*    nllBuf = (float*)(base + 24 * MB);       // 64KB (Kp dead after attn)
    float*    cosT  = (float*)(base + 40 * MB);        // 512KB
    float*    sinT  = cosT + Mm * 64;                  // 512KB
    float*    part1 = sinT + Mm * 64;                  // 2048
    float*    part2 = part1 + 2048;                    // 1024
    float*    inv1  = part2 + 1024;                    // 8
    float*    inv2  = inv1 + 8;                        // 8
    _Float16* Wh    = (_Float16*)(inv2 + 8);           // 135168 halves (8 mats + out_w)

    prep_kernel<<<1040, 256, 0, stream>>>(Wq, Wk, Wv, in_w, out_pw, lin_w, out_w, Wh, cosT, sinT);
    gather_sumsq_kernel<<<NEL / 1024, 256, 0, stream>>>(idx, emb, xh16, part1);
    ssq_reduce_kernel<<<8, 256, 0, stream>>>(part1, 256, inv1);
    normscale_h_kernel<<<NEL / 1024, 256, 0, stream>>>(xh16, rms_scale, inv1, xnh);

    gemm_qkv_kernel<<<BM / 16, 256, 0, stream>>>(xnh, Wh, cosT, sinT, XQKVh);
    gemm_inproj_kernel<<<dim3(BM / 16, 3), 256, 0, stream>>>(XQKVh, Wh + 3 * 16384, in_b, Qp, Kp, Vp);

    attn_kernel<<<64 * 64 / 4, 256, 0, stream>>>(Qp, Kp, Vp, Obuf);

    gemm_ep1_kernel<<<BM / 16, 256, 0, stream>>>(Obuf, Wh + 6 * 16384, out_pb, xnh, xres, part2);
    ssq_reduce_kernel<<<8, 256, 0, stream>>>(part2, 128, inv2);
    normscale_f_kernel<<<NEL / 1024, 256, 0, stream>>>(xres, rms_scale, inv2, x2nh);
    gemm_ep2_kernel<<<BM / 16, 256, 0, stream>>>(x2nh, Wh + 7 * 16384, lin_b, xres, ffoh);

    logits_loss_kernel<<<BM / 64, 256, 0, stream>>>(ffoh, Wh + 131072, out_b, targets, out, nllBuf);
    loss_reduce_kernel<<<1, 256, 0, stream>>>(nllBuf, out + (size_t)BM * Vv);
}

// Round 10
// 212.444 us; speedup vs baseline: 12.6916x; 1.1461x over previous
//
#include <hip/hip_runtime.h>
#include <hip/hip_bf16.h>
#include <math.h>

#define Vv   32
#define Dd   128
#define Hh   8
#define Bb   8
#define Mm   2048
#define BM   (Bb*Mm)        // 16384
#define NEL  (BM*Dd)        // 2097152
#define XNS  140            // LDS stride (halves) for 128-col tiles, bank-padded
#define QKS  396            // LDS stride (halves) for 384-col qkv tile, bank-padded

typedef _Float16 half4_t __attribute__((ext_vector_type(4)));
typedef _Float16 half8_t __attribute__((ext_vector_type(8)));
typedef __fp16   fp16x2  __attribute__((ext_vector_type(2)));
typedef float    float4_t __attribute__((ext_vector_type(4)));
#define MFMA16 __builtin_amdgcn_mfma_f32_16x16x16f16

#if __has_builtin(__builtin_amdgcn_exp2f)
__device__ __forceinline__ float fexp2(float x) { return __builtin_amdgcn_exp2f(x); }
#else
__device__ __forceinline__ float fexp2(float x) { return __expf(x * 0.6931471805599453f); }
#endif

// ---------------- prep: 8 weight mats + out_w -> f16, RoPE tables ----------------
__global__ __launch_bounds__(256) void prep_kernel(const float* __restrict__ Wq,
                                                   const float* __restrict__ Wk,
                                                   const float* __restrict__ Wv,
                                                   const float* __restrict__ in_w,
                                                   const float* __restrict__ out_pw,
                                                   const float* __restrict__ lin_w,
                                                   const float* __restrict__ out_w,
                                                   _Float16* __restrict__ Wh,
                                                   float* __restrict__ cosT,
                                                   float* __restrict__ sinT) {
    int gid = blockIdx.x * 256 + threadIdx.x;       // 1040*256 = 266240
    if (gid < 135168) {
        const float* src; int off;
        if (gid < 131072) {
            int seg = gid >> 14; off = gid & 16383;
            src = seg == 0 ? Wq : seg == 1 ? Wk : seg == 2 ? Wv :
                  seg < 6 ? in_w + (size_t)(seg - 3) * 16384 :
                  seg == 6 ? out_pw : lin_w;
        } else { src = out_w; off = gid - 131072; }
        Wh[gid] = (_Float16)src[off];
    } else {
        int rid = gid - 135168;                     // Mm*64 = 131072
        int i = rid & 63, m = rid >> 6;
        float ex = -2.0f * ((float)i - 1.0f) / 128.0f;
        float basef = expf(ex * 9.210340371976184f);
        float ang = (float)m * basef;
        cosT[rid] = cosf(ang);
        sinT[rid] = sinf(ang);
    }
}

// ---------------- embedding gather -> f16 + per-block ssq partial ----------------
__global__ __launch_bounds__(256) void gather_sumsq_kernel(const int* __restrict__ idx,
                                                           const float* __restrict__ emb,
                                                           _Float16* __restrict__ Xh,
                                                           float* __restrict__ partials) {
    int gid = blockIdx.x * 256 + threadIdx.x;       // NEL/4; grid 2048
    int token = gid >> 5, t4 = gid & 31;
    float4 x = *(const float4*)(emb + (size_t)idx[token] * 128 + t4 * 4);
    half4_t o;
    o[0] = (_Float16)x.x; o[1] = (_Float16)x.y; o[2] = (_Float16)x.z; o[3] = (_Float16)x.w;
    *(half4_t*)(Xh + (size_t)gid * 4) = o;
    float v = x.x * x.x + x.y * x.y + x.z * x.z + x.w * x.w;
    #pragma unroll
    for (int off = 32; off; off >>= 1) v += __shfl_xor(v, off);
    __shared__ float wsum[4];
    int lane = threadIdx.x & 63, wave = threadIdx.x >> 6;
    if (lane == 0) wsum[wave] = v;
    __syncthreads();
    if (threadIdx.x == 0) partials[blockIdx.x] = wsum[0] + wsum[1] + wsum[2] + wsum[3];
}

// ---------------- partials -> inv[b] = 512/sqrt(sum) ----------------
__global__ __launch_bounds__(256) void ssq_reduce_kernel(const float* __restrict__ partials,
                                                         int count,
                                                         float* __restrict__ inv) {
    int b = blockIdx.x, t = threadIdx.x;
    float v = (t < count) ? partials[b * count + t] : 0.f;
    #pragma unroll
    for (int off = 32; off; off >>= 1) v += __shfl_xor(v, off);
    __shared__ float wsum[4];
    int lane = t & 63, wave = t >> 6;
    if (lane == 0) wsum[wave] = v;
    __syncthreads();
    if (t == 0) inv[b] = 512.0f / sqrtf(wsum[0] + wsum[1] + wsum[2] + wsum[3]);
}

// ---------------- normscale: f32 in -> f16 out (second rms_norm) ----------------
__global__ __launch_bounds__(256) void normscale_f_kernel(const float* __restrict__ X,
                                                          const float* __restrict__ scale,
                                                          const float* __restrict__ inv,
                                                          _Float16* __restrict__ outh) {
    int gid = blockIdx.x * 256 + threadIdx.x;       // NEL/4
    float iv = inv[gid >> 16];
    const float* sp = scale + (size_t)((gid >> 5) & 2047) * 128 + (gid & 31) * 4;
    float4 s4 = *(const float4*)sp;
    float4 x = *(const float4*)(X + (size_t)gid * 4);
    half4_t o;
    o[0] = (_Float16)(x.x * iv * s4.x);
    o[1] = (_Float16)(x.y * iv * s4.y);
    o[2] = (_Float16)(x.z * iv * s4.z);
    o[3] = (_Float16)(x.w * iv * s4.w);
    *(half4_t*)(outh + (size_t)gid * 4) = o;
}

// ---------------- FUSED: normscale + QKV proj + RoPE + in_proj -> Qp/Kp/Vp ----------------
// grid 1024; block = 16 token rows; all A-operands staged through LDS (coalesced+padded).
__global__ __launch_bounds__(256) void gemm_qkvproj_kernel(const _Float16* __restrict__ xh,
                                                           const float* __restrict__ scale,
                                                           const float* __restrict__ inv,
                                                           const _Float16* __restrict__ Whqkv,
                                                           const _Float16* __restrict__ Whin,
                                                           const float* __restrict__ in_b,
                                                           const float* __restrict__ cosT,
                                                           const float* __restrict__ sinT,
                                                           _Float16* __restrict__ xnh,
                                                           _Float16* __restrict__ Qp,
                                                           _Float16* __restrict__ Kp,
                                                           _Float16* __restrict__ Vp) {
    __shared__ _Float16 xn[16 * XNS];
    __shared__ _Float16 qkv[16 * QKS];
    int tid = threadIdx.x;
    int row0 = blockIdx.x * 16;
    // ---- stage + rms-norm (coalesced: one half8 per thread) ----
    {
        int rw = tid >> 4, c8 = (tid & 15) * 8;
        float iv = inv[row0 >> 11];
        int m = (row0 + rw) & (Mm - 1);
        const _Float16* xp = xh + (size_t)(row0 + rw) * 128 + c8;
        half8_t x8 = *(const half8_t*)xp;
        const float* sp = scale + (size_t)m * 128 + c8;
        float4 s0 = *(const float4*)sp;
        float4 s1 = *(const float4*)(sp + 4);
        half8_t o8;
        o8[0] = (_Float16)((float)x8[0] * iv * s0.x);
        o8[1] = (_Float16)((float)x8[1] * iv * s0.y);
        o8[2] = (_Float16)((float)x8[2] * iv * s0.z);
        o8[3] = (_Float16)((float)x8[3] * iv * s0.w);
        o8[4] = (_Float16)((float)x8[4] * iv * s1.x);
        o8[5] = (_Float16)((float)x8[5] * iv * s1.y);
        o8[6] = (_Float16)((float)x8[6] * iv * s1.z);
        o8[7] = (_Float16)((float)x8[7] * iv * s1.w);
        *(half8_t*)(xn + rw * XNS + c8) = o8;
        *(half8_t*)(xnh + (size_t)(row0 + rw) * 128 + c8) = o8;
    }
    __syncthreads();
    int wave = tid >> 6, lane = tid & 63;
    int r = lane & 15, c = lane >> 4;
    int nb = wave * 96;
    // ---- phase 1: QKV = xn @ (Wq;Wk;Wv)^T, + RoPE, into qkv LDS ----
    {
        half4_t af[8];
        #pragma unroll
        for (int kk = 0; kk < 8; kk++)
            af[kk] = *(const half4_t*)(xn + r * XNS + kk * 16 + 4 * c);
        float4_t acc[6];
        #pragma unroll
        for (int t = 0; t < 6; t++) acc[t] = (float4_t){0.f, 0.f, 0.f, 0.f};
        #pragma unroll
        for (int kk = 0; kk < 8; kk++) {
            #pragma unroll
            for (int t = 0; t < 6; t++) {
                half4_t wf = *(const half4_t*)(Whqkv + (size_t)(nb + t * 16 + r) * 128 + kk * 16 + 4 * c);
                acc[t] = MFMA16(af[kk], wf, acc[t], 0, 0, 0);
            }
        }
        #pragma unroll
        for (int t = 0; t < 6; t++) {
            int n = nb + t * 16 + r;
            int ci = (n & 127) >> 1;
            #pragma unroll
            for (int reg = 0; reg < 4; reg++) {
                int m2 = (row0 + 4 * c + reg) & (Mm - 1);
                float v = acc[t][reg];
                float vp = __shfl_xor(v, 1);             // pair column n^1 lives in lane^1
                float cs = cosT[m2 * 64 + ci], sn = sinT[m2 * 64 + ci];
                v = (n & 1) ? (-vp * sn + v * cs) : (v * cs + vp * sn);
                qkv[(4 * c + reg) * QKS + n] = (_Float16)v;
            }
        }
    }
    __syncthreads();
    // ---- phase 2: in_proj from qkv LDS -> blocked Qp/Kp/Vp ----
    {
        int seg_lo = nb >> 7;
        int seg_hi = (nb + 80) >> 7;
        half4_t afl[8], afh[8];
        #pragma unroll
        for (int kk = 0; kk < 8; kk++) {
            afl[kk] = *(const half4_t*)(qkv + r * QKS + seg_lo * 128 + kk * 16 + 4 * c);
            afh[kk] = *(const half4_t*)(qkv + r * QKS + seg_hi * 128 + kk * 16 + 4 * c);
        }
        float4_t acc[6];
        #pragma unroll
        for (int t = 0; t < 6; t++) acc[t] = (float4_t){0.f, 0.f, 0.f, 0.f};
        #pragma unroll
        for (int kk = 0; kk < 8; kk++) {
            #pragma unroll
            for (int t = 0; t < 6; t++) {
                int colg = nb + t * 16;
                int seg = colg >> 7;
                int nl = (colg & 127) + r;
                half4_t wf = *(const half4_t*)(Whin + (size_t)seg * 16384 + (size_t)nl * 128 + kk * 16 + 4 * c);
                acc[t] = MFMA16(seg == seg_lo ? afl[kk] : afh[kk], wf, acc[t], 0, 0, 0);
            }
        }
        int bb = row0 >> 11;
        int t16 = (row0 & 2047) >> 4;
        #pragma unroll
        for (int t = 0; t < 6; t++) {
            int colg = nb + t * 16;
            int seg = colg >> 7;
            int h = (colg & 127) >> 4;
            size_t tb = ((size_t)(bb * 8 + h) * 128 + t16) * 256;
            float bv = in_b[colg + r];
            _Float16* dst = seg == 0 ? Qp : seg == 1 ? Kp : Vp;
            #pragma unroll
            for (int reg = 0; reg < 4; reg++) {
                float v = acc[t][reg] + bv;
                int key = 4 * c + reg;
                if (seg < 2) dst[tb + key * 16 + r] = (_Float16)v;   // [token][d=r]
                else         dst[tb + r * 16 + key] = (_Float16)v;   // [d=r][token]
            }
        }
    }
}

// ---------------- out_proj: Oh f16 @ W^T + bias + resid(xnh) -> xres f32, ssq partials ----------------
__global__ __launch_bounds__(256) void gemm_ep1_kernel(const _Float16* __restrict__ Oh,
                                                       const _Float16* __restrict__ W6,
                                                       const float* __restrict__ bias,
                                                       const _Float16* __restrict__ xnh,
                                                       float* __restrict__ xres,
                                                       float* __restrict__ partials) {
    __shared__ _Float16 At[16 * XNS];
    int tid = threadIdx.x;
    int row0 = blockIdx.x * 16;
    {
        int rw = tid >> 4, c8 = (tid & 15) * 8;
        *(half8_t*)(At + rw * XNS + c8) = *(const half8_t*)(Oh + (size_t)(row0 + rw) * 128 + c8);
    }
    __syncthreads();
    int wave = tid >> 6, lane = tid & 63;
    int r = lane & 15, c = lane >> 4;
    int n0 = wave * 32;
    half4_t af[8];
    #pragma unroll
    for (int kk = 0; kk < 8; kk++)
        af[kk] = *(const half4_t*)(At + r * XNS + kk * 16 + 4 * c);
    float4_t acc[2];
    acc[0] = (float4_t){0.f, 0.f, 0.f, 0.f};
    acc[1] = (float4_t){0.f, 0.f, 0.f, 0.f};
    #pragma unroll
    for (int kk = 0; kk < 8; kk++) {
        #pragma unroll
        for (int t = 0; t < 2; t++) {
            half4_t wf = *(const half4_t*)(W6 + (size_t)(n0 + t * 16 + r) * 128 + kk * 16 + 4 * c);
            acc[t] = MFMA16(af[kk], wf, acc[t], 0, 0, 0);
        }
    }
    float lssq = 0.f;
    #pragma unroll
    for (int t = 0; t < 2; t++) {
        int n = n0 + t * 16 + r;
        float bv = bias[n];
        #pragma unroll
        for (int reg = 0; reg < 4; reg++) {
            int row = row0 + 4 * c + reg;
            float v = acc[t][reg] + bv + (float)xnh[(size_t)row * 128 + n];
            lssq += v * v;
            xres[(size_t)row * 128 + n] = v;
        }
    }
    #pragma unroll
    for (int off = 32; off; off >>= 1) lssq += __shfl_xor(lssq, off);
    __shared__ float wsum[4];
    if (lane == 0) wsum[wave] = lssq;
    __syncthreads();
    if (tid == 0) partials[blockIdx.x] = wsum[0] + wsum[1] + wsum[2] + wsum[3];
}

// ---------------- FFN: x2nh f16 @ W^T + bias, relu, + resid(xres f32) -> ffoh f16 ----------------
__global__ __launch_bounds__(256) void gemm_ep2_kernel(const _Float16* __restrict__ Ah,
                                                       const _Float16* __restrict__ W7,
                                                       const float* __restrict__ bias,
                                                       const float* __restrict__ xres,
                                                       _Float16* __restrict__ ffoh) {
    __shared__ _Float16 At[16 * XNS];
    int tid = threadIdx.x;
    int row0 = blockIdx.x * 16;
    {
        int rw = tid >> 4, c8 = (tid & 15) * 8;
        *(half8_t*)(At + rw * XNS + c8) = *(const half8_t*)(Ah + (size_t)(row0 + rw) * 128 + c8);
    }
    __syncthreads();
    int wave = tid >> 6, lane = tid & 63;
    int r = lane & 15, c = lane >> 4;
    int n0 = wave * 32;
    half4_t af[8];
    #pragma unroll
    for (int kk = 0; kk < 8; kk++)
        af[kk] = *(const half4_t*)(At + r * XNS + kk * 16 + 4 * c);
    float4_t acc[2];
    acc[0] = (float4_t){0.f, 0.f, 0.f, 0.f};
    acc[1] = (float4_t){0.f, 0.f, 0.f, 0.f};
    #pragma unroll
    for (int kk = 0; kk < 8; kk++) {
        #pragma unroll
        for (int t = 0; t < 2; t++) {
            half4_t wf = *(const half4_t*)(W7 + (size_t)(n0 + t * 16 + r) * 128 + kk * 16 + 4 * c);
            acc[t] = MFMA16(af[kk], wf, acc[t], 0, 0, 0);
        }
    }
    #pragma unroll
    for (int t = 0; t < 2; t++) {
        int n = n0 + t * 16 + r;
        float bv = bias[n];
        #pragma unroll
        for (int reg = 0; reg < 4; reg++) {
            int row = row0 + 4 * c + reg;
            float v = fmaxf(acc[t][reg] + bv, 0.f) + xres[(size_t)row * 128 + n];
            ffoh[(size_t)row * 128 + n] = (_Float16)v;
        }
    }
}

// ---------------- attention helpers ----------------
__device__ __forceinline__ half4_t attn_exps(float4_t st, float& ls) {
    float p0 = fexp2(st[0]), p1 = fexp2(st[1]);
    float p2 = fexp2(st[2]), p3 = fexp2(st[3]);
    ls += (p0 + p1) + (p2 + p3);
    fp16x2 lo = __builtin_amdgcn_cvt_pkrtz(p0, p1);
    fp16x2 hi = __builtin_amdgcn_cvt_pkrtz(p2, p3);
    half4_t pf;
    pf[0] = (_Float16)lo[0]; pf[1] = (_Float16)lo[1];
    pf[2] = (_Float16)hi[0]; pf[3] = (_Float16)hi[1];
    return pf;
}
__device__ __forceinline__ half4_t attn_exps_masked(float4_t st, float& ls, int r, int c) {
    float p0 = (4 * c + 0 <= r) ? fexp2(st[0]) : 0.f;
    float p1 = (4 * c + 1 <= r) ? fexp2(st[1]) : 0.f;
    float p2 = (4 * c + 2 <= r) ? fexp2(st[2]) : 0.f;
    float p3 = (4 * c + 3 <= r) ? fexp2(st[3]) : 0.f;
    ls += (p0 + p1) + (p2 + p3);
    fp16x2 lo = __builtin_amdgcn_cvt_pkrtz(p0, p1);
    fp16x2 hi = __builtin_amdgcn_cvt_pkrtz(p2, p3);
    half4_t pf;
    pf[0] = (_Float16)lo[0]; pf[1] = (_Float16)lo[1];
    pf[2] = (_Float16)hi[0]; pf[3] = (_Float16)hi[1];
    return pf;
}

// ---------------- MFMA flash attention, paired q-tiles, f16 output ----------------
__global__ __launch_bounds__(256) void attn_kernel(const _Float16* __restrict__ Qp,
                                                   const _Float16* __restrict__ Kp,
                                                   const _Float16* __restrict__ Vp,
                                                   _Float16* __restrict__ Oh) {
    int wave = threadIdx.x >> 6, lane = threadIdx.x & 63;
    int wid = blockIdx.x * 4 + wave;
    int qa = wid & 63, bh = wid >> 6, qb = 127 - qa;
    int r = lane & 15, c = lane >> 4;
    int lofs = r * 16 + 4 * c;
    const _Float16* Kb = Kp + (size_t)bh * 32768 + lofs;
    const _Float16* Vb = Vp + (size_t)bh * 32768 + lofs;
    const _Float16* Qb = Qp + (size_t)bh * 32768 + lofs;
    half4_t qfa = *(const half4_t*)(Qb + qa * 256);
    half4_t qfb = *(const half4_t*)(Qb + qb * 256);
    const _Float16 qscale = (_Float16)0.36067376f;   // 0.25 * log2(e)
    qfa *= qscale;
    qfb *= qscale;
    float4_t zero = {0.f, 0.f, 0.f, 0.f};
    float4_t oa = zero, ob = zero;
    float lsa = 0.f, lsb = 0.f;

    int kt = 0;
    for (; kt + 2 <= qa; kt += 2) {
        half4_t k0 = *(const half4_t*)(Kb + kt * 256);
        half4_t v0 = *(const half4_t*)(Vb + kt * 256);
        half4_t k1 = *(const half4_t*)(Kb + kt * 256 + 256);
        half4_t v1 = *(const half4_t*)(Vb + kt * 256 + 256);
        float4_t s0a = MFMA16(k0, qfa, zero, 0, 0, 0);
        float4_t s0b = MFMA16(k0, qfb, zero, 0, 0, 0);
        float4_t s1a = MFMA16(k1, qfa, zero, 0, 0, 0);
        float4_t s1b = MFMA16(k1, qfb, zero, 0, 0, 0);
        half4_t p0a = attn_exps(s0a, lsa);
        half4_t p0b = attn_exps(s0b, lsb);
        half4_t p1a = attn_exps(s1a, lsa);
        half4_t p1b = attn_exps(s1b, lsb);
        oa = MFMA16(p0a, v0, oa, 0, 0, 0);
        ob = MFMA16(p0b, v0, ob, 0, 0, 0);
        oa = MFMA16(p1a, v1, oa, 0, 0, 0);
        ob = MFMA16(p1b, v1, ob, 0, 0, 0);
    }
    if (kt < qa) {
        half4_t k0 = *(const half4_t*)(Kb + kt * 256);
        half4_t v0 = *(const half4_t*)(Vb + kt * 256);
        float4_t sa = MFMA16(k0, qfa, zero, 0, 0, 0);
        float4_t sb = MFMA16(k0, qfb, zero, 0, 0, 0);
        half4_t pa = attn_exps(sa, lsa);
        half4_t pb = attn_exps(sb, lsb);
        oa = MFMA16(pa, v0, oa, 0, 0, 0);
        ob = MFMA16(pb, v0, ob, 0, 0, 0);
    }
    {
        half4_t k0 = *(const half4_t*)(Kb + qa * 256);
        half4_t v0 = *(const half4_t*)(Vb + qa * 256);
        float4_t sa = MFMA16(k0, qfa, zero, 0, 0, 0);
        float4_t sb = MFMA16(k0, qfb, zero, 0, 0, 0);
        half4_t pa = attn_exps_masked(sa, lsa, r, c);
        half4_t pb = attn_exps(sb, lsb);
        oa = MFMA16(pa, v0, oa, 0, 0, 0);
        ob = MFMA16(pb, v0, ob, 0, 0, 0);
    }
    for (kt = qa + 1; kt + 2 <= qb; kt += 2) {
        half4_t k0 = *(const half4_t*)(Kb + kt * 256);
        half4_t v0 = *(const half4_t*)(Vb + kt * 256);
        half4_t k1 = *(const half4_t*)(Kb + kt * 256 + 256);
        half4_t v1 = *(const half4_t*)(Vb + kt * 256 + 256);
        float4_t s0 = MFMA16(k0, qfb, zero, 0, 0, 0);
        float4_t s1 = MFMA16(k1, qfb, zero, 0, 0, 0);
        half4_t p0 = attn_exps(s0, lsb);
        half4_t p1 = attn_exps(s1, lsb);
        ob = MFMA16(p0, v0, ob, 0, 0, 0);
        ob = MFMA16(p1, v1, ob, 0, 0, 0);
    }
    {
        half4_t k0 = *(const half4_t*)(Kb + qb * 256);
        half4_t v0 = *(const half4_t*)(Vb + qb * 256);
        float4_t sb = MFMA16(k0, qfb, zero, 0, 0, 0);
        half4_t pb = attn_exps_masked(sb, lsb, r, c);
        ob = MFMA16(pb, v0, ob, 0, 0, 0);
    }
    lsa += __shfl_xor(lsa, 16); lsa += __shfl_xor(lsa, 32);
    lsb += __shfl_xor(lsb, 16); lsb += __shfl_xor(lsb, 32);
    int b = bh >> 3, h = bh & 7;
    #pragma unroll
    for (int reg = 0; reg < 4; reg++) {
        float la = __shfl(lsa, 4 * c + reg);
        float lb = __shfl(lsb, 4 * c + reg);
        Oh[(size_t)(b * Mm + qa * 16 + 4 * c + reg) * 128 + h * 16 + r] = (_Float16)(oa[reg] / la);
        Oh[(size_t)(b * Mm + qb * 16 + 4 * c + reg) * 128 + h * 16 + r] = (_Float16)(ob[reg] / lb);
    }
}

// ---------------- MFMA logits (V=32) + log_softmax + per-row NLL ----------------
__global__ __launch_bounds__(256) void logits_loss_kernel(const _Float16* __restrict__ Xh,
                                                          const _Float16* __restrict__ Wo16,
                                                          const float* __restrict__ bo,
                                                          const int* __restrict__ targets,
                                                          float* __restrict__ logits,
                                                          float* __restrict__ nllBuf) {
    int wave = threadIdx.x >> 6, lane = threadIdx.x & 63;
    int r = lane & 15, c = lane >> 4;
    int row0 = (blockIdx.x * 4 + wave) * 16;
    const _Float16* Ar = Xh + (size_t)(row0 + r) * 128 + 4 * c;
    half4_t af[8];
    #pragma unroll
    for (int kk = 0; kk < 8; kk++) af[kk] = *(const half4_t*)(Ar + kk * 16);
    float4_t acc[2];
    acc[0] = (float4_t){0.f, 0.f, 0.f, 0.f};
    acc[1] = (float4_t){0.f, 0.f, 0.f, 0.f};
    #pragma unroll
    for (int kk = 0; kk < 8; kk++) {
        #pragma unroll
        for (int t = 0; t < 2; t++) {
            half4_t wf = *(const half4_t*)(Wo16 + (size_t)(t * 16 + r) * 128 + kk * 16 + 4 * c);
            acc[t] = MFMA16(af[kk], wf, acc[t], 0, 0, 0);
        }
    }
    float b0 = bo[r], b1 = bo[r + 16];
    #pragma unroll
    for (int reg = 0; reg < 4; reg++) {
        int row = row0 + 4 * c + reg;
        float l0 = acc[0][reg] + b0;
        float l1 = acc[1][reg] + b1;
        logits[(size_t)row * 32 + r] = l0;
        logits[(size_t)row * 32 + 16 + r] = l1;
        float mx = fmaxf(l0, l1);
        #pragma unroll
        for (int off = 8; off; off >>= 1) mx = fmaxf(mx, __shfl_xor(mx, off));
        float se = __expf(l0 - mx) + __expf(l1 - mx);
        #pragma unroll
        for (int off = 8; off; off >>= 1) se += __shfl_xor(se, off);
        int tgt = targets[row];
        float sel = (tgt & 16) ? l1 : l0;
        float tval = __shfl(sel, (lane & 48) | (tgt & 15));
        if (r == 0) nllBuf[row] = logf(se) + mx - tval;
    }
}

// ---------------- reduce 16384 NLLs -> mean (double accumulation) ----------------
__global__ __launch_bounds__(256) void loss_reduce_kernel(const float* __restrict__ nllBuf,
                                                          float* __restrict__ out) {
    int t = threadIdx.x;
    double s = 0.0;
    #pragma unroll
    for (int i = 0; i < 64; i++) s += (double)nllBuf[t * 64 + i];
    __shared__ double sh[256];
    sh[t] = s;
    __syncthreads();
    for (int off = 128; off; off >>= 1) {
        if (t < off) sh[t] += sh[t + off];
        __syncthreads();
    }
    if (t == 0) out[0] = (float)(sh[0] * (1.0 / (double)BM));
}

extern "C" void kernel_launch(void* const* d_in, const int* in_sizes, int n_in,
                              void* d_out, int out_size, void* d_ws, size_t ws_size,
                              hipStream_t stream) {
    const int*   idx       = (const int*)d_in[0];
    const int*   targets   = (const int*)d_in[1];
    const float* emb       = (const float*)d_in[2];
    const float* rms_scale = (const float*)d_in[3];
    const float* Wq        = (const float*)d_in[4];
    const float* Wk        = (const float*)d_in[5];
    const float* Wv        = (const float*)d_in[6];
    const float* in_w      = (const float*)d_in[7];
    const float* in_b      = (const float*)d_in[8];
    const float* out_pw    = (const float*)d_in[9];
    const float* out_pb    = (const float*)d_in[10];
    const float* lin_w     = (const float*)d_in[11];
    const float* lin_b     = (const float*)d_in[12];
    const float* out_w     = (const float*)d_in[13];
    const float* out_b     = (const float*)d_in[14];
    float* out = (float*)d_out;

    char* base = (char*)d_ws;
    const size_t MB = 1024 * 1024;
    _Float16* xh16  = (_Float16*)base;                 // 0..4MB   gathered x (f16)
    _Float16* xnh   = (_Float16*)(base + 4 * MB);      // 4..8MB   normed x (resid for ep1)
    _Float16* Oh    = (_Float16*)(base + 8 * MB);      // 8..12MB  attn out (f16)
    _Float16* x2nh  = (_Float16*)(base + 12 * MB);     // 12..16MB second normed x
    _Float16* ffoh  = (_Float16*)(base + 16 * MB);     // 16..20MB ffn out (f16)
    _Float16* Qp    = (_Float16*)(base + 20 * MB);     // 20..24MB
    _Float16* Kp    = (_Float16*)(base + 24 * MB);     // 24..28MB
    _Float16* Vp    = (_Float16*)(base + 28 * MB);     // 28..32MB
    float*    xres  = (float*)(base + 32 * MB);        // 32..40MB (f32)
    float*    cosT  = (float*)(base + 40 * MB);        // 512KB
    float*    sinT  = cosT + Mm * 64;                  // 512KB
    float*    part1 = sinT + Mm * 64;                  // 2048
    float*    part2 = part1 + 2048;                    // 1024
    float*    inv1  = part2 + 1024;                    // 8
    float*    inv2  = inv1 + 8;                        // 8
    _Float16* Wh    = (_Float16*)(inv2 + 8);           // 135168 halves (8 mats + out_w)
    float*    nllBuf = (float*)(Wh + 135168);          // 64KB

    prep_kernel<<<1040, 256, 0, stream>>>(Wq, Wk, Wv, in_w, out_pw, lin_w, out_w, Wh, cosT, sinT);
    gather_sumsq_kernel<<<NEL / 1024, 256, 0, stream>>>(idx, emb, xh16, part1);
    ssq_reduce_kernel<<<8, 256, 0, stream>>>(part1, 256, inv1);

    gemm_qkvproj_kernel<<<BM / 16, 256, 0, stream>>>(xh16, rms_scale, inv1,
                                                     Wh, Wh + 3 * 16384, in_b,
                                                     cosT, sinT, xnh, Qp, Kp, Vp);

    attn_kernel<<<64 * 64 / 4, 256, 0, stream>>>(Qp, Kp, Vp, Oh);

    gemm_ep1_kernel<<<BM / 16, 256, 0, stream>>>(Oh, Wh + 6 * 16384, out_pb, xnh, xres, part2);
    ssq_reduce_kernel<<<8, 256, 0, stream>>>(part2, 128, inv2);
    normscale_f_kernel<<<NEL / 1024, 256, 0, stream>>>(xres, rms_scale, inv2, x2nh);
    gemm_ep2_kernel<<<BM / 16, 256, 0, stream>>>(x2nh, Wh + 7 * 16384, lin_b, xres, ffoh);

    logits_loss_kernel<<<BM / 64, 256, 0, stream>>>(ffoh, Wh + 131072, out_b, targets, out, nllBuf);
    loss_reduce_kernel<<<1, 256, 0, stream>>>(nllBuf, out + (size_t)BM * Vv);
}

// Round 11
// 175.221 us; speedup vs baseline: 15.3876x; 1.2124x over previous
//
#include <hip/hip_runtime.h>
#include <hip/hip_bf16.h>
#include <math.h>

#define Vv   32
#define Dd   128
#define Hh   8
#define Bb   8
#define Mm   2048
#define BM   (Bb*Mm)        // 16384
#define NEL  (BM*Dd)        // 2097152
#define XNS  140            // LDS stride (halves) for 128-col tiles, bank-padded
#define QKS  396            // LDS stride (halves) for 384-col qkv tile, bank-padded

typedef _Float16 half4_t __attribute__((ext_vector_type(4)));
typedef _Float16 half8_t __attribute__((ext_vector_type(8)));
typedef __fp16   fp16x2  __attribute__((ext_vector_type(2)));
typedef float    float4_t __attribute__((ext_vector_type(4)));
#define MFMA16 __builtin_amdgcn_mfma_f32_16x16x16f16

#if __has_builtin(__builtin_amdgcn_exp2f)
__device__ __forceinline__ float fexp2(float x) { return __builtin_amdgcn_exp2f(x); }
#else
__device__ __forceinline__ float fexp2(float x) { return __expf(x * 0.6931471805599453f); }
#endif

// ---------------- prep: weights -> f16 MFMA-fragment-blocked tiles, RoPE tables ----------------
// Blocked layout per 128x128 mat: 64 tiles of 256 halves: tile = nt*8+kk holds
// element [nt*16+r][kk*16+cc] at offset tile*256 + r*16 + cc  (one 512B coalesced wave-load).
__global__ __launch_bounds__(256) void prep_kernel(const float* __restrict__ Wq,
                                                   const float* __restrict__ Wk,
                                                   const float* __restrict__ Wv,
                                                   const float* __restrict__ in_w,
                                                   const float* __restrict__ out_pw,
                                                   const float* __restrict__ lin_w,
                                                   const float* __restrict__ out_w,
                                                   _Float16* __restrict__ Wh,
                                                   float* __restrict__ cosT,
                                                   float* __restrict__ sinT) {
    int gid = blockIdx.x * 256 + threadIdx.x;       // 1040*256 = 266240
    if (gid < 135168) {
        const float* src;
        int i;
        if (gid < 131072) {
            int seg = gid >> 14; i = gid & 16383;
            src = seg == 0 ? Wq : seg == 1 ? Wk : seg == 2 ? Wv :
                  seg < 6 ? in_w + (size_t)(seg - 3) * 16384 :
                  seg == 6 ? out_pw : lin_w;
        } else { src = out_w; i = gid - 131072; }   // out_w: 32x128 -> 16 tiles
        int tile = i >> 8, within = i & 255;
        int nt = tile >> 3, kk = tile & 7;
        int r = within >> 4, cc = within & 15;
        Wh[gid] = (_Float16)src[(nt * 16 + r) * 128 + kk * 16 + cc];
    } else {
        int rid = gid - 135168;                     // Mm*64 = 131072
        int i = rid & 63, m = rid >> 6;
        float ex = -2.0f * ((float)i - 1.0f) / 128.0f;
        float basef = expf(ex * 9.210340371976184f);
        float ang = (float)m * basef;
        cosT[rid] = cosf(ang);
        sinT[rid] = sinf(ang);
    }
}

// ---------------- embedding gather -> f16 + per-block ssq partial ----------------
__global__ __launch_bounds__(256) void gather_sumsq_kernel(const int* __restrict__ idx,
                                                           const float* __restrict__ emb,
                                                           _Float16* __restrict__ Xh,
                                                           float* __restrict__ partials) {
    int gid = blockIdx.x * 256 + threadIdx.x;       // NEL/4; grid 2048
    int token = gid >> 5, t4 = gid & 31;
    float4 x = *(const float4*)(emb + (size_t)idx[token] * 128 + t4 * 4);
    half4_t o;
    o[0] = (_Float16)x.x; o[1] = (_Float16)x.y; o[2] = (_Float16)x.z; o[3] = (_Float16)x.w;
    *(half4_t*)(Xh + (size_t)gid * 4) = o;
    float v = x.x * x.x + x.y * x.y + x.z * x.z + x.w * x.w;
    #pragma unroll
    for (int off = 32; off; off >>= 1) v += __shfl_xor(v, off);
    __shared__ float wsum[4];
    int lane = threadIdx.x & 63, wave = threadIdx.x >> 6;
    if (lane == 0) wsum[wave] = v;
    __syncthreads();
    if (threadIdx.x == 0) partials[blockIdx.x] = wsum[0] + wsum[1] + wsum[2] + wsum[3];
}

// ---------------- partials -> inv[b] = 512/sqrt(sum) ----------------
__global__ __launch_bounds__(256) void ssq_reduce_kernel(const float* __restrict__ partials,
                                                         int count,
                                                         float* __restrict__ inv) {
    int b = blockIdx.x, t = threadIdx.x;
    float v = (t < count) ? partials[b * count + t] : 0.f;
    #pragma unroll
    for (int off = 32; off; off >>= 1) v += __shfl_xor(v, off);
    __shared__ float wsum[4];
    int lane = t & 63, wave = t >> 6;
    if (lane == 0) wsum[wave] = v;
    __syncthreads();
    if (t == 0) inv[b] = 512.0f / sqrtf(wsum[0] + wsum[1] + wsum[2] + wsum[3]);
}

// ---------------- normscale: f32 in -> f16 out (second rms_norm) ----------------
__global__ __launch_bounds__(256) void normscale_f_kernel(const float* __restrict__ X,
                                                          const float* __restrict__ scale,
                                                          const float* __restrict__ inv,
                                                          _Float16* __restrict__ outh) {
    int gid = blockIdx.x * 256 + threadIdx.x;       // NEL/4
    float iv = inv[gid >> 16];
    const float* sp = scale + (size_t)((gid >> 5) & 2047) * 128 + (gid & 31) * 4;
    float4 s4 = *(const float4*)sp;
    float4 x = *(const float4*)(X + (size_t)gid * 4);
    half4_t o;
    o[0] = (_Float16)(x.x * iv * s4.x);
    o[1] = (_Float16)(x.y * iv * s4.y);
    o[2] = (_Float16)(x.z * iv * s4.z);
    o[3] = (_Float16)(x.w * iv * s4.w);
    *(half4_t*)(outh + (size_t)gid * 4) = o;
}

// ---------------- FUSED: normscale + QKV proj + RoPE + in_proj -> Qp/Kp/Vp ----------------
// grid 512; block = 32 token rows (2 row-tiles/wave); blocked weights; LDS-staged A.
__global__ __launch_bounds__(256) void gemm_qkvproj_kernel(const _Float16* __restrict__ xh,
                                                           const float* __restrict__ scale,
                                                           const float* __restrict__ inv,
                                                           const _Float16* __restrict__ Whqkv,
                                                           const _Float16* __restrict__ Whin,
                                                           const float* __restrict__ in_b,
                                                           const float* __restrict__ cosT,
                                                           const float* __restrict__ sinT,
                                                           _Float16* __restrict__ xnh,
                                                           _Float16* __restrict__ Qp,
                                                           _Float16* __restrict__ Kp,
                                                           _Float16* __restrict__ Vp) {
    __shared__ _Float16 xn[32 * XNS];
    __shared__ _Float16 qkv[32 * QKS];
    int tid = threadIdx.x;
    int row0 = blockIdx.x * 32;
    // ---- stage + rms-norm (coalesced: half8 per thread, 2 iters) ----
    {
        float iv = inv[row0 >> 11];
        #pragma unroll
        for (int it = 0; it < 2; it++) {
            int idx = tid + it * 256;
            int rw = idx >> 4, c8 = (idx & 15) * 8;
            int m = (row0 + rw) & (Mm - 1);
            half8_t x8 = *(const half8_t*)(xh + (size_t)(row0 + rw) * 128 + c8);
            const float* sp = scale + (size_t)m * 128 + c8;
            float4 s0 = *(const float4*)sp;
            float4 s1 = *(const float4*)(sp + 4);
            half8_t o8;
            o8[0] = (_Float16)((float)x8[0] * iv * s0.x);
            o8[1] = (_Float16)((float)x8[1] * iv * s0.y);
            o8[2] = (_Float16)((float)x8[2] * iv * s0.z);
            o8[3] = (_Float16)((float)x8[3] * iv * s0.w);
            o8[4] = (_Float16)((float)x8[4] * iv * s1.x);
            o8[5] = (_Float16)((float)x8[5] * iv * s1.y);
            o8[6] = (_Float16)((float)x8[6] * iv * s1.z);
            o8[7] = (_Float16)((float)x8[7] * iv * s1.w);
            *(half8_t*)(xn + rw * XNS + c8) = o8;
            *(half8_t*)(xnh + (size_t)(row0 + rw) * 128 + c8) = o8;
        }
    }
    __syncthreads();
    int wave = tid >> 6, lane = tid & 63;
    int r = lane & 15, c = lane >> 4;
    int lofs = r * 16 + 4 * c;
    int nb = wave * 96;                              // global col base (6 tiles)
    int nb16 = wave * 6;                             // col-tile base
    // ---- phase 1: QKV = xn @ (Wq;Wk;Wv)^T (+RoPE) into qkv LDS ----
    {
        half4_t af[2][8];
        #pragma unroll
        for (int rt = 0; rt < 2; rt++)
            #pragma unroll
            for (int kk = 0; kk < 8; kk++)
                af[rt][kk] = *(const half4_t*)(xn + (rt * 16 + r) * XNS + kk * 16 + 4 * c);
        float4_t acc[2][6];
        #pragma unroll
        for (int rt = 0; rt < 2; rt++)
            #pragma unroll
            for (int t = 0; t < 6; t++) acc[rt][t] = (float4_t){0.f, 0.f, 0.f, 0.f};
        #pragma unroll
        for (int kk = 0; kk < 8; kk++) {
            half4_t wf[6];
            #pragma unroll
            for (int t = 0; t < 6; t++)
                wf[t] = *(const half4_t*)(Whqkv + ((nb16 + t) * 8 + kk) * 256 + lofs);
            #pragma unroll
            for (int t = 0; t < 6; t++) {
                acc[0][t] = MFMA16(af[0][kk], wf[t], acc[0][t], 0, 0, 0);
                acc[1][t] = MFMA16(af[1][kk], wf[t], acc[1][t], 0, 0, 0);
            }
        }
        #pragma unroll
        for (int rt = 0; rt < 2; rt++) {
            #pragma unroll
            for (int t = 0; t < 6; t++) {
                int n = nb + t * 16 + r;
                int ci = (n & 127) >> 1;
                #pragma unroll
                for (int reg = 0; reg < 4; reg++) {
                    int m2 = (row0 + rt * 16 + 4 * c + reg) & (Mm - 1);
                    float v = acc[rt][t][reg];
                    float vp = __shfl_xor(v, 1);     // pair column n^1 lives in lane^1
                    float cs = cosT[m2 * 64 + ci], sn = sinT[m2 * 64 + ci];
                    v = (n & 1) ? (-vp * sn + v * cs) : (v * cs + vp * sn);
                    qkv[(rt * 16 + 4 * c + reg) * QKS + n] = (_Float16)v;
                }
            }
        }
    }
    __syncthreads();
    // ---- phase 2: in_proj from qkv LDS -> blocked Qp/Kp/Vp ----
    {
        int seg_lo = nb >> 7;
        int seg_hi = (nb + 80) >> 7;
        half4_t aql[2][8], aqh[2][8];
        #pragma unroll
        for (int rt = 0; rt < 2; rt++)
            #pragma unroll
            for (int kk = 0; kk < 8; kk++) {
                aql[rt][kk] = *(const half4_t*)(qkv + (rt * 16 + r) * QKS + seg_lo * 128 + kk * 16 + 4 * c);
                aqh[rt][kk] = *(const half4_t*)(qkv + (rt * 16 + r) * QKS + seg_hi * 128 + kk * 16 + 4 * c);
            }
        float4_t acc[2][6];
        #pragma unroll
        for (int rt = 0; rt < 2; rt++)
            #pragma unroll
            for (int t = 0; t < 6; t++) acc[rt][t] = (float4_t){0.f, 0.f, 0.f, 0.f};
        #pragma unroll
        for (int kk = 0; kk < 8; kk++) {
            half4_t wf[6];
            #pragma unroll
            for (int t = 0; t < 6; t++) {
                int colg = nb + t * 16;
                int seg = colg >> 7;
                int ntl = (colg & 127) >> 4;
                wf[t] = *(const half4_t*)(Whin + ((seg * 8 + ntl) * 8 + kk) * 256 + lofs);
            }
            #pragma unroll
            for (int t = 0; t < 6; t++) {
                int seg = (nb + t * 16) >> 7;
                acc[0][t] = MFMA16(seg == seg_lo ? aql[0][kk] : aqh[0][kk], wf[t], acc[0][t], 0, 0, 0);
                acc[1][t] = MFMA16(seg == seg_lo ? aql[1][kk] : aqh[1][kk], wf[t], acc[1][t], 0, 0, 0);
            }
        }
        int bb = row0 >> 11;
        #pragma unroll
        for (int rt = 0; rt < 2; rt++) {
            int t16 = ((row0 + rt * 16) & 2047) >> 4;
            #pragma unroll
            for (int t = 0; t < 6; t++) {
                int colg = nb + t * 16;
                int seg = colg >> 7;
                int h = (colg & 127) >> 4;
                size_t tb = ((size_t)(bb * 8 + h) * 128 + t16) * 256;
                float bv = in_b[colg + r];
                _Float16* dst = seg == 0 ? Qp : seg == 1 ? Kp : Vp;
                #pragma unroll
                for (int reg = 0; reg < 4; reg++) {
                    float v = acc[rt][t][reg] + bv;
                    int key = 4 * c + reg;
                    if (seg < 2) dst[tb + key * 16 + r] = (_Float16)v;   // [token][d=r]
                    else         dst[tb + r * 16 + key] = (_Float16)v;   // [d=r][token]
                }
            }
        }
    }
}

// ---------------- out_proj: Oh f16 @ W^T + bias + resid(xnh) -> xres f32, ssq partials ----------------
// grid 512; block = 32 rows; 2 row-tiles x 2 col-tiles per wave
__global__ __launch_bounds__(256) void gemm_ep1_kernel(const _Float16* __restrict__ Oh,
                                                       const _Float16* __restrict__ W6,
                                                       const float* __restrict__ bias,
                                                       const _Float16* __restrict__ xnh,
                                                       float* __restrict__ xres,
                                                       float* __restrict__ partials) {
    __shared__ _Float16 At[32 * XNS];
    int tid = threadIdx.x;
    int row0 = blockIdx.x * 32;
    #pragma unroll
    for (int it = 0; it < 2; it++) {
        int idx = tid + it * 256;
        int rw = idx >> 4, c8 = (idx & 15) * 8;
        *(half8_t*)(At + rw * XNS + c8) = *(const half8_t*)(Oh + (size_t)(row0 + rw) * 128 + c8);
    }
    __syncthreads();
    int wave = tid >> 6, lane = tid & 63;
    int r = lane & 15, c = lane >> 4;
    int lofs = r * 16 + 4 * c;
    int n0 = wave * 32;
    half4_t af[2][8];
    #pragma unroll
    for (int rt = 0; rt < 2; rt++)
        #pragma unroll
        for (int kk = 0; kk < 8; kk++)
            af[rt][kk] = *(const half4_t*)(At + (rt * 16 + r) * XNS + kk * 16 + 4 * c);
    float4_t acc[2][2];
    #pragma unroll
    for (int rt = 0; rt < 2; rt++) {
        acc[rt][0] = (float4_t){0.f, 0.f, 0.f, 0.f};
        acc[rt][1] = (float4_t){0.f, 0.f, 0.f, 0.f};
    }
    #pragma unroll
    for (int kk = 0; kk < 8; kk++) {
        half4_t wf[2];
        wf[0] = *(const half4_t*)(W6 + ((wave * 2 + 0) * 8 + kk) * 256 + lofs);
        wf[1] = *(const half4_t*)(W6 + ((wave * 2 + 1) * 8 + kk) * 256 + lofs);
        #pragma unroll
        for (int t = 0; t < 2; t++) {
            acc[0][t] = MFMA16(af[0][kk], wf[t], acc[0][t], 0, 0, 0);
            acc[1][t] = MFMA16(af[1][kk], wf[t], acc[1][t], 0, 0, 0);
        }
    }
    float lssq = 0.f;
    #pragma unroll
    for (int rt = 0; rt < 2; rt++) {
        #pragma unroll
        for (int t = 0; t < 2; t++) {
            int n = n0 + t * 16 + r;
            float bv = bias[n];
            #pragma unroll
            for (int reg = 0; reg < 4; reg++) {
                int row = row0 + rt * 16 + 4 * c + reg;
                float v = acc[rt][t][reg] + bv + (float)xnh[(size_t)row * 128 + n];
                lssq += v * v;
                xres[(size_t)row * 128 + n] = v;
            }
        }
    }
    #pragma unroll
    for (int off = 32; off; off >>= 1) lssq += __shfl_xor(lssq, off);
    __shared__ float wsum[4];
    if (lane == 0) wsum[wave] = lssq;
    __syncthreads();
    if (tid == 0) partials[blockIdx.x] = wsum[0] + wsum[1] + wsum[2] + wsum[3];
}

// ---------------- FFN: x2nh f16 @ W^T + bias, relu, + resid(xres f32) -> ffoh f16 ----------------
__global__ __launch_bounds__(256) void gemm_ep2_kernel(const _Float16* __restrict__ Ah,
                                                       const _Float16* __restrict__ W7,
                                                       const float* __restrict__ bias,
                                                       const float* __restrict__ xres,
                                                       _Float16* __restrict__ ffoh) {
    __shared__ _Float16 At[32 * XNS];
    int tid = threadIdx.x;
    int row0 = blockIdx.x * 32;
    #pragma unroll
    for (int it = 0; it < 2; it++) {
        int idx = tid + it * 256;
        int rw = idx >> 4, c8 = (idx & 15) * 8;
        *(half8_t*)(At + rw * XNS + c8) = *(const half8_t*)(Ah + (size_t)(row0 + rw) * 128 + c8);
    }
    __syncthreads();
    int wave = tid >> 6, lane = tid & 63;
    int r = lane & 15, c = lane >> 4;
    int lofs = r * 16 + 4 * c;
    int n0 = wave * 32;
    half4_t af[2][8];
    #pragma unroll
    for (int rt = 0; rt < 2; rt++)
        #pragma unroll
        for (int kk = 0; kk < 8; kk++)
            af[rt][kk] = *(const half4_t*)(At + (rt * 16 + r) * XNS + kk * 16 + 4 * c);
    float4_t acc[2][2];
    #pragma unroll
    for (int rt = 0; rt < 2; rt++) {
        acc[rt][0] = (float4_t){0.f, 0.f, 0.f, 0.f};
        acc[rt][1] = (float4_t){0.f, 0.f, 0.f, 0.f};
    }
    #pragma unroll
    for (int kk = 0; kk < 8; kk++) {
        half4_t wf[2];
        wf[0] = *(const half4_t*)(W7 + ((wave * 2 + 0) * 8 + kk) * 256 + lofs);
        wf[1] = *(const half4_t*)(W7 + ((wave * 2 + 1) * 8 + kk) * 256 + lofs);
        #pragma unroll
        for (int t = 0; t < 2; t++) {
            acc[0][t] = MFMA16(af[0][kk], wf[t], acc[0][t], 0, 0, 0);
            acc[1][t] = MFMA16(af[1][kk], wf[t], acc[1][t], 0, 0, 0);
        }
    }
    #pragma unroll
    for (int rt = 0; rt < 2; rt++) {
        #pragma unroll
        for (int t = 0; t < 2; t++) {
            int n = n0 + t * 16 + r;
            float bv = bias[n];
            #pragma unroll
            for (int reg = 0; reg < 4; reg++) {
                int row = row0 + rt * 16 + 4 * c + reg;
                float v = fmaxf(acc[rt][t][reg] + bv, 0.f) + xres[(size_t)row * 128 + n];
                ffoh[(size_t)row * 128 + n] = (_Float16)v;
            }
        }
    }
}

// ---------------- attention helpers ----------------
__device__ __forceinline__ half4_t attn_exps(float4_t st, float& ls) {
    float p0 = fexp2(st[0]), p1 = fexp2(st[1]);
    float p2 = fexp2(st[2]), p3 = fexp2(st[3]);
    ls += (p0 + p1) + (p2 + p3);
    fp16x2 lo = __builtin_amdgcn_cvt_pkrtz(p0, p1);
    fp16x2 hi = __builtin_amdgcn_cvt_pkrtz(p2, p3);
    half4_t pf;
    pf[0] = (_Float16)lo[0]; pf[1] = (_Float16)lo[1];
    pf[2] = (_Float16)hi[0]; pf[3] = (_Float16)hi[1];
    return pf;
}
__device__ __forceinline__ half4_t attn_exps_masked(float4_t st, float& ls, int r, int c) {
    float p0 = (4 * c + 0 <= r) ? fexp2(st[0]) : 0.f;
    float p1 = (4 * c + 1 <= r) ? fexp2(st[1]) : 0.f;
    float p2 = (4 * c + 2 <= r) ? fexp2(st[2]) : 0.f;
    float p3 = (4 * c + 3 <= r) ? fexp2(st[3]) : 0.f;
    ls += (p0 + p1) + (p2 + p3);
    fp16x2 lo = __builtin_amdgcn_cvt_pkrtz(p0, p1);
    fp16x2 hi = __builtin_amdgcn_cvt_pkrtz(p2, p3);
    half4_t pf;
    pf[0] = (_Float16)lo[0]; pf[1] = (_Float16)lo[1];
    pf[2] = (_Float16)hi[0]; pf[3] = (_Float16)hi[1];
    return pf;
}

// ---------------- MFMA flash attention, paired q-tiles, f16 output ----------------
__global__ __launch_bounds__(256) void attn_kernel(const _Float16* __restrict__ Qp,
                                                   const _Float16* __restrict__ Kp,
                                                   const _Float16* __restrict__ Vp,
                                                   _Float16* __restrict__ Oh) {
    int wave = threadIdx.x >> 6, lane = threadIdx.x & 63;
    int wid = blockIdx.x * 4 + wave;
    int qa = wid & 63, bh = wid >> 6, qb = 127 - qa;
    int r = lane & 15, c = lane >> 4;
    int lofs = r * 16 + 4 * c;
    const _Float16* Kb = Kp + (size_t)bh * 32768 + lofs;
    const _Float16* Vb = Vp + (size_t)bh * 32768 + lofs;
    const _Float16* Qb = Qp + (size_t)bh * 32768 + lofs;
    half4_t qfa = *(const half4_t*)(Qb + qa * 256);
    half4_t qfb = *(const half4_t*)(Qb + qb * 256);
    const _Float16 qscale = (_Float16)0.36067376f;   // 0.25 * log2(e)
    qfa *= qscale;
    qfb *= qscale;
    float4_t zero = {0.f, 0.f, 0.f, 0.f};
    float4_t oa = zero, ob = zero;
    float lsa = 0.f, lsb = 0.f;

    int kt = 0;
    for (; kt + 2 <= qa; kt += 2) {
        half4_t k0 = *(const half4_t*)(Kb + kt * 256);
        half4_t v0 = *(const half4_t*)(Vb + kt * 256);
        half4_t k1 = *(const half4_t*)(Kb + kt * 256 + 256);
        half4_t v1 = *(const half4_t*)(Vb + kt * 256 + 256);
        float4_t s0a = MFMA16(k0, qfa, zero, 0, 0, 0);
        float4_t s0b = MFMA16(k0, qfb, zero, 0, 0, 0);
        float4_t s1a = MFMA16(k1, qfa, zero, 0, 0, 0);
        float4_t s1b = MFMA16(k1, qfb, zero, 0, 0, 0);
        half4_t p0a = attn_exps(s0a, lsa);
        half4_t p0b = attn_exps(s0b, lsb);
        half4_t p1a = attn_exps(s1a, lsa);
        half4_t p1b = attn_exps(s1b, lsb);
        oa = MFMA16(p0a, v0, oa, 0, 0, 0);
        ob = MFMA16(p0b, v0, ob, 0, 0, 0);
        oa = MFMA16(p1a, v1, oa, 0, 0, 0);
        ob = MFMA16(p1b, v1, ob, 0, 0, 0);
    }
    if (kt < qa) {
        half4_t k0 = *(const half4_t*)(Kb + kt * 256);
        half4_t v0 = *(const half4_t*)(Vb + kt * 256);
        float4_t sa = MFMA16(k0, qfa, zero, 0, 0, 0);
        float4_t sb = MFMA16(k0, qfb, zero, 0, 0, 0);
        half4_t pa = attn_exps(sa, lsa);
        half4_t pb = attn_exps(sb, lsb);
        oa = MFMA16(pa, v0, oa, 0, 0, 0);
        ob = MFMA16(pb, v0, ob, 0, 0, 0);
    }
    {
        half4_t k0 = *(const half4_t*)(Kb + qa * 256);
        half4_t v0 = *(const half4_t*)(Vb + qa * 256);
        float4_t sa = MFMA16(k0, qfa, zero, 0, 0, 0);
        float4_t sb = MFMA16(k0, qfb, zero, 0, 0, 0);
        half4_t pa = attn_exps_masked(sa, lsa, r, c);
        half4_t pb = attn_exps(sb, lsb);
        oa = MFMA16(pa, v0, oa, 0, 0, 0);
        ob = MFMA16(pb, v0, ob, 0, 0, 0);
    }
    for (kt = qa + 1; kt + 2 <= qb; kt += 2) {
        half4_t k0 = *(const half4_t*)(Kb + kt * 256);
        half4_t v0 = *(const half4_t*)(Vb + kt * 256);
        half4_t k1 = *(const half4_t*)(Kb + kt * 256 + 256);
        half4_t v1 = *(const half4_t*)(Vb + kt * 256 + 256);
        float4_t s0 = MFMA16(k0, qfb, zero, 0, 0, 0);
        float4_t s1 = MFMA16(k1, qfb, zero, 0, 0, 0);
        half4_t p0 = attn_exps(s0, lsb);
        half4_t p1 = attn_exps(s1, lsb);
        ob = MFMA16(p0, v0, ob, 0, 0, 0);
        ob = MFMA16(p1, v1, ob, 0, 0, 0);
    }
    {
        half4_t k0 = *(const half4_t*)(Kb + qb * 256);
        half4_t v0 = *(const half4_t*)(Vb + qb * 256);
        float4_t sb = MFMA16(k0, qfb, zero, 0, 0, 0);
        half4_t pb = attn_exps_masked(sb, lsb, r, c);
        ob = MFMA16(pb, v0, ob, 0, 0, 0);
    }
    lsa += __shfl_xor(lsa, 16); lsa += __shfl_xor(lsa, 32);
    lsb += __shfl_xor(lsb, 16); lsb += __shfl_xor(lsb, 32);
    int b = bh >> 3, h = bh & 7;
    #pragma unroll
    for (int reg = 0; reg < 4; reg++) {
        float la = __shfl(lsa, 4 * c + reg);
        float lb = __shfl(lsb, 4 * c + reg);
        Oh[(size_t)(b * Mm + qa * 16 + 4 * c + reg) * 128 + h * 16 + r] = (_Float16)(oa[reg] / la);
        Oh[(size_t)(b * Mm + qb * 16 + 4 * c + reg) * 128 + h * 16 + r] = (_Float16)(ob[reg] / lb);
    }
}

// ---------------- MFMA logits (V=32) + log_softmax + per-row NLL (LDS-staged A, blocked Wo) ----------------
// grid 256; block = 64 rows (4 waves x 16)
__global__ __launch_bounds__(256) void logits_loss_kernel(const _Float16* __restrict__ Xh,
                                                          const _Float16* __restrict__ Wo16,
                                                          const float* __restrict__ bo,
                                                          const int* __restrict__ targets,
                                                          float* __restrict__ logits,
                                                          float* __restrict__ nllBuf) {
    __shared__ _Float16 At[64 * XNS];
    int tid = threadIdx.x;
    int rowb = blockIdx.x * 64;
    #pragma unroll
    for (int it = 0; it < 4; it++) {
        int idx = tid + it * 256;
        int rw = idx >> 4, c8 = (idx & 15) * 8;
        *(half8_t*)(At + rw * XNS + c8) = *(const half8_t*)(Xh + (size_t)(rowb + rw) * 128 + c8);
    }
    __syncthreads();
    int wave = tid >> 6, lane = tid & 63;
    int r = lane & 15, c = lane >> 4;
    int lofs = r * 16 + 4 * c;
    int row0 = rowb + wave * 16;
    half4_t af[8];
    #pragma unroll
    for (int kk = 0; kk < 8; kk++)
        af[kk] = *(const half4_t*)(At + (wave * 16 + r) * XNS + kk * 16 + 4 * c);
    float4_t acc[2];
    acc[0] = (float4_t){0.f, 0.f, 0.f, 0.f};
    acc[1] = (float4_t){0.f, 0.f, 0.f, 0.f};
    #pragma unroll
    for (int kk = 0; kk < 8; kk++) {
        #pragma unroll
        for (int t = 0; t < 2; t++) {
            half4_t wf = *(const half4_t*)(Wo16 + (t * 8 + kk) * 256 + lofs);
            acc[t] = MFMA16(af[kk], wf, acc[t], 0, 0, 0);
        }
    }
    float b0 = bo[r], b1 = bo[r + 16];
    #pragma unroll
    for (int reg = 0; reg < 4; reg++) {
        int row = row0 + 4 * c + reg;
        float l0 = acc[0][reg] + b0;
        float l1 = acc[1][reg] + b1;
        logits[(size_t)row * 32 + r] = l0;
        logits[(size_t)row * 32 + 16 + r] = l1;
        float mx = fmaxf(l0, l1);
        #pragma unroll
        for (int off = 8; off; off >>= 1) mx = fmaxf(mx, __shfl_xor(mx, off));
        float se = __expf(l0 - mx) + __expf(l1 - mx);
        #pragma unroll
        for (int off = 8; off; off >>= 1) se += __shfl_xor(se, off);
        int tgt = targets[row];
        float sel = (tgt & 16) ? l1 : l0;
        float tval = __shfl(sel, (lane & 48) | (tgt & 15));
        if (r == 0) nllBuf[row] = logf(se) + mx - tval;
    }
}

// ---------------- reduce 16384 NLLs -> mean (double accumulation) ----------------
__global__ __launch_bounds__(256) void loss_reduce_kernel(const float* __restrict__ nllBuf,
                                                          float* __restrict__ out) {
    int t = threadIdx.x;
    double s = 0.0;
    #pragma unroll
    for (int i = 0; i < 64; i++) s += (double)nllBuf[t * 64 + i];
    __shared__ double sh[256];
    sh[t] = s;
    __syncthreads();
    for (int off = 128; off; off >>= 1) {
        if (t < off) sh[t] += sh[t + off];
        __syncthreads();
    }
    if (t == 0) out[0] = (float)(sh[0] * (1.0 / (double)BM));
}

extern "C" void kernel_launch(void* const* d_in, const int* in_sizes, int n_in,
                              void* d_out, int out_size, void* d_ws, size_t ws_size,
                              hipStream_t stream) {
    const int*   idx       = (const int*)d_in[0];
    const int*   targets   = (const int*)d_in[1];
    const float* emb       = (const float*)d_in[2];
    const float* rms_scale = (const float*)d_in[3];
    const float* Wq        = (const float*)d_in[4];
    const float* Wk        = (const float*)d_in[5];
    const float* Wv        = (const float*)d_in[6];
    const float* in_w      = (const float*)d_in[7];
    const float* in_b      = (const float*)d_in[8];
    const float* out_pw    = (const float*)d_in[9];
    const float* out_pb    = (const float*)d_in[10];
    const float* lin_w     = (const float*)d_in[11];
    const float* lin_b     = (const float*)d_in[12];
    const float* out_w     = (const float*)d_in[13];
    const float* out_b     = (const float*)d_in[14];
    float* out = (float*)d_out;

    char* base = (char*)d_ws;
    const size_t MB = 1024 * 1024;
    _Float16* xh16  = (_Float16*)base;                 // 0..4MB   gathered x (f16)
    _Float16* xnh   = (_Float16*)(base + 4 * MB);      // 4..8MB   normed x (resid for ep1)
    _Float16* Oh    = (_Float16*)(base + 8 * MB);      // 8..12MB  attn out (f16)
    _Float16* x2nh  = (_Float16*)(base + 12 * MB);     // 12..16MB second normed x
    _Float16* ffoh  = (_Float16*)(base + 16 * MB);     // 16..20MB ffn out (f16)
    _Float16* Qp    = (_Float16*)(base + 20 * MB);     // 20..24MB
    _Float16* Kp    = (_Float16*)(base + 24 * MB);     // 24..28MB
    _Float16* Vp    = (_Float16*)(base + 28 * MB);     // 28..32MB
    float*    xres  = (float*)(base + 32 * MB);        // 32..40MB (f32)
    float*    cosT  = (float*)(base + 40 * MB);        // 512KB
    float*    sinT  = cosT + Mm * 64;                  // 512KB
    float*    part1 = sinT + Mm * 64;                  // 2048
    float*    part2 = part1 + 2048;                    // 512
    float*    inv1  = part2 + 512;                     // 8
    float*    inv2  = inv1 + 8;                        // 8
    _Float16* Wh    = (_Float16*)(inv2 + 8);           // 135168 halves (8 mats + out_w, blocked)
    float*    nllBuf = (float*)(Wh + 135168);          // 64KB

    prep_kernel<<<1040, 256, 0, stream>>>(Wq, Wk, Wv, in_w, out_pw, lin_w, out_w, Wh, cosT, sinT);
    gather_sumsq_kernel<<<NEL / 1024, 256, 0, stream>>>(idx, emb, xh16, part1);
    ssq_reduce_kernel<<<8, 256, 0, stream>>>(part1, 256, inv1);

    gemm_qkvproj_kernel<<<BM / 32, 256, 0, stream>>>(xh16, rms_scale, inv1,
                                                     Wh, Wh + 3 * 16384, in_b,
                                                     cosT, sinT, xnh, Qp, Kp, Vp);

    attn_kernel<<<64 * 64 / 4, 256, 0, stream>>>(Qp, Kp, Vp, Oh);

    gemm_ep1_kernel<<<BM / 32, 256, 0, stream>>>(Oh, Wh + 6 * 16384, out_pb, xnh, xres, part2);
    ssq_reduce_kernel<<<8, 256, 0, stream>>>(part2, 64, inv2);
    normscale_f_kernel<<<NEL / 1024, 256, 0, stream>>>(xres, rms_scale, inv2, x2nh);
    gemm_ep2_kernel<<<BM / 32, 256, 0, stream>>>(x2nh, Wh + 7 * 16384, lin_b, xres, ffoh);

    logits_loss_kernel<<<BM / 64, 256, 0, stream>>>(ffoh, Wh + 131072, out_b, targets, out, nllBuf);
    loss_reduce_kernel<<<1, 256, 0, stream>>>(nllBuf, out + (size_t)BM * Vv);
}